// Round 5
// baseline (583.503 us; speedup 1.0000x reference)
//
#include <hip/hip_runtime.h>
#include <stdint.h>

#define MAX_RAY 100
#define ECAP 256           // per-cell key stage in emit (Poisson(122) -> P(>256) ~ 1e-24; fallback covers)
#define NBUCK 512          // coarse buckets = top 9 Morton bits
#define PTS_PER_BLK 4096
#define PLACE_CAP 5120     // bucket mean 3906, sigma ~62
typedef unsigned long long ull;
typedef uint32_t u32;

#define N0 262144          // finest cells
#define NBLK0 128          // N0 / 2048
#define NBLKB 168          // 128 + 32 + 8 segid-scan blocks (2048 cells each)

// ---------- helpers ----------
__device__ __forceinline__ u32 spread1(u32 v) {
    v &= 0x1FF;
    v = (v | (v << 8)) & 0x00FF00FF;
    v = (v | (v << 4)) & 0x0F0F0F0F;
    v = (v | (v << 2)) & 0x33333333;
    v = (v | (v << 1)) & 0x55555555;
    return v;
}
__device__ __forceinline__ u32 morton2(u32 i, u32 j) { return (spread1(i) << 1) | spread1(j); }

__device__ __forceinline__ void px_of(const float2 cv, int& pi, int& pj) {
    float fi = fminf(fmaxf(cv.x * 512.0f, 0.0f), 511.0f);
    float fj = fminf(fmaxf(cv.y * 512.0f, 0.0f), 511.0f);
    pi = (int)fi;   // trunc == floor for non-negative; bit-identical to reference
    pj = (int)fj;
}

// ---------- K0: bucket-level histogram (LDS-staged) ----------
__global__ __launch_bounds__(256)
void bucket_hist_kernel(const float2* __restrict__ coords,
                        u32* __restrict__ bucketCnt, int n) {
    __shared__ u32 lh[NBUCK];
    int t = threadIdx.x;
    for (int i = t; i < NBUCK; i += 256) lh[i] = 0;
    __syncthreads();
    int base = blockIdx.x * PTS_PER_BLK;
#pragma unroll
    for (int k = 0; k < 16; ++k) {
        int p = base + k * 256 + t;
        if (p < n) {
            int pi, pj; px_of(coords[p], pi, pj);
            atomicAdd(&lh[morton2(pi, pj) >> 9], 1u);
        }
    }
    __syncthreads();
    for (int i = t; i < NBUCK; i += 256)
        if (lh[i]) atomicAdd(&bucketCnt[i], lh[i]);
}

// ---------- K0b: scan 512 bucket counts -> start + cursor ----------
__global__ __launch_bounds__(NBUCK)
void bucket_scan_kernel(const u32* __restrict__ bucketCnt,
                        u32* __restrict__ bucketStart,
                        u32* __restrict__ bucketCur, int n) {
    __shared__ u32 part[NBUCK];
    int t = threadIdx.x;
    u32 v = bucketCnt[t];
    part[t] = v; __syncthreads();
    for (int off = 1; off < NBUCK; off <<= 1) {
        u32 x = part[t]; u32 a = (t >= off) ? part[t - off] : 0u;
        __syncthreads(); part[t] = x + a; __syncthreads();
    }
    u32 ex = part[t] - v;
    bucketStart[t] = ex; bucketCur[t] = ex;
    if (t == NBUCK - 1) bucketStart[NBUCK] = (u32)n;
}

// ---------- K1: block-local counting sort by bucket, flush runs ----------
// entry = depth(32) | mlow(9) | idx(21)
__global__ __launch_bounds__(256)
void bucket_scatter_kernel(const float2* __restrict__ coords,
                           const float* __restrict__ depth,
                           u32* __restrict__ bucketCur,
                           ull* __restrict__ keys, int n) {
    __shared__ u32 lhist[NBUCK], lofs[NBUCK], lcur[NBUCK], temp[256];
    __shared__ ull stage[PTS_PER_BLK];
    int t = threadIdx.x;
    for (int i = t; i < NBUCK; i += 256) lhist[i] = 0;
    __syncthreads();
    int base = blockIdx.x * PTS_PER_BLK;
    ull ent[16]; u32 cb[16];
#pragma unroll
    for (int k = 0; k < 16; ++k) {
        int p = base + k * 256 + t;
        cb[k] = 0xFFFFFFFFu;
        if (p < n) {
            int pi, pj; px_of(coords[p], pi, pj);
            u32 m = morton2(pi, pj);
            cb[k] = m >> 9;
            ent[k] = ((ull)__float_as_uint(depth[p]) << 32)
                   | ((ull)(m & 511u) << 21) | (ull)(u32)p;
            atomicAdd(&lhist[cb[k]], 1u);
        }
    }
    __syncthreads();
    u32 pv = lhist[2 * t] + lhist[2 * t + 1];
    temp[t] = pv; __syncthreads();
    for (int off = 1; off < 256; off <<= 1) {
        u32 x = temp[t]; u32 a = (t >= off) ? temp[t - off] : 0u;
        __syncthreads(); temp[t] = x + a; __syncthreads();
    }
    u32 pb = temp[t] - pv;
    lofs[2 * t] = pb;                  lofs[2 * t + 1] = pb + lhist[2 * t];
    lcur[2 * t] = pb;                  lcur[2 * t + 1] = pb + lhist[2 * t];
    __syncthreads();
#pragma unroll
    for (int k = 0; k < 16; ++k) {
        if (cb[k] != 0xFFFFFFFFu) {
            u32 pos = atomicAdd(&lcur[cb[k]], 1u);
            stage[pos] = ent[k];
        }
    }
    __syncthreads();
    for (int b = t; b < NBUCK; b += 256) {
        u32 cnt = lhist[b];
        if (!cnt) continue;
        u32 gb = atomicAdd(&bucketCur[b], cnt);
        u32 lo = lofs[b];
        for (u32 i = 0; i < cnt; ++i) keys[gb + i] = stage[lo + i];
    }
}

// ---------- K2a: per-bucket cell histogram -> countsM ----------
__global__ __launch_bounds__(256)
void cell_hist_kernel(const ull* __restrict__ keys,
                      const u32* __restrict__ bucketStart,
                      u32* __restrict__ countsM) {
    __shared__ u32 lh[NBUCK];
    int b = blockIdx.x, t = threadIdx.x;
    for (int i = t; i < NBUCK; i += 256) lh[i] = 0;
    __syncthreads();
    u32 s = bucketStart[b], e = bucketStart[b + 1];
    for (u32 i = s + t; i < e; i += 256) {
        u32 mlow = (u32)(keys[i] >> 21) & 511u;
        atomicAdd(&lh[mlow], 1u);
    }
    __syncthreads();
    for (int i = t; i < NBUCK; i += 256) countsM[(b << 9) + i] = lh[i];
}

// ---------- scanA: countsM -> startsM ----------
__global__ __launch_bounds__(256)
void scanA_partial(const u32* __restrict__ countsM, u32* __restrict__ bsum) {
    int b = blockIdx.x, t = threadIdx.x;
    const uint4* src = (const uint4*)(countsM + b * 2048);
    uint4 a = src[t * 2], c = src[t * 2 + 1];
    u32 s = a.x + a.y + a.z + a.w + c.x + c.y + c.z + c.w;
    __shared__ u32 red[256];
    red[t] = s; __syncthreads();
    for (int off = 128; off; off >>= 1) {
        if (t < off) red[t] += red[t + off];
        __syncthreads();
    }
    if (!t) bsum[b] = red[0];
}

__global__ __launch_bounds__(128)
void scanA_bsum(const u32* __restrict__ bsum, u32* __restrict__ bpre,
                u32* __restrict__ startsM) {
    __shared__ u32 part[NBLK0];
    int t = threadIdx.x;
    u32 v = bsum[t];
    part[t] = v; __syncthreads();
    for (int off = 1; off < NBLK0; off <<= 1) {
        u32 x = part[t];
        u32 a = (t >= off) ? part[t - off] : 0;
        __syncthreads(); part[t] = x + a; __syncthreads();
    }
    bpre[t] = part[t] - v;
    if (t == NBLK0 - 1) startsM[N0] = part[t];   // sentinel = n
}

__global__ __launch_bounds__(256)
void scanA_final(const u32* __restrict__ countsM, const u32* __restrict__ bpre,
                 u32* __restrict__ startsM) {
    int b = blockIdx.x, t = threadIdx.x;
    const uint4* src = (const uint4*)(countsM + b * 2048);
    uint4 a = src[t * 2], c = src[t * 2 + 1];
    u32 e[8] = {a.x, a.y, a.z, a.w, c.x, c.y, c.z, c.w};
    u32 tsum = 0;
#pragma unroll
    for (int k = 0; k < 8; ++k) tsum += e[k];
    __shared__ u32 part[256];
    part[t] = tsum; __syncthreads();
    for (int off = 1; off < 256; off <<= 1) {
        u32 x = part[t];
        u32 ad = (t >= off) ? part[t - off] : 0;
        __syncthreads(); part[t] = x + ad; __syncthreads();
    }
    u32 run = bpre[b] + part[t] - tsum;
    u32 o[8];
#pragma unroll
    for (int k = 0; k < 8; ++k) { o[k] = run; run += e[k]; }
    uint4* d1 = (uint4*)(startsM + b * 2048);
    d1[t * 2]     = make_uint4(o[0], o[1], o[2], o[3]);
    d1[t * 2 + 1] = make_uint4(o[4], o[5], o[6], o[7]);
}

// ---------- K2b: in-place placement into exact cell slots ----------
__global__ __launch_bounds__(256)
void place_kernel(ull* __restrict__ keys,
                  const u32* __restrict__ bucketStart,
                  const u32* __restrict__ startsM) {
    __shared__ ull stage[PLACE_CAP];
    __shared__ u32 cur[NBUCK];
    int b = blockIdx.x, t = threadIdx.x;
    u32 s = bucketStart[b], e = bucketStart[b + 1];
    u32 cnt = e - s;
    u32 lim = cnt < PLACE_CAP ? cnt : PLACE_CAP;
    for (u32 i = t; i < lim; i += 256) stage[i] = keys[s + i];
    for (int i = t; i < NBUCK; i += 256) cur[i] = startsM[(b << 9) + i];
    __syncthreads();
    for (u32 i = t; i < lim; i += 256) {
        ull en = stage[i];
        u32 mlow = (u32)(en >> 21) & 511u;
        u32 slot = atomicAdd(&cur[mlow], 1u);
        keys[slot] = ((en >> 32) << 32) | (en & 0x1FFFFFull);
    }
}

// ---------- segid scans ----------
__device__ __forceinline__ void blk_map(int b, int& si, int& bb) {
    if (b < 128)      { si = 0; bb = b; }
    else if (b < 160) { si = 1; bb = b - 128; }
    else              { si = 2; bb = b - 160; }
}
__device__ __forceinline__ u32 cell_cnt(const u32* startsM, int c, int wbits, int si) {
    u32 ci = (u32)c >> wbits, cj = (u32)c & ((1u << wbits) - 1u);
    u32 mb = morton2(ci, cj) << (2 * si);
    return startsM[mb + (1u << (2 * si))] - startsM[mb];
}

__global__ __launch_bounds__(256)
void scanB_partial(const u32* __restrict__ startsM, u32* __restrict__ bsumB) {
    int si, bb; blk_map(blockIdx.x, si, bb);
    int wbits = 9 - si, t = threadIdx.x;
    int base = bb * 2048 + t * 8;
    u32 s = 0;
#pragma unroll
    for (int k = 0; k < 8; ++k)
        s += (cell_cnt(startsM, base + k, wbits, si) > 0) ? 1u : 0u;
    __shared__ u32 red[256];
    red[t] = s; __syncthreads();
    for (int off = 128; off; off >>= 1) {
        if (t < off) red[t] += red[t + off];
        __syncthreads();
    }
    if (!t) bsumB[blockIdx.x] = red[0];
}

__global__ __launch_bounds__(256)
void scanB_bsum(const u32* __restrict__ bsumB, u32* __restrict__ bpreB,
                u32* __restrict__ ncells) {
    __shared__ u32 part[256];
    int t = threadIdx.x;
    u32 v = (t < NBLKB) ? bsumB[t] : 0u;
    int rid = (t < 128) ? 0 : ((t < 160) ? 1 : 2);
    part[t] = v; __syncthreads();
    for (int off = 1; off < 256; off <<= 1) {
        u32 x = part[t];
        int tp = t - off;
        int ridp = (tp < 128) ? 0 : ((tp < 160) ? 1 : 2);
        u32 a = (tp >= 0 && ridp == rid) ? part[tp] : 0u;
        __syncthreads(); part[t] = x + a; __syncthreads();
    }
    if (t < NBLKB) bpreB[t] = part[t] - v;
    if (t == 127) ncells[0] = part[t];     // segment totals (inclusive at segment end)
    if (t == 159) ncells[1] = part[t];
    if (t == 167) ncells[2] = part[t];
}

struct SegArgs {
    u32* segid[3]; float* lens[3]; float* canvas[3];
};
__global__ __launch_bounds__(256)
void scanB_final(const u32* __restrict__ startsM, const u32* __restrict__ bpreB,
                 SegArgs sa) {
    int si, bb; blk_map(blockIdx.x, si, bb);
    int wbits = 9 - si, t = threadIdx.x;
    int base = bb * 2048 + t * 8;
    u32 cnt[8], flg[8], tsum = 0;
#pragma unroll
    for (int k = 0; k < 8; ++k) {
        cnt[k] = cell_cnt(startsM, base + k, wbits, si);
        flg[k] = cnt[k] ? 1u : 0u;
        tsum += flg[k];
    }
    __shared__ u32 part[256];
    part[t] = tsum; __syncthreads();
    for (int off = 1; off < 256; off <<= 1) {
        u32 x = part[t];
        u32 ad = (t >= off) ? part[t - off] : 0u;
        __syncthreads(); part[t] = x + ad; __syncthreads();
    }
    u32 run = bpreB[blockIdx.x] + part[t] - tsum;
    u32* segid = sa.segid[si];
    float* lens = sa.lens[si];
    float* canvas = sa.canvas[si];
    u32 wmask = (1u << wbits) - 1u;
#pragma unroll
    for (int k = 0; k < 8; ++k) {
        int c = base + k;
        segid[c] = run;
        if (flg[k]) {
            u32 s = run;
            u32 len = cnt[k] < MAX_RAY ? cnt[k] : MAX_RAY;
            lens[s] = (float)len;
            canvas[2 * s]     = (float)((u32)c >> wbits);
            canvas[2 * s + 1] = (float)((u32)c & wmask);
            run += 1;
        }
    }
}

// ---------- K5: emit — rank into LDS tile, stream out full coverage (zeros incl.) ----------
struct EmitArgs {
    const u32* segid[3]; float* batch[3];
};
__global__ __launch_bounds__(256)
void emit_kernel(const float* __restrict__ pm,
                 const u32* __restrict__ startsM,
                 const ull* __restrict__ keys,
                 EmitArgs ea) {
    // block -> (si, 64-cell group); grids: 4096 + 1024 + 256 = 5376
    int b = blockIdx.x, si, bb;
    if (b < 4096)      { si = 0; bb = b; }
    else if (b < 5120) { si = 1; bb = b - 4096; }
    else               { si = 2; bb = b - 5120; }
    int wbits = 9 - si;
    int HW = 1 << (2 * wbits);
    const u32* segid = ea.segid[si];
    float* batch = ea.batch[si];

    __shared__ float tile[MAX_RAY][65];       // +1 pad: rank-writes spread banks
    __shared__ ull   lk[4][ECAP];
    __shared__ u32   s_s0[64], s_cnt[64], s_seg[64];

    int t = threadIdx.x, wave = t >> 6, lane = t & 63;
    int c0 = bb * 64;

    float* tf = &tile[0][0];
    for (int i = t; i < MAX_RAY * 65; i += 256) tf[i] = 0.0f;
    if (t < 64) {
        int cell = c0 + t;
        u32 ci = (u32)cell >> wbits, cj = (u32)cell & ((1u << wbits) - 1u);
        u32 mb = morton2(ci, cj) << (2 * si);
        u32 s0 = startsM[mb];
        s_s0[t]  = s0;
        s_cnt[t] = startsM[mb + (1u << (2 * si))] - s0;
        s_seg[t] = segid[cell];
    }
    __syncthreads();

    // 16 rounds: wave w handles local cell rnd*4 + w
    for (int rnd = 0; rnd < 16; ++rnd) {
        int lc = rnd * 4 + wave;
        u32 cnt = s_cnt[lc], s0 = s_s0[lc];
        bool fits = (cnt <= ECAP);
        if (fits) {
            for (u32 i = lane; i < cnt; i += 64)
                lk[wave][i] = keys[s0 + i];
        }
        __syncthreads();   // uniform; makes stage visible across lanes
        if (fits) {
            for (u32 i = lane; i < cnt; i += 64) {
                ull mk = lk[wave][i];
                u32 r = 0;
                for (u32 j = 0; j < cnt; ++j)       // j wave-uniform -> LDS broadcast
                    r += (lk[wave][j] < mk) ? 1u : 0u;
                if (r < MAX_RAY) tile[r][lc] = pm[(u32)mk];
            }
        } else {            // pathological cell: rank via global reads
            for (u32 i = lane; i < cnt; i += 64) {
                ull mk = keys[s0 + i];
                u32 r = 0;
                for (u32 j = 0; j < cnt; ++j)
                    r += (keys[s0 + j] < mk) ? 1u : 0u;
                if (r < MAX_RAY) tile[r][lc] = pm[(u32)mk];
            }
        }
    }
    __syncthreads();

    // stream rows out: occupied cells have consecutive segs -> coalesced
    u32 myCnt = s_cnt[lane], mySeg = s_seg[lane];
    for (int r = wave; r < MAX_RAY; r += 4) {
        if (myCnt) batch[(size_t)r * (size_t)HW + mySeg] = tile[r][lane];
    }
}

// ---------- K6: zero the unoccupied-tail columns of batch ----------
__global__ __launch_bounds__(256)
void zero_tail_kernel(const u32* __restrict__ ncells,
                      float* __restrict__ b0, float* __restrict__ b1,
                      float* __restrict__ b2) {
    int b = blockIdx.x, si, col; float* base; int HW;
    if (b < 1024)      { si = 0; base = b0; HW = 262144; col = b * 256 + (int)threadIdx.x; }
    else if (b < 1280) { si = 1; base = b1; HW = 65536;  col = (b - 1024) * 256 + (int)threadIdx.x; }
    else               { si = 2; base = b2; HW = 16384;  col = (b - 1280) * 256 + (int)threadIdx.x; }
    if ((u32)col >= ncells[si]) {
        for (int r = 0; r < MAX_RAY; ++r)
            base[(size_t)r * (size_t)HW + col] = 0.0f;
    }
}

extern "C" void kernel_launch(void* const* d_in, const int* in_sizes, int n_in,
                              void* d_out, int out_size, void* d_ws, size_t ws_size,
                              hipStream_t stream) {
    const float2* coords = (const float2*)d_in[0];
    const float*  depth  = (const float*)d_in[1];
    const float*  pm     = (const float*)d_in[2];
    float* out = (float*)d_out;
    const int n = in_sizes[1];

    const int HWs[3] = {512 * 512, 256 * 256, 128 * 128};

    // ---- workspace (~19.4 MB) ----
    char* ws = (char*)d_ws;
    size_t off = 0;
    ull* keys    = (ull*)(ws + off); off += (size_t)n * 8;
    u32* countsM = (u32*)(ws + off); off += (size_t)N0 * 4;
    u32* startsM = (u32*)(ws + off); off += (size_t)(N0 + 64) * 4;
    u32* segid[3];
    for (int i = 0; i < 3; ++i) { segid[i] = (u32*)(ws + off); off += (size_t)HWs[i] * 4; }
    u32* bsumA = (u32*)(ws + off); off += 256 * 4;
    u32* bpreA = (u32*)(ws + off); off += 256 * 4;
    u32* bsumB = (u32*)(ws + off); off += 256 * 4;
    u32* bpreB = (u32*)(ws + off); off += 256 * 4;
    u32* bucketCnt   = (u32*)(ws + off); off += NBUCK * 4;
    u32* bucketStart = (u32*)(ws + off); off += (NBUCK + 64) * 4;
    u32* bucketCur   = (u32*)(ws + off); off += NBUCK * 4;
    u32* ncells      = (u32*)(ws + off); off += 64 * 4;

    // ---- output offsets ----
    size_t offB[3], offL[3], offC[3];
    size_t o = 0;
    for (int i = 0; i < 3; ++i) { offB[i] = o; o += (size_t)MAX_RAY * HWs[i]; }
    for (int i = 0; i < 3; ++i) { offL[i] = o; o += (size_t)HWs[i]; }
    for (int i = 0; i < 3; ++i) { offC[i] = o; o += 2 * (size_t)HWs[i]; }

    // only lens+canvas (contiguous at end, 4.13 MB) need memset; batch is fully
    // written by emit_kernel + zero_tail_kernel
    hipMemsetAsync(out + offL[0], 0, (o - offL[0]) * sizeof(float), stream);
    hipMemsetAsync(bucketCnt, 0, NBUCK * 4, stream);

    const int nblkPts = (n + PTS_PER_BLK - 1) / PTS_PER_BLK;

    bucket_hist_kernel<<<nblkPts, 256, 0, stream>>>(coords, bucketCnt, n);
    bucket_scan_kernel<<<1, NBUCK, 0, stream>>>(bucketCnt, bucketStart, bucketCur, n);
    bucket_scatter_kernel<<<nblkPts, 256, 0, stream>>>(coords, depth, bucketCur, keys, n);
    cell_hist_kernel<<<NBUCK, 256, 0, stream>>>(keys, bucketStart, countsM);
    scanA_partial<<<NBLK0, 256, 0, stream>>>(countsM, bsumA);
    scanA_bsum<<<1, NBLK0, 0, stream>>>(bsumA, bpreA, startsM);
    scanA_final<<<NBLK0, 256, 0, stream>>>(countsM, bpreA, startsM);
    place_kernel<<<NBUCK, 256, 0, stream>>>(keys, bucketStart, startsM);

    SegArgs sa;
    for (int i = 0; i < 3; ++i) {
        sa.segid[i]  = segid[i];
        sa.lens[i]   = out + offL[i];
        sa.canvas[i] = out + offC[i];
    }
    scanB_partial<<<NBLKB, 256, 0, stream>>>(startsM, bsumB);
    scanB_bsum<<<1, 256, 0, stream>>>(bsumB, bpreB, ncells);
    scanB_final<<<NBLKB, 256, 0, stream>>>(startsM, bpreB, sa);

    EmitArgs ea;
    for (int i = 0; i < 3; ++i) {
        ea.segid[i] = segid[i];
        ea.batch[i] = out + offB[i];
    }
    emit_kernel<<<5376, 256, 0, stream>>>(pm, startsM, keys, ea);
    zero_tail_kernel<<<1344, 256, 0, stream>>>(ncells, out + offB[0],
                                               out + offB[1], out + offB[2]);
}

// Round 6
// 401.969 us; speedup vs baseline: 1.4516x; 1.4516x over previous
//
#include <hip/hip_runtime.h>
#include <stdint.h>

#define MAX_RAY 100
#define NBUCK 512          // coarse buckets = top 9 Morton bits
#define PTS_PER_BLK 4096
#define PLACE_CAP 5120     // bucket mean 3906, sigma ~62
typedef unsigned long long ull;
typedef uint32_t u32;

#define N0 262144          // finest cells
#define NBLK0 128          // N0 / 2048
#define NBLKB 168          // 128 + 32 + 8 segid-scan blocks (2048 cells each)

// ---------- helpers ----------
__device__ __forceinline__ u32 spread1(u32 v) {
    v &= 0x1FF;
    v = (v | (v << 8)) & 0x00FF00FF;
    v = (v | (v << 4)) & 0x0F0F0F0F;
    v = (v | (v << 2)) & 0x33333333;
    v = (v | (v << 1)) & 0x55555555;
    return v;
}
__device__ __forceinline__ u32 morton2(u32 i, u32 j) { return (spread1(i) << 1) | spread1(j); }

__device__ __forceinline__ void px_of(const float2 cv, int& pi, int& pj) {
    float fi = fminf(fmaxf(cv.x * 512.0f, 0.0f), 511.0f);
    float fj = fminf(fmaxf(cv.y * 512.0f, 0.0f), 511.0f);
    pi = (int)fi;   // trunc == floor for non-negative; bit-identical to reference
    pj = (int)fj;
}

// ---------- K0: bucket-level histogram (LDS-staged) ----------
__global__ __launch_bounds__(256)
void bucket_hist_kernel(const float2* __restrict__ coords,
                        u32* __restrict__ bucketCnt, int n) {
    __shared__ u32 lh[NBUCK];
    int t = threadIdx.x;
    for (int i = t; i < NBUCK; i += 256) lh[i] = 0;
    __syncthreads();
    int base = blockIdx.x * PTS_PER_BLK;
#pragma unroll
    for (int k = 0; k < 16; ++k) {
        int p = base + k * 256 + t;
        if (p < n) {
            int pi, pj; px_of(coords[p], pi, pj);
            atomicAdd(&lh[morton2(pi, pj) >> 9], 1u);
        }
    }
    __syncthreads();
    for (int i = t; i < NBUCK; i += 256)
        if (lh[i]) atomicAdd(&bucketCnt[i], lh[i]);
}

// ---------- K0b: scan 512 bucket counts -> start + cursor ----------
__global__ __launch_bounds__(NBUCK)
void bucket_scan_kernel(const u32* __restrict__ bucketCnt,
                        u32* __restrict__ bucketStart,
                        u32* __restrict__ bucketCur, int n) {
    __shared__ u32 part[NBUCK];
    int t = threadIdx.x;
    u32 v = bucketCnt[t];
    part[t] = v; __syncthreads();
    for (int off = 1; off < NBUCK; off <<= 1) {
        u32 x = part[t]; u32 a = (t >= off) ? part[t - off] : 0u;
        __syncthreads(); part[t] = x + a; __syncthreads();
    }
    u32 ex = part[t] - v;
    bucketStart[t] = ex; bucketCur[t] = ex;
    if (t == NBUCK - 1) bucketStart[NBUCK] = (u32)n;
}

// ---------- K1: block-local counting sort by bucket; flush keys (+payload) ----------
// entry = depth(32) | mlow(9) | idx(21)
__global__ __launch_bounds__(256)
void bucket_scatter_kernel(const float2* __restrict__ coords,
                           const float* __restrict__ depth,
                           const float* __restrict__ pm,
                           u32* __restrict__ bucketCur,
                           ull* __restrict__ keys,
                           u32* __restrict__ payg,     // may be null
                           int n) {
    __shared__ u32 lhist[NBUCK], lofs[NBUCK], lcur[NBUCK], gbase[NBUCK], temp[256];
    __shared__ ull stage[PTS_PER_BLK];
    int t = threadIdx.x;
    for (int i = t; i < NBUCK; i += 256) lhist[i] = 0;
    __syncthreads();
    int base = blockIdx.x * PTS_PER_BLK;
    ull ent[16]; u32 cb[16]; u32 pos[16];
#pragma unroll
    for (int k = 0; k < 16; ++k) {
        int p = base + k * 256 + t;
        cb[k] = 0xFFFFFFFFu;
        if (p < n) {
            int pi, pj; px_of(coords[p], pi, pj);
            u32 m = morton2(pi, pj);
            cb[k] = m >> 9;
            ent[k] = ((ull)__float_as_uint(depth[p]) << 32)
                   | ((ull)(m & 511u) << 21) | (ull)(u32)p;
            atomicAdd(&lhist[cb[k]], 1u);
        }
    }
    __syncthreads();
    u32 pv = lhist[2 * t] + lhist[2 * t + 1];
    temp[t] = pv; __syncthreads();
    for (int off = 1; off < 256; off <<= 1) {
        u32 x = temp[t]; u32 a = (t >= off) ? temp[t - off] : 0u;
        __syncthreads(); temp[t] = x + a; __syncthreads();
    }
    u32 pb = temp[t] - pv;
    lofs[2 * t] = pb;                  lofs[2 * t + 1] = pb + lhist[2 * t];
    lcur[2 * t] = pb;                  lcur[2 * t + 1] = pb + lhist[2 * t];
    __syncthreads();
#pragma unroll
    for (int k = 0; k < 16; ++k) {
        if (cb[k] != 0xFFFFFFFFu) {
            pos[k] = atomicAdd(&lcur[cb[k]], 1u);
            stage[pos[k]] = ent[k];
        }
    }
    __syncthreads();
    for (int b = t; b < NBUCK; b += 256) {
        u32 cnt = lhist[b];
        if (!cnt) continue;
        u32 gb = atomicAdd(&bucketCur[b], cnt);
        gbase[b] = gb;
        u32 lo = lofs[b];
        for (u32 i = 0; i < cnt; ++i) keys[gb + i] = stage[lo + i];
    }
    if (payg) {
        __syncthreads();
        u32* pstage = (u32*)stage;          // reuse staging LDS for payloads
#pragma unroll
        for (int k = 0; k < 16; ++k) {
            int p = base + k * 256 + t;
            if (cb[k] != 0xFFFFFFFFu) pstage[pos[k]] = __float_as_uint(pm[p]);
        }
        __syncthreads();
        for (int b = t; b < NBUCK; b += 256) {
            u32 cnt = lhist[b];
            if (!cnt) continue;
            u32 gb = gbase[b], lo = lofs[b];
            for (u32 i = 0; i < cnt; ++i) payg[gb + i] = pstage[lo + i];
        }
    }
}

// ---------- K2a: per-bucket cell histogram -> countsM ----------
__global__ __launch_bounds__(256)
void cell_hist_kernel(const ull* __restrict__ keys,
                      const u32* __restrict__ bucketStart,
                      u32* __restrict__ countsM) {
    __shared__ u32 lh[NBUCK];
    int b = blockIdx.x, t = threadIdx.x;
    for (int i = t; i < NBUCK; i += 256) lh[i] = 0;
    __syncthreads();
    u32 s = bucketStart[b], e = bucketStart[b + 1];
    for (u32 i = s + t; i < e; i += 256) {
        u32 mlow = (u32)(keys[i] >> 21) & 511u;
        atomicAdd(&lh[mlow], 1u);
    }
    __syncthreads();
    for (int i = t; i < NBUCK; i += 256) countsM[(b << 9) + i] = lh[i];
}

// ---------- scanA: countsM -> startsM ----------
__global__ __launch_bounds__(256)
void scanA_partial(const u32* __restrict__ countsM, u32* __restrict__ bsum) {
    int b = blockIdx.x, t = threadIdx.x;
    const uint4* src = (const uint4*)(countsM + b * 2048);
    uint4 a = src[t * 2], c = src[t * 2 + 1];
    u32 s = a.x + a.y + a.z + a.w + c.x + c.y + c.z + c.w;
    __shared__ u32 red[256];
    red[t] = s; __syncthreads();
    for (int off = 128; off; off >>= 1) {
        if (t < off) red[t] += red[t + off];
        __syncthreads();
    }
    if (!t) bsum[b] = red[0];
}

__global__ __launch_bounds__(128)
void scanA_bsum(const u32* __restrict__ bsum, u32* __restrict__ bpre,
                u32* __restrict__ startsM) {
    __shared__ u32 part[NBLK0];
    int t = threadIdx.x;
    u32 v = bsum[t];
    part[t] = v; __syncthreads();
    for (int off = 1; off < NBLK0; off <<= 1) {
        u32 x = part[t];
        u32 a = (t >= off) ? part[t - off] : 0;
        __syncthreads(); part[t] = x + a; __syncthreads();
    }
    bpre[t] = part[t] - v;
    if (t == NBLK0 - 1) startsM[N0] = part[t];   // sentinel = n
}

__global__ __launch_bounds__(256)
void scanA_final(const u32* __restrict__ countsM, const u32* __restrict__ bpre,
                 u32* __restrict__ startsM) {
    int b = blockIdx.x, t = threadIdx.x;
    const uint4* src = (const uint4*)(countsM + b * 2048);
    uint4 a = src[t * 2], c = src[t * 2 + 1];
    u32 e[8] = {a.x, a.y, a.z, a.w, c.x, c.y, c.z, c.w};
    u32 tsum = 0;
#pragma unroll
    for (int k = 0; k < 8; ++k) tsum += e[k];
    __shared__ u32 part[256];
    part[t] = tsum; __syncthreads();
    for (int off = 1; off < 256; off <<= 1) {
        u32 x = part[t];
        u32 ad = (t >= off) ? part[t - off] : 0;
        __syncthreads(); part[t] = x + ad; __syncthreads();
    }
    u32 run = bpre[b] + part[t] - tsum;
    u32 o[8];
#pragma unroll
    for (int k = 0; k < 8; ++k) { o[k] = run; run += e[k]; }
    uint4* d1 = (uint4*)(startsM + b * 2048);
    d1[t * 2]     = make_uint4(o[0], o[1], o[2], o[3]);
    d1[t * 2 + 1] = make_uint4(o[4], o[5], o[6], o[7]);
}

// ---------- K2b: in-place placement into exact cell slots (keys + payload) ----------
__global__ __launch_bounds__(256)
void place_kernel(ull* __restrict__ keys,
                  u32* __restrict__ payg,              // may be null
                  const u32* __restrict__ bucketStart,
                  const u32* __restrict__ startsM) {
    __shared__ ull stage[PLACE_CAP];
    __shared__ u32 pstage[PLACE_CAP];
    __shared__ u32 cur[NBUCK];
    int b = blockIdx.x, t = threadIdx.x;
    u32 s = bucketStart[b], e = bucketStart[b + 1];
    u32 cnt = e - s;
    u32 lim = cnt < PLACE_CAP ? cnt : PLACE_CAP;
    for (u32 i = t; i < lim; i += 256) stage[i] = keys[s + i];
    if (payg) for (u32 i = t; i < lim; i += 256) pstage[i] = payg[s + i];
    for (int i = t; i < NBUCK; i += 256) cur[i] = startsM[(b << 9) + i];
    __syncthreads();
    for (u32 i = t; i < lim; i += 256) {
        ull en = stage[i];
        u32 mlow = (u32)(en >> 21) & 511u;
        u32 slot = atomicAdd(&cur[mlow], 1u);
        keys[slot] = ((en >> 32) << 32) | (en & 0x1FFFFFull);
        if (payg) payg[slot] = pstage[i];
    }
}

// ---------- segid scans ----------
__device__ __forceinline__ void blk_map(int b, int& si, int& bb) {
    if (b < 128)      { si = 0; bb = b; }
    else if (b < 160) { si = 1; bb = b - 128; }
    else              { si = 2; bb = b - 160; }
}
__device__ __forceinline__ u32 cell_cnt(const u32* startsM, int c, int wbits, int si) {
    u32 ci = (u32)c >> wbits, cj = (u32)c & ((1u << wbits) - 1u);
    u32 mb = morton2(ci, cj) << (2 * si);
    return startsM[mb + (1u << (2 * si))] - startsM[mb];
}

__global__ __launch_bounds__(256)
void scanB_partial(const u32* __restrict__ startsM, u32* __restrict__ bsumB) {
    int si, bb; blk_map(blockIdx.x, si, bb);
    int wbits = 9 - si, t = threadIdx.x;
    int base = bb * 2048 + t * 8;
    u32 s = 0;
#pragma unroll
    for (int k = 0; k < 8; ++k)
        s += (cell_cnt(startsM, base + k, wbits, si) > 0) ? 1u : 0u;
    __shared__ u32 red[256];
    red[t] = s; __syncthreads();
    for (int off = 128; off; off >>= 1) {
        if (t < off) red[t] += red[t + off];
        __syncthreads();
    }
    if (!t) bsumB[blockIdx.x] = red[0];
}

__global__ __launch_bounds__(256)
void scanB_bsum(const u32* __restrict__ bsumB, u32* __restrict__ bpreB,
                u32* __restrict__ ncells) {
    __shared__ u32 part[256];
    int t = threadIdx.x;
    u32 v = (t < NBLKB) ? bsumB[t] : 0u;
    int rid = (t < 128) ? 0 : ((t < 160) ? 1 : 2);
    part[t] = v; __syncthreads();
    for (int off = 1; off < 256; off <<= 1) {
        u32 x = part[t];
        int tp = t - off;
        int ridp = (tp < 128) ? 0 : ((tp < 160) ? 1 : 2);
        u32 a = (tp >= 0 && ridp == rid) ? part[tp] : 0u;
        __syncthreads(); part[t] = x + a; __syncthreads();
    }
    if (t < NBLKB) bpreB[t] = part[t] - v;
    if (t == 127) ncells[0] = part[t];
    if (t == 159) ncells[1] = part[t];
    if (t == 167) ncells[2] = part[t];
}

struct SegArgs {
    u32* segid[3]; float* lens[3]; float* canvas[3];
};
__global__ __launch_bounds__(256)
void scanB_final(const u32* __restrict__ startsM, const u32* __restrict__ bpreB,
                 SegArgs sa) {
    int si, bb; blk_map(blockIdx.x, si, bb);
    int wbits = 9 - si, t = threadIdx.x;
    int base = bb * 2048 + t * 8;
    u32 cnt[8], flg[8], tsum = 0;
#pragma unroll
    for (int k = 0; k < 8; ++k) {
        cnt[k] = cell_cnt(startsM, base + k, wbits, si);
        flg[k] = cnt[k] ? 1u : 0u;
        tsum += flg[k];
    }
    __shared__ u32 part[256];
    part[t] = tsum; __syncthreads();
    for (int off = 1; off < 256; off <<= 1) {
        u32 x = part[t];
        u32 ad = (t >= off) ? part[t - off] : 0u;
        __syncthreads(); part[t] = x + ad; __syncthreads();
    }
    u32 run = bpreB[blockIdx.x] + part[t] - tsum;
    u32* segid = sa.segid[si];
    float* lens = sa.lens[si];
    float* canvas = sa.canvas[si];
    u32 wmask = (1u << wbits) - 1u;
#pragma unroll
    for (int k = 0; k < 8; ++k) {
        int c = base + k;
        segid[c] = run;
        if (flg[k]) {
            u32 s = run;
            u32 len = cnt[k] < MAX_RAY ? cnt[k] : MAX_RAY;
            lens[s] = (float)len;
            canvas[2 * s]     = (float)((u32)c >> wbits);
            canvas[2 * s + 1] = (float)((u32)c & wmask);
            run += 1;
        }
    }
}

// ---------- K5: emit — shfl-rank per wave, tile in LDS, coalesced full-coverage out ----------
struct EmitArgs {
    const u32* segid[3]; float* batch[3];
};
__global__ __launch_bounds__(256)
void emit_kernel(const float* __restrict__ pm,
                 const u32* __restrict__ payload,     // may be null -> gather pm by idx
                 const u32* __restrict__ startsM,
                 const ull* __restrict__ keys,
                 EmitArgs ea) {
    int b = blockIdx.x, si, bb;
    if (b < 4096)      { si = 0; bb = b; }
    else if (b < 5120) { si = 1; bb = b - 4096; }
    else               { si = 2; bb = b - 5120; }
    int wbits = 9 - si;
    int HW = 1 << (2 * wbits);
    const u32* segid = ea.segid[si];
    float* batch = ea.batch[si];

    __shared__ float tile[MAX_RAY][65];      // NOT zero-initialized (zeros synthesized on store)
    __shared__ u32 s_s0[64], s_cnt[64], s_seg[64];

    int t = threadIdx.x, wave = t >> 6, lane = t & 63;
    int c0 = bb * 64;
    if (t < 64) {
        int cell = c0 + t;
        u32 ci = (u32)cell >> wbits, cj = (u32)cell & ((1u << wbits) - 1u);
        u32 mb = morton2(ci, cj) << (2 * si);
        u32 s0 = startsM[mb];
        s_s0[t]  = s0;
        s_cnt[t] = startsM[mb + (1u << (2 * si))] - s0;
        s_seg[t] = segid[cell];
    }
    __syncthreads();

    // wave handles 16 columns; no barriers inside (tile columns disjoint per wave)
    for (int q = 0; q < 16; ++q) {
        int lc = wave * 16 + q;
        u32 cnt = s_cnt[lc], s0 = s_s0[lc];
        if (cnt == 0) continue;                        // wave-uniform
        if (cnt <= 64) {
            bool v = lane < cnt;
            ull k0 = v ? keys[s0 + lane] : 0ull;
            u32 r0 = 0;
            for (u32 j = 0; j < cnt; ++j) {
                ull kj = __shfl(k0, (int)j);
                r0 += (kj < k0) ? 1u : 0u;
            }
            if (v && r0 < MAX_RAY) {
                u32 pv = payload ? payload[s0 + lane] : __float_as_uint(pm[(u32)(k0 & 0x1FFFFFull)]);
                tile[r0][lc] = __uint_as_float(pv);
            }
        } else if (cnt <= 256) {
            bool v0 = lane < cnt, v1 = 64 + lane < cnt, v2 = 128 + lane < cnt, v3 = 192 + lane < cnt;
            ull k0 = v0 ? keys[s0 + lane] : 0ull;
            ull k1 = v1 ? keys[s0 + 64 + lane] : 0ull;
            ull k2 = v2 ? keys[s0 + 128 + lane] : 0ull;
            ull k3 = v3 ? keys[s0 + 192 + lane] : 0ull;
            u32 r0 = 0, r1 = 0, r2 = 0, r3 = 0;
            for (u32 w = 0; w * 64 < cnt; ++w) {
                ull kw = (w == 0) ? k0 : (w == 1) ? k1 : (w == 2) ? k2 : k3;
                u32 jmax = cnt - w * 64; if (jmax > 64) jmax = 64;
                for (u32 l = 0; l < jmax; ++l) {
                    ull kj = __shfl(kw, (int)l);
                    r0 += (kj < k0) ? 1u : 0u;
                    r1 += (kj < k1) ? 1u : 0u;
                    r2 += (kj < k2) ? 1u : 0u;
                    r3 += (kj < k3) ? 1u : 0u;
                }
            }
            #define EMIT_W(V, R, OFS) \
                if (V && (R) < MAX_RAY) { \
                    u32 pv = payload ? payload[s0 + (OFS) + lane] \
                                     : __float_as_uint(pm[(u32)(((OFS) == 0 ? k0 : (OFS) == 64 ? k1 : (OFS) == 128 ? k2 : k3) & 0x1FFFFFull)]); \
                    tile[R][lc] = __uint_as_float(pv); \
                }
            EMIT_W(v0, r0, 0) EMIT_W(v1, r1, 64) EMIT_W(v2, r2, 128) EMIT_W(v3, r3, 192)
            #undef EMIT_W
        } else {   // pathological (statistically never)
            for (u32 i = lane; i < cnt; i += 64) {
                ull mk = keys[s0 + i];
                u32 r = 0;
                for (u32 j = 0; j < cnt; ++j) r += (keys[s0 + j] < mk) ? 1u : 0u;
                if (r < MAX_RAY) {
                    u32 pv = payload ? payload[s0 + i] : __float_as_uint(pm[(u32)(mk & 0x1FFFFFull)]);
                    tile[r][lc] = __uint_as_float(pv);
                }
            }
        }
    }
    __syncthreads();

    u32 myCnt = s_cnt[lane], mySeg = s_seg[lane];
    u32 lim = myCnt < MAX_RAY ? myCnt : MAX_RAY;
    for (int r = wave; r < MAX_RAY; r += 4) {
        if (myCnt) batch[(size_t)r * (size_t)HW + mySeg] = (r < (int)lim) ? tile[r][lane] : 0.0f;
    }
}

// ---------- K6: zero the unoccupied-tail columns of batch ----------
__global__ __launch_bounds__(256)
void zero_tail_kernel(const u32* __restrict__ ncells,
                      float* __restrict__ b0, float* __restrict__ b1,
                      float* __restrict__ b2) {
    int b = blockIdx.x, si, col; float* base; int HW;
    if (b < 1024)      { si = 0; base = b0; HW = 262144; col = b * 256 + (int)threadIdx.x; }
    else if (b < 1280) { si = 1; base = b1; HW = 65536;  col = (b - 1024) * 256 + (int)threadIdx.x; }
    else               { si = 2; base = b2; HW = 16384;  col = (b - 1280) * 256 + (int)threadIdx.x; }
    if ((u32)col >= ncells[si]) {
        for (int r = 0; r < MAX_RAY; ++r)
            base[(size_t)r * (size_t)HW + col] = 0.0f;
    }
}

extern "C" void kernel_launch(void* const* d_in, const int* in_sizes, int n_in,
                              void* d_out, int out_size, void* d_ws, size_t ws_size,
                              hipStream_t stream) {
    const float2* coords = (const float2*)d_in[0];
    const float*  depth  = (const float*)d_in[1];
    const float*  pm     = (const float*)d_in[2];
    float* out = (float*)d_out;
    const int n = in_sizes[1];

    const int HWs[3] = {512 * 512, 256 * 256, 128 * 128};

    // ---- workspace (~27.6 MB with payload) ----
    char* ws = (char*)d_ws;
    size_t off = 0;
    ull* keys    = (ull*)(ws + off); off += (size_t)n * 8;
    u32* countsM = (u32*)(ws + off); off += (size_t)N0 * 4;
    u32* startsM = (u32*)(ws + off); off += (size_t)(N0 + 64) * 4;
    u32* segid[3];
    for (int i = 0; i < 3; ++i) { segid[i] = (u32*)(ws + off); off += (size_t)HWs[i] * 4; }
    u32* bsumA = (u32*)(ws + off); off += 256 * 4;
    u32* bpreA = (u32*)(ws + off); off += 256 * 4;
    u32* bsumB = (u32*)(ws + off); off += 256 * 4;
    u32* bpreB = (u32*)(ws + off); off += 256 * 4;
    u32* bucketCnt   = (u32*)(ws + off); off += NBUCK * 4;
    u32* bucketStart = (u32*)(ws + off); off += (NBUCK + 64) * 4;
    u32* bucketCur   = (u32*)(ws + off); off += NBUCK * 4;
    u32* ncells      = (u32*)(ws + off); off += 64 * 4;
    u32* payg        = (u32*)(ws + off);
    size_t needPay = off + (size_t)n * 4;
    if (ws_size < needPay) payg = nullptr;   // fallback: emit gathers pm by idx

    // ---- output offsets ----
    size_t offB[3], offL[3], offC[3];
    size_t o = 0;
    for (int i = 0; i < 3; ++i) { offB[i] = o; o += (size_t)MAX_RAY * HWs[i]; }
    for (int i = 0; i < 3; ++i) { offL[i] = o; o += (size_t)HWs[i]; }
    for (int i = 0; i < 3; ++i) { offC[i] = o; o += 2 * (size_t)HWs[i]; }

    hipMemsetAsync(out + offL[0], 0, (o - offL[0]) * sizeof(float), stream);
    hipMemsetAsync(bucketCnt, 0, NBUCK * 4, stream);

    const int nblkPts = (n + PTS_PER_BLK - 1) / PTS_PER_BLK;

    bucket_hist_kernel<<<nblkPts, 256, 0, stream>>>(coords, bucketCnt, n);
    bucket_scan_kernel<<<1, NBUCK, 0, stream>>>(bucketCnt, bucketStart, bucketCur, n);
    bucket_scatter_kernel<<<nblkPts, 256, 0, stream>>>(coords, depth, pm, bucketCur,
                                                       keys, payg, n);
    cell_hist_kernel<<<NBUCK, 256, 0, stream>>>(keys, bucketStart, countsM);
    scanA_partial<<<NBLK0, 256, 0, stream>>>(countsM, bsumA);
    scanA_bsum<<<1, NBLK0, 0, stream>>>(bsumA, bpreA, startsM);
    scanA_final<<<NBLK0, 256, 0, stream>>>(countsM, bpreA, startsM);
    place_kernel<<<NBUCK, 256, 0, stream>>>(keys, payg, bucketStart, startsM);

    SegArgs sa;
    for (int i = 0; i < 3; ++i) {
        sa.segid[i]  = segid[i];
        sa.lens[i]   = out + offL[i];
        sa.canvas[i] = out + offC[i];
    }
    scanB_partial<<<NBLKB, 256, 0, stream>>>(startsM, bsumB);
    scanB_bsum<<<1, 256, 0, stream>>>(bsumB, bpreB, ncells);
    scanB_final<<<NBLKB, 256, 0, stream>>>(startsM, bpreB, sa);

    EmitArgs ea;
    for (int i = 0; i < 3; ++i) {
        ea.segid[i] = segid[i];
        ea.batch[i] = out + offB[i];
    }
    emit_kernel<<<5376, 256, 0, stream>>>(pm, payg, startsM, keys, ea);
    zero_tail_kernel<<<1344, 256, 0, stream>>>(ncells, out + offB[0],
                                               out + offB[1], out + offB[2]);
}

// Round 7
// 398.142 us; speedup vs baseline: 1.4656x; 1.0096x over previous
//
#include <hip/hip_runtime.h>
#include <stdint.h>

#define MAX_RAY 100
#define NBUCK 512          // coarse buckets = top 9 Morton bits
#define PTS_PER_BLK 4096
#define PLACE_CAP 5120     // bucket mean 3906, sigma ~62
typedef unsigned long long ull;
typedef uint32_t u32;

#define N0 262144          // finest cells
#define NBLK0 128          // N0 / 2048
#define NBLKB 168          // 128 + 32 + 8 segid-scan blocks (2048 cells each)

// ---------- helpers ----------
__device__ __forceinline__ u32 spread1(u32 v) {
    v &= 0x1FF;
    v = (v | (v << 8)) & 0x00FF00FF;
    v = (v | (v << 4)) & 0x0F0F0F0F;
    v = (v | (v << 2)) & 0x33333333;
    v = (v | (v << 1)) & 0x55555555;
    return v;
}
__device__ __forceinline__ u32 morton2(u32 i, u32 j) { return (spread1(i) << 1) | spread1(j); }

__device__ __forceinline__ void px_of(const float2 cv, int& pi, int& pj) {
    float fi = fminf(fmaxf(cv.x * 512.0f, 0.0f), 511.0f);
    float fj = fminf(fmaxf(cv.y * 512.0f, 0.0f), 511.0f);
    pi = (int)fi;   // trunc == floor for non-negative; bit-identical to reference
    pj = (int)fj;
}

// ---------- K0: bucket-level histogram (LDS-staged) ----------
__global__ __launch_bounds__(256)
void bucket_hist_kernel(const float2* __restrict__ coords,
                        u32* __restrict__ bucketCnt, int n) {
    __shared__ u32 lh[NBUCK];
    int t = threadIdx.x;
    for (int i = t; i < NBUCK; i += 256) lh[i] = 0;
    __syncthreads();
    int base = blockIdx.x * PTS_PER_BLK;
#pragma unroll
    for (int k = 0; k < 16; ++k) {
        int p = base + k * 256 + t;
        if (p < n) {
            int pi, pj; px_of(coords[p], pi, pj);
            atomicAdd(&lh[morton2(pi, pj) >> 9], 1u);
        }
    }
    __syncthreads();
    for (int i = t; i < NBUCK; i += 256)
        if (lh[i]) atomicAdd(&bucketCnt[i], lh[i]);
}

// ---------- K0b: scan 512 bucket counts -> start + cursor ----------
__global__ __launch_bounds__(NBUCK)
void bucket_scan_kernel(const u32* __restrict__ bucketCnt,
                        u32* __restrict__ bucketStart,
                        u32* __restrict__ bucketCur, int n) {
    __shared__ u32 part[NBUCK];
    int t = threadIdx.x;
    u32 v = bucketCnt[t];
    part[t] = v; __syncthreads();
    for (int off = 1; off < NBUCK; off <<= 1) {
        u32 x = part[t]; u32 a = (t >= off) ? part[t - off] : 0u;
        __syncthreads(); part[t] = x + a; __syncthreads();
    }
    u32 ex = part[t] - v;
    bucketStart[t] = ex; bucketCur[t] = ex;
    if (t == NBUCK - 1) bucketStart[NBUCK] = (u32)n;
}

// ---------- K1: block-local counting sort by bucket; flush keys (+payload) ----------
// entry = depth(32) | mlow(9) | idx(21)
__global__ __launch_bounds__(256)
void bucket_scatter_kernel(const float2* __restrict__ coords,
                           const float* __restrict__ depth,
                           const float* __restrict__ pm,
                           u32* __restrict__ bucketCur,
                           ull* __restrict__ keys,
                           u32* __restrict__ payg,     // may be null
                           int n) {
    __shared__ u32 lhist[NBUCK], lofs[NBUCK], lcur[NBUCK], gbase[NBUCK], temp[256];
    __shared__ ull stage[PTS_PER_BLK];
    int t = threadIdx.x;
    for (int i = t; i < NBUCK; i += 256) lhist[i] = 0;
    __syncthreads();
    int base = blockIdx.x * PTS_PER_BLK;
    ull ent[16]; u32 cb[16]; u32 pos[16];
#pragma unroll
    for (int k = 0; k < 16; ++k) {
        int p = base + k * 256 + t;
        cb[k] = 0xFFFFFFFFu;
        if (p < n) {
            int pi, pj; px_of(coords[p], pi, pj);
            u32 m = morton2(pi, pj);
            cb[k] = m >> 9;
            ent[k] = ((ull)__float_as_uint(depth[p]) << 32)
                   | ((ull)(m & 511u) << 21) | (ull)(u32)p;
            atomicAdd(&lhist[cb[k]], 1u);
        }
    }
    __syncthreads();
    u32 pv = lhist[2 * t] + lhist[2 * t + 1];
    temp[t] = pv; __syncthreads();
    for (int off = 1; off < 256; off <<= 1) {
        u32 x = temp[t]; u32 a = (t >= off) ? temp[t - off] : 0u;
        __syncthreads(); temp[t] = x + a; __syncthreads();
    }
    u32 pb = temp[t] - pv;
    lofs[2 * t] = pb;                  lofs[2 * t + 1] = pb + lhist[2 * t];
    lcur[2 * t] = pb;                  lcur[2 * t + 1] = pb + lhist[2 * t];
    __syncthreads();
#pragma unroll
    for (int k = 0; k < 16; ++k) {
        if (cb[k] != 0xFFFFFFFFu) {
            pos[k] = atomicAdd(&lcur[cb[k]], 1u);
            stage[pos[k]] = ent[k];
        }
    }
    __syncthreads();
    for (int b = t; b < NBUCK; b += 256) {
        u32 cnt = lhist[b];
        if (!cnt) continue;
        u32 gb = atomicAdd(&bucketCur[b], cnt);
        gbase[b] = gb;
        u32 lo = lofs[b];
        for (u32 i = 0; i < cnt; ++i) keys[gb + i] = stage[lo + i];
    }
    if (payg) {
        __syncthreads();
        u32* pstage = (u32*)stage;          // reuse staging LDS for payloads
#pragma unroll
        for (int k = 0; k < 16; ++k) {
            int p = base + k * 256 + t;
            if (cb[k] != 0xFFFFFFFFu) pstage[pos[k]] = __float_as_uint(pm[p]);
        }
        __syncthreads();
        for (int b = t; b < NBUCK; b += 256) {
            u32 cnt = lhist[b];
            if (!cnt) continue;
            u32 gb = gbase[b], lo = lofs[b];
            for (u32 i = 0; i < cnt; ++i) payg[gb + i] = pstage[lo + i];
        }
    }
}

// ---------- K2a: per-bucket cell histogram -> countsM ----------
__global__ __launch_bounds__(256)
void cell_hist_kernel(const ull* __restrict__ keys,
                      const u32* __restrict__ bucketStart,
                      u32* __restrict__ countsM) {
    __shared__ u32 lh[NBUCK];
    int b = blockIdx.x, t = threadIdx.x;
    for (int i = t; i < NBUCK; i += 256) lh[i] = 0;
    __syncthreads();
    u32 s = bucketStart[b], e = bucketStart[b + 1];
    for (u32 i = s + t; i < e; i += 256) {
        u32 mlow = (u32)(keys[i] >> 21) & 511u;
        atomicAdd(&lh[mlow], 1u);
    }
    __syncthreads();
    for (int i = t; i < NBUCK; i += 256) countsM[(b << 9) + i] = lh[i];
}

// ---------- scanA: countsM -> startsM ----------
__global__ __launch_bounds__(256)
void scanA_partial(const u32* __restrict__ countsM, u32* __restrict__ bsum) {
    int b = blockIdx.x, t = threadIdx.x;
    const uint4* src = (const uint4*)(countsM + b * 2048);
    uint4 a = src[t * 2], c = src[t * 2 + 1];
    u32 s = a.x + a.y + a.z + a.w + c.x + c.y + c.z + c.w;
    __shared__ u32 red[256];
    red[t] = s; __syncthreads();
    for (int off = 128; off; off >>= 1) {
        if (t < off) red[t] += red[t + off];
        __syncthreads();
    }
    if (!t) bsum[b] = red[0];
}

__global__ __launch_bounds__(128)
void scanA_bsum(const u32* __restrict__ bsum, u32* __restrict__ bpre,
                u32* __restrict__ startsM) {
    __shared__ u32 part[NBLK0];
    int t = threadIdx.x;
    u32 v = bsum[t];
    part[t] = v; __syncthreads();
    for (int off = 1; off < NBLK0; off <<= 1) {
        u32 x = part[t];
        u32 a = (t >= off) ? part[t - off] : 0;
        __syncthreads(); part[t] = x + a; __syncthreads();
    }
    bpre[t] = part[t] - v;
    if (t == NBLK0 - 1) startsM[N0] = part[t];   // sentinel = n
}

__global__ __launch_bounds__(256)
void scanA_final(const u32* __restrict__ countsM, const u32* __restrict__ bpre,
                 u32* __restrict__ startsM) {
    int b = blockIdx.x, t = threadIdx.x;
    const uint4* src = (const uint4*)(countsM + b * 2048);
    uint4 a = src[t * 2], c = src[t * 2 + 1];
    u32 e[8] = {a.x, a.y, a.z, a.w, c.x, c.y, c.z, c.w};
    u32 tsum = 0;
#pragma unroll
    for (int k = 0; k < 8; ++k) tsum += e[k];
    __shared__ u32 part[256];
    part[t] = tsum; __syncthreads();
    for (int off = 1; off < 256; off <<= 1) {
        u32 x = part[t];
        u32 ad = (t >= off) ? part[t - off] : 0;
        __syncthreads(); part[t] = x + ad; __syncthreads();
    }
    u32 run = bpre[b] + part[t] - tsum;
    u32 o[8];
#pragma unroll
    for (int k = 0; k < 8; ++k) { o[k] = run; run += e[k]; }
    uint4* d1 = (uint4*)(startsM + b * 2048);
    d1[t * 2]     = make_uint4(o[0], o[1], o[2], o[3]);
    d1[t * 2 + 1] = make_uint4(o[4], o[5], o[6], o[7]);
}

// ---------- K2b: in-place placement into exact cell slots (keys + payload) ----------
__global__ __launch_bounds__(256)
void place_kernel(ull* __restrict__ keys,
                  u32* __restrict__ payg,              // may be null
                  const u32* __restrict__ bucketStart,
                  const u32* __restrict__ startsM) {
    __shared__ ull stage[PLACE_CAP];
    __shared__ u32 pstage[PLACE_CAP];
    __shared__ u32 cur[NBUCK];
    int b = blockIdx.x, t = threadIdx.x;
    u32 s = bucketStart[b], e = bucketStart[b + 1];
    u32 cnt = e - s;
    u32 lim = cnt < PLACE_CAP ? cnt : PLACE_CAP;
    for (u32 i = t; i < lim; i += 256) stage[i] = keys[s + i];
    if (payg) for (u32 i = t; i < lim; i += 256) pstage[i] = payg[s + i];
    for (int i = t; i < NBUCK; i += 256) cur[i] = startsM[(b << 9) + i];
    __syncthreads();
    for (u32 i = t; i < lim; i += 256) {
        ull en = stage[i];
        u32 mlow = (u32)(en >> 21) & 511u;
        u32 slot = atomicAdd(&cur[mlow], 1u);
        keys[slot] = ((en >> 32) << 32) | (en & 0x1FFFFFull);
        if (payg) payg[slot] = pstage[i];
    }
}

// ---------- segid scans ----------
__device__ __forceinline__ void blk_map(int b, int& si, int& bb) {
    if (b < 128)      { si = 0; bb = b; }
    else if (b < 160) { si = 1; bb = b - 128; }
    else              { si = 2; bb = b - 160; }
}
__device__ __forceinline__ u32 cell_cnt(const u32* startsM, int c, int wbits, int si) {
    u32 ci = (u32)c >> wbits, cj = (u32)c & ((1u << wbits) - 1u);
    u32 mb = morton2(ci, cj) << (2 * si);
    return startsM[mb + (1u << (2 * si))] - startsM[mb];
}

__global__ __launch_bounds__(256)
void scanB_partial(const u32* __restrict__ startsM, u32* __restrict__ bsumB) {
    int si, bb; blk_map(blockIdx.x, si, bb);
    int wbits = 9 - si, t = threadIdx.x;
    int base = bb * 2048 + t * 8;
    u32 s = 0;
#pragma unroll
    for (int k = 0; k < 8; ++k)
        s += (cell_cnt(startsM, base + k, wbits, si) > 0) ? 1u : 0u;
    __shared__ u32 red[256];
    red[t] = s; __syncthreads();
    for (int off = 128; off; off >>= 1) {
        if (t < off) red[t] += red[t + off];
        __syncthreads();
    }
    if (!t) bsumB[blockIdx.x] = red[0];
}

__global__ __launch_bounds__(256)
void scanB_bsum(const u32* __restrict__ bsumB, u32* __restrict__ bpreB,
                u32* __restrict__ ncells) {
    __shared__ u32 part[256];
    int t = threadIdx.x;
    u32 v = (t < NBLKB) ? bsumB[t] : 0u;
    int rid = (t < 128) ? 0 : ((t < 160) ? 1 : 2);
    part[t] = v; __syncthreads();
    for (int off = 1; off < 256; off <<= 1) {
        u32 x = part[t];
        int tp = t - off;
        int ridp = (tp < 128) ? 0 : ((tp < 160) ? 1 : 2);
        u32 a = (tp >= 0 && ridp == rid) ? part[tp] : 0u;
        __syncthreads(); part[t] = x + a; __syncthreads();
    }
    if (t < NBLKB) bpreB[t] = part[t] - v;
    if (t == 127) ncells[0] = part[t];
    if (t == 159) ncells[1] = part[t];
    if (t == 167) ncells[2] = part[t];
}

struct SegArgs {
    u32* segid[3]; float* lens[3]; float* canvas[3];
};
__global__ __launch_bounds__(256)
void scanB_final(const u32* __restrict__ startsM, const u32* __restrict__ bpreB,
                 SegArgs sa) {
    int si, bb; blk_map(blockIdx.x, si, bb);
    int wbits = 9 - si, t = threadIdx.x;
    int base = bb * 2048 + t * 8;
    u32 cnt[8], flg[8], tsum = 0;
#pragma unroll
    for (int k = 0; k < 8; ++k) {
        cnt[k] = cell_cnt(startsM, base + k, wbits, si);
        flg[k] = cnt[k] ? 1u : 0u;
        tsum += flg[k];
    }
    __shared__ u32 part[256];
    part[t] = tsum; __syncthreads();
    for (int off = 1; off < 256; off <<= 1) {
        u32 x = part[t];
        u32 ad = (t >= off) ? part[t - off] : 0u;
        __syncthreads(); part[t] = x + ad; __syncthreads();
    }
    u32 run = bpreB[blockIdx.x] + part[t] - tsum;
    u32* segid = sa.segid[si];
    float* lens = sa.lens[si];
    float* canvas = sa.canvas[si];
    u32 wmask = (1u << wbits) - 1u;
#pragma unroll
    for (int k = 0; k < 8; ++k) {
        int c = base + k;
        segid[c] = run;
        if (flg[k]) {
            u32 s = run;
            u32 len = cnt[k] < MAX_RAY ? cnt[k] : MAX_RAY;
            lens[s] = (float)len;
            canvas[2 * s]     = (float)((u32)c >> wbits);
            canvas[2 * s + 1] = (float)((u32)c & wmask);
            run += 1;
        }
    }
}

// ---------- K5: emit — register-prefetched shfl-rank, coalesced full-coverage out ----------
struct EmitArgs {
    const u32* segid[3]; float* batch[3];
};
__global__ __launch_bounds__(256)
void emit_kernel(const float* __restrict__ pm,
                 const u32* __restrict__ payload,     // may be null -> gather pm by idx
                 const u32* __restrict__ startsM,
                 const ull* __restrict__ keys,
                 EmitArgs ea) {
    int b = blockIdx.x, si, bb;
    if (b < 4096)      { si = 0; bb = b; }
    else if (b < 5120) { si = 1; bb = b - 4096; }
    else               { si = 2; bb = b - 5120; }
    int wbits = 9 - si;
    int HW = 1 << (2 * wbits);
    const u32* segid = ea.segid[si];
    float* batch = ea.batch[si];

    __shared__ float tile[MAX_RAY][65];      // NOT zero-initialized (zeros synthesized on store)
    __shared__ u32 s_s0[64], s_cnt[64], s_seg[64];

    int t = threadIdx.x, wave = t >> 6, lane = t & 63;
    int c0 = bb * 64;
    if (t < 64) {
        int cell = c0 + t;
        u32 ci = (u32)cell >> wbits, cj = (u32)cell & ((1u << wbits) - 1u);
        u32 mb = morton2(ci, cj) << (2 * si);
        u32 s0 = startsM[mb];
        s_s0[t]  = s0;
        s_cnt[t] = startsM[mb + (1u << (2 * si))] - s0;
        s_seg[t] = segid[cell];
    }
    __syncthreads();

    // ---- prefetch phase: 32 independent loads per wave (keys + payload, chunk 0) ----
    ull k0[16]; u32 p0[16];
#pragma unroll
    for (int q = 0; q < 16; ++q) {
        int lc = wave * 16 + q;
        u32 cnt = s_cnt[lc], s0 = s_s0[lc];
        bool v = lane < cnt;
        k0[q] = v ? keys[s0 + lane] : ~0ull;                 // sentinel max
        p0[q] = v ? (payload ? payload[s0 + lane]
                             : __float_as_uint(pm[(u32)(k0[q] & 0x1FFFFFull)]))
                  : 0u;
    }

    // ---- rank phase: pure shfl/VALU for cnt<=64; per-cell chunked for bigger ----
#pragma unroll
    for (int q = 0; q < 16; ++q) {
        int lc = wave * 16 + q;
        u32 cnt = s_cnt[lc], s0 = s_s0[lc];
        if (cnt == 0) continue;                              // wave-uniform
        if (cnt <= 64) {
            ull mk = k0[q];
            u32 r = 0;
            for (u32 j = 0; j < cnt; ++j) {
                ull kj = __shfl(k0[q], (int)j);
                r += (kj < mk) ? 1u : 0u;
            }
            if (lane < cnt && r < MAX_RAY)
                tile[r][lc] = __uint_as_float(p0[q]);
        } else if (cnt <= 256) {
            bool v1 = 64 + lane < cnt, v2 = 128 + lane < cnt, v3 = 192 + lane < cnt;
            ull kk1 = v1 ? keys[s0 + 64 + lane] : ~0ull;
            ull kk2 = v2 ? keys[s0 + 128 + lane] : ~0ull;
            ull kk3 = v3 ? keys[s0 + 192 + lane] : ~0ull;
            u32 r0 = 0, r1 = 0, r2 = 0, r3 = 0;
            for (u32 w = 0; w * 64 < cnt; ++w) {
                ull kw = (w == 0) ? k0[q] : (w == 1) ? kk1 : (w == 2) ? kk2 : kk3;
                u32 jmax = cnt - w * 64; if (jmax > 64) jmax = 64;
                for (u32 l = 0; l < jmax; ++l) {
                    ull kj = __shfl(kw, (int)l);
                    r0 += (kj < k0[q]) ? 1u : 0u;
                    r1 += (kj < kk1) ? 1u : 0u;
                    r2 += (kj < kk2) ? 1u : 0u;
                    r3 += (kj < kk3) ? 1u : 0u;
                }
            }
            if (lane < cnt && r0 < MAX_RAY) tile[r0][lc] = __uint_as_float(p0[q]);
            #define EMIT_W(V, R, OFS, KREG) \
                if (V && (R) < MAX_RAY) { \
                    u32 pv = payload ? payload[s0 + (OFS) + lane] \
                                     : __float_as_uint(pm[(u32)((KREG) & 0x1FFFFFull)]); \
                    tile[R][lc] = __uint_as_float(pv); \
                }
            EMIT_W(v1, r1, 64, kk1) EMIT_W(v2, r2, 128, kk2) EMIT_W(v3, r3, 192, kk3)
            #undef EMIT_W
        } else {   // pathological (statistically never)
            for (u32 i = lane; i < cnt; i += 64) {
                ull mk = keys[s0 + i];
                u32 r = 0;
                for (u32 j = 0; j < cnt; ++j) r += (keys[s0 + j] < mk) ? 1u : 0u;
                if (r < MAX_RAY) {
                    u32 pv = payload ? payload[s0 + i] : __float_as_uint(pm[(u32)(mk & 0x1FFFFFull)]);
                    tile[r][lc] = __uint_as_float(pv);
                }
            }
        }
    }
    __syncthreads();

    u32 myCnt = s_cnt[lane], mySeg = s_seg[lane];
    u32 lim = myCnt < MAX_RAY ? myCnt : MAX_RAY;
    for (int r = wave; r < MAX_RAY; r += 4) {
        if (myCnt) batch[(size_t)r * (size_t)HW + mySeg] = (r < (int)lim) ? tile[r][lane] : 0.0f;
    }
}

// ---------- K6: zero the unoccupied-tail columns of batch ----------
__global__ __launch_bounds__(256)
void zero_tail_kernel(const u32* __restrict__ ncells,
                      float* __restrict__ b0, float* __restrict__ b1,
                      float* __restrict__ b2) {
    int b = blockIdx.x, si, col; float* base; int HW;
    if (b < 1024)      { si = 0; base = b0; HW = 262144; col = b * 256 + (int)threadIdx.x; }
    else if (b < 1280) { si = 1; base = b1; HW = 65536;  col = (b - 1024) * 256 + (int)threadIdx.x; }
    else               { si = 2; base = b2; HW = 16384;  col = (b - 1280) * 256 + (int)threadIdx.x; }
    if ((u32)col >= ncells[si]) {
        for (int r = 0; r < MAX_RAY; ++r)
            base[(size_t)r * (size_t)HW + col] = 0.0f;
    }
}

extern "C" void kernel_launch(void* const* d_in, const int* in_sizes, int n_in,
                              void* d_out, int out_size, void* d_ws, size_t ws_size,
                              hipStream_t stream) {
    const float2* coords = (const float2*)d_in[0];
    const float*  depth  = (const float*)d_in[1];
    const float*  pm     = (const float*)d_in[2];
    float* out = (float*)d_out;
    const int n = in_sizes[1];

    const int HWs[3] = {512 * 512, 256 * 256, 128 * 128};

    // ---- workspace (~27.6 MB with payload) ----
    char* ws = (char*)d_ws;
    size_t off = 0;
    ull* keys    = (ull*)(ws + off); off += (size_t)n * 8;
    u32* countsM = (u32*)(ws + off); off += (size_t)N0 * 4;
    u32* startsM = (u32*)(ws + off); off += (size_t)(N0 + 64) * 4;
    u32* segid[3];
    for (int i = 0; i < 3; ++i) { segid[i] = (u32*)(ws + off); off += (size_t)HWs[i] * 4; }
    u32* bsumA = (u32*)(ws + off); off += 256 * 4;
    u32* bpreA = (u32*)(ws + off); off += 256 * 4;
    u32* bsumB = (u32*)(ws + off); off += 256 * 4;
    u32* bpreB = (u32*)(ws + off); off += 256 * 4;
    u32* bucketCnt   = (u32*)(ws + off); off += NBUCK * 4;
    u32* bucketStart = (u32*)(ws + off); off += (NBUCK + 64) * 4;
    u32* bucketCur   = (u32*)(ws + off); off += NBUCK * 4;
    u32* ncells      = (u32*)(ws + off); off += 64 * 4;
    u32* payg        = (u32*)(ws + off);
    size_t needPay = off + (size_t)n * 4;
    if (ws_size < needPay) payg = nullptr;   // fallback: emit gathers pm by idx

    // ---- output offsets ----
    size_t offB[3], offL[3], offC[3];
    size_t o = 0;
    for (int i = 0; i < 3; ++i) { offB[i] = o; o += (size_t)MAX_RAY * HWs[i]; }
    for (int i = 0; i < 3; ++i) { offL[i] = o; o += (size_t)HWs[i]; }
    for (int i = 0; i < 3; ++i) { offC[i] = o; o += 2 * (size_t)HWs[i]; }

    hipMemsetAsync(out + offL[0], 0, (o - offL[0]) * sizeof(float), stream);
    hipMemsetAsync(bucketCnt, 0, NBUCK * 4, stream);

    const int nblkPts = (n + PTS_PER_BLK - 1) / PTS_PER_BLK;

    bucket_hist_kernel<<<nblkPts, 256, 0, stream>>>(coords, bucketCnt, n);
    bucket_scan_kernel<<<1, NBUCK, 0, stream>>>(bucketCnt, bucketStart, bucketCur, n);
    bucket_scatter_kernel<<<nblkPts, 256, 0, stream>>>(coords, depth, pm, bucketCur,
                                                       keys, payg, n);
    cell_hist_kernel<<<NBUCK, 256, 0, stream>>>(keys, bucketStart, countsM);
    scanA_partial<<<NBLK0, 256, 0, stream>>>(countsM, bsumA);
    scanA_bsum<<<1, NBLK0, 0, stream>>>(bsumA, bpreA, startsM);
    scanA_final<<<NBLK0, 256, 0, stream>>>(countsM, bpreA, startsM);
    place_kernel<<<NBUCK, 256, 0, stream>>>(keys, payg, bucketStart, startsM);

    SegArgs sa;
    for (int i = 0; i < 3; ++i) {
        sa.segid[i]  = segid[i];
        sa.lens[i]   = out + offL[i];
        sa.canvas[i] = out + offC[i];
    }
    scanB_partial<<<NBLKB, 256, 0, stream>>>(startsM, bsumB);
    scanB_bsum<<<1, 256, 0, stream>>>(bsumB, bpreB, ncells);
    scanB_final<<<NBLKB, 256, 0, stream>>>(startsM, bpreB, sa);

    EmitArgs ea;
    for (int i = 0; i < 3; ++i) {
        ea.segid[i] = segid[i];
        ea.batch[i] = out + offB[i];
    }
    emit_kernel<<<5376, 256, 0, stream>>>(pm, payg, startsM, keys, ea);
    zero_tail_kernel<<<1344, 256, 0, stream>>>(ncells, out + offB[0],
                                               out + offB[1], out + offB[2]);
}

// Round 8
// 291.690 us; speedup vs baseline: 2.0004x; 1.3649x over previous
//
#include <hip/hip_runtime.h>
#include <stdint.h>

#define MAX_RAY 100
#define LKCAP 256          // per-wave staged keys (Poisson(122): P(cnt>256) ~ 0)
#define NBUCK 512          // coarse buckets = top 9 Morton bits
#define PTS_PER_BLK 4096
#define PLACE_CAP 5120     // bucket mean 3906, sigma ~62
typedef unsigned long long ull;
typedef uint32_t u32;

#define N0 262144          // finest cells
#define NBLK0 128          // N0 / 2048
#define NBLKB 168          // 128 + 32 + 8 segid-scan blocks (2048 cells each)

// ---------- helpers ----------
__device__ __forceinline__ u32 spread1(u32 v) {
    v &= 0x1FF;
    v = (v | (v << 8)) & 0x00FF00FF;
    v = (v | (v << 4)) & 0x0F0F0F0F;
    v = (v | (v << 2)) & 0x33333333;
    v = (v | (v << 1)) & 0x55555555;
    return v;
}
__device__ __forceinline__ u32 morton2(u32 i, u32 j) { return (spread1(i) << 1) | spread1(j); }

__device__ __forceinline__ void px_of(const float2 cv, int& pi, int& pj) {
    float fi = fminf(fmaxf(cv.x * 512.0f, 0.0f), 511.0f);
    float fj = fminf(fmaxf(cv.y * 512.0f, 0.0f), 511.0f);
    pi = (int)fi;   // trunc == floor for non-negative; bit-identical to reference
    pj = (int)fj;
}

// ---------- K0: bucket-level histogram (LDS-staged) ----------
__global__ __launch_bounds__(256)
void bucket_hist_kernel(const float2* __restrict__ coords,
                        u32* __restrict__ bucketCnt, int n) {
    __shared__ u32 lh[NBUCK];
    int t = threadIdx.x;
    for (int i = t; i < NBUCK; i += 256) lh[i] = 0;
    __syncthreads();
    int base = blockIdx.x * PTS_PER_BLK;
#pragma unroll
    for (int k = 0; k < 16; ++k) {
        int p = base + k * 256 + t;
        if (p < n) {
            int pi, pj; px_of(coords[p], pi, pj);
            atomicAdd(&lh[morton2(pi, pj) >> 9], 1u);
        }
    }
    __syncthreads();
    for (int i = t; i < NBUCK; i += 256)
        if (lh[i]) atomicAdd(&bucketCnt[i], lh[i]);
}

// ---------- K0b: scan 512 bucket counts -> start + cursor ----------
__global__ __launch_bounds__(NBUCK)
void bucket_scan_kernel(const u32* __restrict__ bucketCnt,
                        u32* __restrict__ bucketStart,
                        u32* __restrict__ bucketCur, int n) {
    __shared__ u32 part[NBUCK];
    int t = threadIdx.x;
    u32 v = bucketCnt[t];
    part[t] = v; __syncthreads();
    for (int off = 1; off < NBUCK; off <<= 1) {
        u32 x = part[t]; u32 a = (t >= off) ? part[t - off] : 0u;
        __syncthreads(); part[t] = x + a; __syncthreads();
    }
    u32 ex = part[t] - v;
    bucketStart[t] = ex; bucketCur[t] = ex;
    if (t == NBUCK - 1) bucketStart[NBUCK] = (u32)n;
}

// ---------- K1: block-local counting sort by bucket; flush keys (+payload) ----------
// entry = depth(32) | mlow(9) | idx(21)
__global__ __launch_bounds__(256)
void bucket_scatter_kernel(const float2* __restrict__ coords,
                           const float* __restrict__ depth,
                           const float* __restrict__ pm,
                           u32* __restrict__ bucketCur,
                           ull* __restrict__ keys,
                           u32* __restrict__ payg,     // may be null
                           int n) {
    __shared__ u32 lhist[NBUCK], lofs[NBUCK], lcur[NBUCK], gbase[NBUCK], temp[256];
    __shared__ ull stage[PTS_PER_BLK];
    int t = threadIdx.x;
    for (int i = t; i < NBUCK; i += 256) lhist[i] = 0;
    __syncthreads();
    int base = blockIdx.x * PTS_PER_BLK;
    ull ent[16]; u32 cb[16]; u32 pos[16];
#pragma unroll
    for (int k = 0; k < 16; ++k) {
        int p = base + k * 256 + t;
        cb[k] = 0xFFFFFFFFu;
        if (p < n) {
            int pi, pj; px_of(coords[p], pi, pj);
            u32 m = morton2(pi, pj);
            cb[k] = m >> 9;
            ent[k] = ((ull)__float_as_uint(depth[p]) << 32)
                   | ((ull)(m & 511u) << 21) | (ull)(u32)p;
            atomicAdd(&lhist[cb[k]], 1u);
        }
    }
    __syncthreads();
    u32 pv = lhist[2 * t] + lhist[2 * t + 1];
    temp[t] = pv; __syncthreads();
    for (int off = 1; off < 256; off <<= 1) {
        u32 x = temp[t]; u32 a = (t >= off) ? temp[t - off] : 0u;
        __syncthreads(); temp[t] = x + a; __syncthreads();
    }
    u32 pb = temp[t] - pv;
    lofs[2 * t] = pb;                  lofs[2 * t + 1] = pb + lhist[2 * t];
    lcur[2 * t] = pb;                  lcur[2 * t + 1] = pb + lhist[2 * t];
    __syncthreads();
#pragma unroll
    for (int k = 0; k < 16; ++k) {
        if (cb[k] != 0xFFFFFFFFu) {
            pos[k] = atomicAdd(&lcur[cb[k]], 1u);
            stage[pos[k]] = ent[k];
        }
    }
    __syncthreads();
    for (int b = t; b < NBUCK; b += 256) {
        u32 cnt = lhist[b];
        if (!cnt) continue;
        u32 gb = atomicAdd(&bucketCur[b], cnt);
        gbase[b] = gb;
        u32 lo = lofs[b];
        for (u32 i = 0; i < cnt; ++i) keys[gb + i] = stage[lo + i];
    }
    if (payg) {
        __syncthreads();
        u32* pstage = (u32*)stage;          // reuse staging LDS for payloads
#pragma unroll
        for (int k = 0; k < 16; ++k) {
            int p = base + k * 256 + t;
            if (cb[k] != 0xFFFFFFFFu) pstage[pos[k]] = __float_as_uint(pm[p]);
        }
        __syncthreads();
        for (int b = t; b < NBUCK; b += 256) {
            u32 cnt = lhist[b];
            if (!cnt) continue;
            u32 gb = gbase[b], lo = lofs[b];
            for (u32 i = 0; i < cnt; ++i) payg[gb + i] = pstage[lo + i];
        }
    }
}

// ---------- K2a: per-bucket cell histogram -> countsM ----------
__global__ __launch_bounds__(256)
void cell_hist_kernel(const ull* __restrict__ keys,
                      const u32* __restrict__ bucketStart,
                      u32* __restrict__ countsM) {
    __shared__ u32 lh[NBUCK];
    int b = blockIdx.x, t = threadIdx.x;
    for (int i = t; i < NBUCK; i += 256) lh[i] = 0;
    __syncthreads();
    u32 s = bucketStart[b], e = bucketStart[b + 1];
    for (u32 i = s + t; i < e; i += 256) {
        u32 mlow = (u32)(keys[i] >> 21) & 511u;
        atomicAdd(&lh[mlow], 1u);
    }
    __syncthreads();
    for (int i = t; i < NBUCK; i += 256) countsM[(b << 9) + i] = lh[i];
}

// ---------- scanA: countsM -> startsM ----------
__global__ __launch_bounds__(256)
void scanA_partial(const u32* __restrict__ countsM, u32* __restrict__ bsum) {
    int b = blockIdx.x, t = threadIdx.x;
    const uint4* src = (const uint4*)(countsM + b * 2048);
    uint4 a = src[t * 2], c = src[t * 2 + 1];
    u32 s = a.x + a.y + a.z + a.w + c.x + c.y + c.z + c.w;
    __shared__ u32 red[256];
    red[t] = s; __syncthreads();
    for (int off = 128; off; off >>= 1) {
        if (t < off) red[t] += red[t + off];
        __syncthreads();
    }
    if (!t) bsum[b] = red[0];
}

__global__ __launch_bounds__(128)
void scanA_bsum(const u32* __restrict__ bsum, u32* __restrict__ bpre,
                u32* __restrict__ startsM) {
    __shared__ u32 part[NBLK0];
    int t = threadIdx.x;
    u32 v = bsum[t];
    part[t] = v; __syncthreads();
    for (int off = 1; off < NBLK0; off <<= 1) {
        u32 x = part[t];
        u32 a = (t >= off) ? part[t - off] : 0;
        __syncthreads(); part[t] = x + a; __syncthreads();
    }
    bpre[t] = part[t] - v;
    if (t == NBLK0 - 1) startsM[N0] = part[t];   // sentinel = n
}

__global__ __launch_bounds__(256)
void scanA_final(const u32* __restrict__ countsM, const u32* __restrict__ bpre,
                 u32* __restrict__ startsM) {
    int b = blockIdx.x, t = threadIdx.x;
    const uint4* src = (const uint4*)(countsM + b * 2048);
    uint4 a = src[t * 2], c = src[t * 2 + 1];
    u32 e[8] = {a.x, a.y, a.z, a.w, c.x, c.y, c.z, c.w};
    u32 tsum = 0;
#pragma unroll
    for (int k = 0; k < 8; ++k) tsum += e[k];
    __shared__ u32 part[256];
    part[t] = tsum; __syncthreads();
    for (int off = 1; off < 256; off <<= 1) {
        u32 x = part[t];
        u32 ad = (t >= off) ? part[t - off] : 0;
        __syncthreads(); part[t] = x + ad; __syncthreads();
    }
    u32 run = bpre[b] + part[t] - tsum;
    u32 o[8];
#pragma unroll
    for (int k = 0; k < 8; ++k) { o[k] = run; run += e[k]; }
    uint4* d1 = (uint4*)(startsM + b * 2048);
    d1[t * 2]     = make_uint4(o[0], o[1], o[2], o[3]);
    d1[t * 2 + 1] = make_uint4(o[4], o[5], o[6], o[7]);
}

// ---------- K2b: in-place placement into exact cell slots (keys + payload) ----------
__global__ __launch_bounds__(256)
void place_kernel(ull* __restrict__ keys,
                  u32* __restrict__ payg,              // may be null
                  const u32* __restrict__ bucketStart,
                  const u32* __restrict__ startsM) {
    __shared__ ull stage[PLACE_CAP];
    __shared__ u32 pstage[PLACE_CAP];
    __shared__ u32 cur[NBUCK];
    int b = blockIdx.x, t = threadIdx.x;
    u32 s = bucketStart[b], e = bucketStart[b + 1];
    u32 cnt = e - s;
    u32 lim = cnt < PLACE_CAP ? cnt : PLACE_CAP;
    for (u32 i = t; i < lim; i += 256) stage[i] = keys[s + i];
    if (payg) for (u32 i = t; i < lim; i += 256) pstage[i] = payg[s + i];
    for (int i = t; i < NBUCK; i += 256) cur[i] = startsM[(b << 9) + i];
    __syncthreads();
    for (u32 i = t; i < lim; i += 256) {
        ull en = stage[i];
        u32 mlow = (u32)(en >> 21) & 511u;
        u32 slot = atomicAdd(&cur[mlow], 1u);
        keys[slot] = ((en >> 32) << 32) | (en & 0x1FFFFFull);
        if (payg) payg[slot] = pstage[i];
    }
}

// ---------- segid scans ----------
__device__ __forceinline__ void blk_map(int b, int& si, int& bb) {
    if (b < 128)      { si = 0; bb = b; }
    else if (b < 160) { si = 1; bb = b - 128; }
    else              { si = 2; bb = b - 160; }
}
__device__ __forceinline__ u32 cell_cnt(const u32* startsM, int c, int wbits, int si) {
    u32 ci = (u32)c >> wbits, cj = (u32)c & ((1u << wbits) - 1u);
    u32 mb = morton2(ci, cj) << (2 * si);
    return startsM[mb + (1u << (2 * si))] - startsM[mb];
}

__global__ __launch_bounds__(256)
void scanB_partial(const u32* __restrict__ startsM, u32* __restrict__ bsumB) {
    int si, bb; blk_map(blockIdx.x, si, bb);
    int wbits = 9 - si, t = threadIdx.x;
    int base = bb * 2048 + t * 8;
    u32 s = 0;
#pragma unroll
    for (int k = 0; k < 8; ++k)
        s += (cell_cnt(startsM, base + k, wbits, si) > 0) ? 1u : 0u;
    __shared__ u32 red[256];
    red[t] = s; __syncthreads();
    for (int off = 128; off; off >>= 1) {
        if (t < off) red[t] += red[t + off];
        __syncthreads();
    }
    if (!t) bsumB[blockIdx.x] = red[0];
}

__global__ __launch_bounds__(256)
void scanB_bsum(const u32* __restrict__ bsumB, u32* __restrict__ bpreB,
                u32* __restrict__ ncells) {
    __shared__ u32 part[256];
    int t = threadIdx.x;
    u32 v = (t < NBLKB) ? bsumB[t] : 0u;
    int rid = (t < 128) ? 0 : ((t < 160) ? 1 : 2);
    part[t] = v; __syncthreads();
    for (int off = 1; off < 256; off <<= 1) {
        u32 x = part[t];
        int tp = t - off;
        int ridp = (tp < 128) ? 0 : ((tp < 160) ? 1 : 2);
        u32 a = (tp >= 0 && ridp == rid) ? part[tp] : 0u;
        __syncthreads(); part[t] = x + a; __syncthreads();
    }
    if (t < NBLKB) bpreB[t] = part[t] - v;
    if (t == 127) ncells[0] = part[t];
    if (t == 159) ncells[1] = part[t];
    if (t == 167) ncells[2] = part[t];
}

struct SegArgs {
    u32* segid[3]; float* lens[3]; float* canvas[3];
};
__global__ __launch_bounds__(256)
void scanB_final(const u32* __restrict__ startsM, const u32* __restrict__ bpreB,
                 SegArgs sa) {
    int si, bb; blk_map(blockIdx.x, si, bb);
    int wbits = 9 - si, t = threadIdx.x;
    int base = bb * 2048 + t * 8;
    u32 cnt[8], flg[8], tsum = 0;
#pragma unroll
    for (int k = 0; k < 8; ++k) {
        cnt[k] = cell_cnt(startsM, base + k, wbits, si);
        flg[k] = cnt[k] ? 1u : 0u;
        tsum += flg[k];
    }
    __shared__ u32 part[256];
    part[t] = tsum; __syncthreads();
    for (int off = 1; off < 256; off <<= 1) {
        u32 x = part[t];
        u32 ad = (t >= off) ? part[t - off] : 0u;
        __syncthreads(); part[t] = x + ad; __syncthreads();
    }
    u32 run = bpreB[blockIdx.x] + part[t] - tsum;
    u32* segid = sa.segid[si];
    float* lens = sa.lens[si];
    float* canvas = sa.canvas[si];
    u32 wmask = (1u << wbits) - 1u;
#pragma unroll
    for (int k = 0; k < 8; ++k) {
        int c = base + k;
        segid[c] = run;
        if (flg[k]) {
            u32 s = run;
            u32 len = cnt[k] < MAX_RAY ? cnt[k] : MAX_RAY;
            lens[s] = (float)len;
            canvas[2 * s]     = (float)((u32)c >> wbits);
            canvas[2 * s + 1] = (float)((u32)c & wmask);
            run += 1;
        }
    }
}

// ---------- K5: emit — LDS-broadcast rank (4-wide), pipelined, coalesced out ----------
struct CellRegs { ull k0, k1, k2, k3; u32 p0, p1, p2, p3; };

__device__ __forceinline__ void loadCell(const ull* __restrict__ keys,
                                         const u32* __restrict__ payg,
                                         const float* __restrict__ pm,
                                         u32 s0, u32 cnt, u32 lane, CellRegs& c) {
    c.k0 = c.k1 = c.k2 = c.k3 = ~0ull;
    c.p0 = c.p1 = c.p2 = c.p3 = 0u;
    u32 m = lane * 4u;
    if (cnt == 0u || cnt > (u32)LKCAP || m >= cnt) return;
    struct __attribute__((packed, aligned(8))) U2 { ull x, y; };
    const U2* kp = (const U2*)(keys + s0 + m);
    U2 a = kp[0], b = kp[1];
    c.k0 = a.x; c.k1 = a.y; c.k2 = b.x; c.k3 = b.y;
    if (payg) {
        struct __attribute__((packed, aligned(4))) U4 { u32 x, y, z, w; };
        U4 pv = *(const U4*)(payg + s0 + m);
        c.p0 = pv.x; c.p1 = pv.y; c.p2 = pv.z; c.p3 = pv.w;
    } else {
        c.p0 = __float_as_uint(pm[(u32)(c.k0 & 0x1FFFFFull)]);
        if (m + 1 < cnt) c.p1 = __float_as_uint(pm[(u32)(c.k1 & 0x1FFFFFull)]);
        if (m + 2 < cnt) c.p2 = __float_as_uint(pm[(u32)(c.k2 & 0x1FFFFFull)]);
        if (m + 3 < cnt) c.p3 = __float_as_uint(pm[(u32)(c.k3 & 0x1FFFFFull)]);
    }
    if (m + 1 >= cnt) c.k1 = ~0ull;    // sentinel: never counts as "less"
    if (m + 2 >= cnt) c.k2 = ~0ull;
    if (m + 3 >= cnt) c.k3 = ~0ull;
}

struct EmitArgs {
    const u32* segid[3]; float* batch[3];
};
__global__ __launch_bounds__(256)
void emit_kernel(const float* __restrict__ pm,
                 const u32* __restrict__ payload,     // may be null -> gather pm by idx
                 const u32* __restrict__ startsM,
                 const ull* __restrict__ keys,
                 EmitArgs ea) {
    // heavy scale first: blocks [0,256)=si2, [256,1280)=si1, [1280,5376)=si0
    int b = blockIdx.x, si, bb;
    if (b < 256)       { si = 2; bb = b; }
    else if (b < 1280) { si = 1; bb = b - 256; }
    else               { si = 0; bb = b - 1280; }
    int wbits = 9 - si;
    int HW = 1 << (2 * wbits);
    const u32* segid = ea.segid[si];
    float* batch = ea.batch[si];

    __shared__ float tile[MAX_RAY][65];      // zeros synthesized on store, not memset
    __shared__ ull lk[4][LKCAP];             // per-wave -> NO barriers in cell loop
    __shared__ u32 s_s0[64], s_cnt[64], s_seg[64];

    int t = threadIdx.x, wave = t >> 6, lane = t & 63;
    int c0 = bb * 64;
    if (t < 64) {
        int cell = c0 + t;
        u32 ci = (u32)cell >> wbits, cj = (u32)cell & ((1u << wbits) - 1u);
        u32 mb = morton2(ci, cj) << (2 * si);
        u32 s0 = startsM[mb];
        s_s0[t]  = s0;
        s_cnt[t] = startsM[mb + (1u << (2 * si))] - s0;
        s_seg[t] = segid[cell];
    }
    __syncthreads();

    CellRegs cur, nxt;
    {
        int lc = wave * 16;
        loadCell(keys, payload, pm, s_s0[lc], s_cnt[lc], (u32)lane, cur);
    }
    for (int q = 0; q < 16; ++q) {
        int lc = wave * 16 + q;
        u32 cnt = s_cnt[lc], s0 = s_s0[lc];
        u32 m = (u32)lane * 4u;
        bool fits = (cnt <= (u32)LKCAP);
        // stage current cell's keys from regs to per-wave LDS
        if (fits && m < cnt) {
            ulonglong2 a; a.x = cur.k0; a.y = cur.k1;
            ulonglong2 bb2; bb2.x = cur.k2; bb2.y = cur.k3;
            *((ulonglong2*)&lk[wave][m])     = a;
            *((ulonglong2*)&lk[wave][m + 2]) = bb2;
        }
        // prefetch next cell into regs (hides global latency under rank VALU)
        if (q < 15) {
            int lc2 = lc + 1;
            loadCell(keys, payload, pm, s_s0[lc2], s_cnt[lc2], (u32)lane, nxt);
        }
        if (cnt) {
            if (fits) {
                asm volatile("s_waitcnt lgkmcnt(0)" ::: "memory");
                u32 cntR = (cnt + 3u) & ~3u;
                u32 r0 = 0, r1 = 0, r2 = 0, r3 = 0;
                for (u32 j = 0; j < cntR; j += 4) {
                    ulonglong2 a  = *((const ulonglong2*)&lk[wave][j]);      // uniform -> broadcast
                    ulonglong2 b2 = *((const ulonglong2*)&lk[wave][j + 2]);
                    r0 += (a.x < cur.k0) + (a.y < cur.k0) + (b2.x < cur.k0) + (b2.y < cur.k0);
                    r1 += (a.x < cur.k1) + (a.y < cur.k1) + (b2.x < cur.k1) + (b2.y < cur.k1);
                    r2 += (a.x < cur.k2) + (a.y < cur.k2) + (b2.x < cur.k2) + (b2.y < cur.k2);
                    r3 += (a.x < cur.k3) + (a.y < cur.k3) + (b2.x < cur.k3) + (b2.y < cur.k3);
                }
                if (m < cnt) {
                    if (r0 < MAX_RAY)                 tile[r0][lc] = __uint_as_float(cur.p0);
                    if (m + 1 < cnt && r1 < MAX_RAY)  tile[r1][lc] = __uint_as_float(cur.p1);
                    if (m + 2 < cnt && r2 < MAX_RAY)  tile[r2][lc] = __uint_as_float(cur.p2);
                    if (m + 3 < cnt && r3 < MAX_RAY)  tile[r3][lc] = __uint_as_float(cur.p3);
                }
            } else {   // pathological cell (statistically never): global all-pairs
                for (u32 i = lane; i < cnt; i += 64) {
                    ull mk = keys[s0 + i];
                    u32 r = 0;
                    for (u32 j = 0; j < cnt; ++j) r += (keys[s0 + j] < mk) ? 1u : 0u;
                    if (r < MAX_RAY) {
                        u32 pv = payload ? payload[s0 + i]
                                         : __float_as_uint(pm[(u32)(mk & 0x1FFFFFull)]);
                        tile[r][lc] = __uint_as_float(pv);
                    }
                }
            }
        }
        cur = nxt;
    }
    __syncthreads();

    u32 myCnt = s_cnt[lane], mySeg = s_seg[lane];
    u32 lim = myCnt < MAX_RAY ? myCnt : MAX_RAY;
    for (int r = wave; r < MAX_RAY; r += 4) {
        if (myCnt) batch[(size_t)r * (size_t)HW + mySeg] = (r < (int)lim) ? tile[r][lane] : 0.0f;
    }
}

// ---------- K6: zero the unoccupied-tail columns of batch ----------
__global__ __launch_bounds__(256)
void zero_tail_kernel(const u32* __restrict__ ncells,
                      float* __restrict__ b0, float* __restrict__ b1,
                      float* __restrict__ b2) {
    int b = blockIdx.x, si, col; float* base; int HW;
    if (b < 1024)      { si = 0; base = b0; HW = 262144; col = b * 256 + (int)threadIdx.x; }
    else if (b < 1280) { si = 1; base = b1; HW = 65536;  col = (b - 1024) * 256 + (int)threadIdx.x; }
    else               { si = 2; base = b2; HW = 16384;  col = (b - 1280) * 256 + (int)threadIdx.x; }
    if ((u32)col >= ncells[si]) {
        for (int r = 0; r < MAX_RAY; ++r)
            base[(size_t)r * (size_t)HW + col] = 0.0f;
    }
}

extern "C" void kernel_launch(void* const* d_in, const int* in_sizes, int n_in,
                              void* d_out, int out_size, void* d_ws, size_t ws_size,
                              hipStream_t stream) {
    const float2* coords = (const float2*)d_in[0];
    const float*  depth  = (const float*)d_in[1];
    const float*  pm     = (const float*)d_in[2];
    float* out = (float*)d_out;
    const int n = in_sizes[1];

    const int HWs[3] = {512 * 512, 256 * 256, 128 * 128};

    // ---- workspace (~27.6 MB with payload) ----
    char* ws = (char*)d_ws;
    size_t off = 0;
    ull* keys    = (ull*)(ws + off); off += (size_t)n * 8;
    u32* countsM = (u32*)(ws + off); off += (size_t)N0 * 4;
    u32* startsM = (u32*)(ws + off); off += (size_t)(N0 + 64) * 4;
    u32* segid[3];
    for (int i = 0; i < 3; ++i) { segid[i] = (u32*)(ws + off); off += (size_t)HWs[i] * 4; }
    u32* bsumA = (u32*)(ws + off); off += 256 * 4;
    u32* bpreA = (u32*)(ws + off); off += 256 * 4;
    u32* bsumB = (u32*)(ws + off); off += 256 * 4;
    u32* bpreB = (u32*)(ws + off); off += 256 * 4;
    u32* bucketCnt   = (u32*)(ws + off); off += NBUCK * 4;
    u32* bucketStart = (u32*)(ws + off); off += (NBUCK + 64) * 4;
    u32* bucketCur   = (u32*)(ws + off); off += NBUCK * 4;
    u32* ncells      = (u32*)(ws + off); off += 64 * 4;
    u32* payg        = (u32*)(ws + off);
    size_t needPay = off + (size_t)n * 4;
    if (ws_size < needPay) payg = nullptr;   // fallback: emit gathers pm by idx

    // ---- output offsets ----
    size_t offB[3], offL[3], offC[3];
    size_t o = 0;
    for (int i = 0; i < 3; ++i) { offB[i] = o; o += (size_t)MAX_RAY * HWs[i]; }
    for (int i = 0; i < 3; ++i) { offL[i] = o; o += (size_t)HWs[i]; }
    for (int i = 0; i < 3; ++i) { offC[i] = o; o += 2 * (size_t)HWs[i]; }

    hipMemsetAsync(out + offL[0], 0, (o - offL[0]) * sizeof(float), stream);
    hipMemsetAsync(bucketCnt, 0, NBUCK * 4, stream);

    const int nblkPts = (n + PTS_PER_BLK - 1) / PTS_PER_BLK;

    bucket_hist_kernel<<<nblkPts, 256, 0, stream>>>(coords, bucketCnt, n);
    bucket_scan_kernel<<<1, NBUCK, 0, stream>>>(bucketCnt, bucketStart, bucketCur, n);
    bucket_scatter_kernel<<<nblkPts, 256, 0, stream>>>(coords, depth, pm, bucketCur,
                                                       keys, payg, n);
    cell_hist_kernel<<<NBUCK, 256, 0, stream>>>(keys, bucketStart, countsM);
    scanA_partial<<<NBLK0, 256, 0, stream>>>(countsM, bsumA);
    scanA_bsum<<<1, NBLK0, 0, stream>>>(bsumA, bpreA, startsM);
    scanA_final<<<NBLK0, 256, 0, stream>>>(countsM, bpreA, startsM);
    place_kernel<<<NBUCK, 256, 0, stream>>>(keys, payg, bucketStart, startsM);

    SegArgs sa;
    for (int i = 0; i < 3; ++i) {
        sa.segid[i]  = segid[i];
        sa.lens[i]   = out + offL[i];
        sa.canvas[i] = out + offC[i];
    }
    scanB_partial<<<NBLKB, 256, 0, stream>>>(startsM, bsumB);
    scanB_bsum<<<1, 256, 0, stream>>>(bsumB, bpreB, ncells);
    scanB_final<<<NBLKB, 256, 0, stream>>>(startsM, bpreB, sa);

    EmitArgs ea;
    for (int i = 0; i < 3; ++i) {
        ea.segid[i] = segid[i];
        ea.batch[i] = out + offB[i];
    }
    emit_kernel<<<5376, 256, 0, stream>>>(pm, payg, startsM, keys, ea);
    zero_tail_kernel<<<1344, 256, 0, stream>>>(ncells, out + offB[0],
                                               out + offB[1], out + offB[2]);
}

// Round 9
// 194.945 us; speedup vs baseline: 2.9932x; 1.4963x over previous
//
#include <hip/hip_runtime.h>
#include <stdint.h>

#define MAX_RAY 100
#define NBUCK 512          // coarse buckets = top 9 Morton bits
#define PTS_PER_BLK 4096
#define PLACE_CAP 5120     // bucket mean 3906, sigma ~62
typedef unsigned long long ull;
typedef uint32_t u32;

#define N0 262144          // finest cells
#define NBLK0 128          // N0 / 2048
#define NBLKB 168          // 128 + 32 + 8 segid-scan blocks (2048 cells each)

// per-wave LDS key pool: max over scales of NG*STRIDE = 8*34=272 (si0)
#define LKELEMS 272

// ---------- helpers ----------
__device__ __forceinline__ u32 spread1(u32 v) {
    v &= 0x1FF;
    v = (v | (v << 8)) & 0x00FF00FF;
    v = (v | (v << 4)) & 0x0F0F0F0F;
    v = (v | (v << 2)) & 0x33333333;
    v = (v | (v << 1)) & 0x55555555;
    return v;
}
__device__ __forceinline__ u32 morton2(u32 i, u32 j) { return (spread1(i) << 1) | spread1(j); }

__device__ __forceinline__ void px_of(const float2 cv, int& pi, int& pj) {
    float fi = fminf(fmaxf(cv.x * 512.0f, 0.0f), 511.0f);
    float fj = fminf(fmaxf(cv.y * 512.0f, 0.0f), 511.0f);
    pi = (int)fi;   // trunc == floor for non-negative; bit-identical to reference
    pj = (int)fj;
}

// ---------- K0: bucket-level histogram (LDS-staged) ----------
__global__ __launch_bounds__(256)
void bucket_hist_kernel(const float2* __restrict__ coords,
                        u32* __restrict__ bucketCnt, int n) {
    __shared__ u32 lh[NBUCK];
    int t = threadIdx.x;
    for (int i = t; i < NBUCK; i += 256) lh[i] = 0;
    __syncthreads();
    int base = blockIdx.x * PTS_PER_BLK;
#pragma unroll
    for (int k = 0; k < 16; ++k) {
        int p = base + k * 256 + t;
        if (p < n) {
            int pi, pj; px_of(coords[p], pi, pj);
            atomicAdd(&lh[morton2(pi, pj) >> 9], 1u);
        }
    }
    __syncthreads();
    for (int i = t; i < NBUCK; i += 256)
        if (lh[i]) atomicAdd(&bucketCnt[i], lh[i]);
}

// ---------- K0b: scan 512 bucket counts -> start + cursor ----------
__global__ __launch_bounds__(NBUCK)
void bucket_scan_kernel(const u32* __restrict__ bucketCnt,
                        u32* __restrict__ bucketStart,
                        u32* __restrict__ bucketCur, int n) {
    __shared__ u32 part[NBUCK];
    int t = threadIdx.x;
    u32 v = bucketCnt[t];
    part[t] = v; __syncthreads();
    for (int off = 1; off < NBUCK; off <<= 1) {
        u32 x = part[t]; u32 a = (t >= off) ? part[t - off] : 0u;
        __syncthreads(); part[t] = x + a; __syncthreads();
    }
    u32 ex = part[t] - v;
    bucketStart[t] = ex; bucketCur[t] = ex;
    if (t == NBUCK - 1) bucketStart[NBUCK] = (u32)n;
}

// ---------- K1: block-local counting sort by bucket; flush keys (+payload) ----------
// entry = depth(32) | mlow(9) | idx(21)
__global__ __launch_bounds__(256)
void bucket_scatter_kernel(const float2* __restrict__ coords,
                           const float* __restrict__ depth,
                           const float* __restrict__ pm,
                           u32* __restrict__ bucketCur,
                           ull* __restrict__ keys,
                           u32* __restrict__ payg,     // may be null
                           int n) {
    __shared__ u32 lhist[NBUCK], lofs[NBUCK], lcur[NBUCK], gbase[NBUCK], temp[256];
    __shared__ ull stage[PTS_PER_BLK];
    int t = threadIdx.x;
    for (int i = t; i < NBUCK; i += 256) lhist[i] = 0;
    __syncthreads();
    int base = blockIdx.x * PTS_PER_BLK;
    ull ent[16]; u32 cb[16]; u32 pos[16];
#pragma unroll
    for (int k = 0; k < 16; ++k) {
        int p = base + k * 256 + t;
        cb[k] = 0xFFFFFFFFu;
        if (p < n) {
            int pi, pj; px_of(coords[p], pi, pj);
            u32 m = morton2(pi, pj);
            cb[k] = m >> 9;
            ent[k] = ((ull)__float_as_uint(depth[p]) << 32)
                   | ((ull)(m & 511u) << 21) | (ull)(u32)p;
            atomicAdd(&lhist[cb[k]], 1u);
        }
    }
    __syncthreads();
    u32 pv = lhist[2 * t] + lhist[2 * t + 1];
    temp[t] = pv; __syncthreads();
    for (int off = 1; off < 256; off <<= 1) {
        u32 x = temp[t]; u32 a = (t >= off) ? temp[t - off] : 0u;
        __syncthreads(); temp[t] = x + a; __syncthreads();
    }
    u32 pb = temp[t] - pv;
    lofs[2 * t] = pb;                  lofs[2 * t + 1] = pb + lhist[2 * t];
    lcur[2 * t] = pb;                  lcur[2 * t + 1] = pb + lhist[2 * t];
    __syncthreads();
#pragma unroll
    for (int k = 0; k < 16; ++k) {
        if (cb[k] != 0xFFFFFFFFu) {
            pos[k] = atomicAdd(&lcur[cb[k]], 1u);
            stage[pos[k]] = ent[k];
        }
    }
    __syncthreads();
    for (int b = t; b < NBUCK; b += 256) {
        u32 cnt = lhist[b];
        if (!cnt) continue;
        u32 gb = atomicAdd(&bucketCur[b], cnt);
        gbase[b] = gb;
        u32 lo = lofs[b];
        for (u32 i = 0; i < cnt; ++i) keys[gb + i] = stage[lo + i];
    }
    if (payg) {
        __syncthreads();
        u32* pstage = (u32*)stage;          // reuse staging LDS for payloads
#pragma unroll
        for (int k = 0; k < 16; ++k) {
            int p = base + k * 256 + t;
            if (cb[k] != 0xFFFFFFFFu) pstage[pos[k]] = __float_as_uint(pm[p]);
        }
        __syncthreads();
        for (int b = t; b < NBUCK; b += 256) {
            u32 cnt = lhist[b];
            if (!cnt) continue;
            u32 gb = gbase[b], lo = lofs[b];
            for (u32 i = 0; i < cnt; ++i) payg[gb + i] = pstage[lo + i];
        }
    }
}

// ---------- K2a: per-bucket cell histogram -> countsM ----------
__global__ __launch_bounds__(256)
void cell_hist_kernel(const ull* __restrict__ keys,
                      const u32* __restrict__ bucketStart,
                      u32* __restrict__ countsM) {
    __shared__ u32 lh[NBUCK];
    int b = blockIdx.x, t = threadIdx.x;
    for (int i = t; i < NBUCK; i += 256) lh[i] = 0;
    __syncthreads();
    u32 s = bucketStart[b], e = bucketStart[b + 1];
    for (u32 i = s + t; i < e; i += 256) {
        u32 mlow = (u32)(keys[i] >> 21) & 511u;
        atomicAdd(&lh[mlow], 1u);
    }
    __syncthreads();
    for (int i = t; i < NBUCK; i += 256) countsM[(b << 9) + i] = lh[i];
}

// ---------- scanA: countsM -> startsM ----------
__global__ __launch_bounds__(256)
void scanA_partial(const u32* __restrict__ countsM, u32* __restrict__ bsum) {
    int b = blockIdx.x, t = threadIdx.x;
    const uint4* src = (const uint4*)(countsM + b * 2048);
    uint4 a = src[t * 2], c = src[t * 2 + 1];
    u32 s = a.x + a.y + a.z + a.w + c.x + c.y + c.z + c.w;
    __shared__ u32 red[256];
    red[t] = s; __syncthreads();
    for (int off = 128; off; off >>= 1) {
        if (t < off) red[t] += red[t + off];
        __syncthreads();
    }
    if (!t) bsum[b] = red[0];
}

__global__ __launch_bounds__(128)
void scanA_bsum(const u32* __restrict__ bsum, u32* __restrict__ bpre,
                u32* __restrict__ startsM) {
    __shared__ u32 part[NBLK0];
    int t = threadIdx.x;
    u32 v = bsum[t];
    part[t] = v; __syncthreads();
    for (int off = 1; off < NBLK0; off <<= 1) {
        u32 x = part[t];
        u32 a = (t >= off) ? part[t - off] : 0;
        __syncthreads(); part[t] = x + a; __syncthreads();
    }
    bpre[t] = part[t] - v;
    if (t == NBLK0 - 1) startsM[N0] = part[t];   // sentinel = n
}

__global__ __launch_bounds__(256)
void scanA_final(const u32* __restrict__ countsM, const u32* __restrict__ bpre,
                 u32* __restrict__ startsM) {
    int b = blockIdx.x, t = threadIdx.x;
    const uint4* src = (const uint4*)(countsM + b * 2048);
    uint4 a = src[t * 2], c = src[t * 2 + 1];
    u32 e[8] = {a.x, a.y, a.z, a.w, c.x, c.y, c.z, c.w};
    u32 tsum = 0;
#pragma unroll
    for (int k = 0; k < 8; ++k) tsum += e[k];
    __shared__ u32 part[256];
    part[t] = tsum; __syncthreads();
    for (int off = 1; off < 256; off <<= 1) {
        u32 x = part[t];
        u32 ad = (t >= off) ? part[t - off] : 0;
        __syncthreads(); part[t] = x + ad; __syncthreads();
    }
    u32 run = bpre[b] + part[t] - tsum;
    u32 o[8];
#pragma unroll
    for (int k = 0; k < 8; ++k) { o[k] = run; run += e[k]; }
    uint4* d1 = (uint4*)(startsM + b * 2048);
    d1[t * 2]     = make_uint4(o[0], o[1], o[2], o[3]);
    d1[t * 2 + 1] = make_uint4(o[4], o[5], o[6], o[7]);
}

// ---------- K2b: in-place placement into exact cell slots (keys + payload) ----------
__global__ __launch_bounds__(256)
void place_kernel(ull* __restrict__ keys,
                  u32* __restrict__ payg,              // may be null
                  const u32* __restrict__ bucketStart,
                  const u32* __restrict__ startsM) {
    __shared__ ull stage[PLACE_CAP];
    __shared__ u32 pstage[PLACE_CAP];
    __shared__ u32 cur[NBUCK];
    int b = blockIdx.x, t = threadIdx.x;
    u32 s = bucketStart[b], e = bucketStart[b + 1];
    u32 cnt = e - s;
    u32 lim = cnt < PLACE_CAP ? cnt : PLACE_CAP;
    for (u32 i = t; i < lim; i += 256) stage[i] = keys[s + i];
    if (payg) for (u32 i = t; i < lim; i += 256) pstage[i] = payg[s + i];
    for (int i = t; i < NBUCK; i += 256) cur[i] = startsM[(b << 9) + i];
    __syncthreads();
    for (u32 i = t; i < lim; i += 256) {
        ull en = stage[i];
        u32 mlow = (u32)(en >> 21) & 511u;
        u32 slot = atomicAdd(&cur[mlow], 1u);
        keys[slot] = ((en >> 32) << 32) | (en & 0x1FFFFFull);
        if (payg) payg[slot] = pstage[i];
    }
}

// ---------- segid scans ----------
__device__ __forceinline__ void blk_map(int b, int& si, int& bb) {
    if (b < 128)      { si = 0; bb = b; }
    else if (b < 160) { si = 1; bb = b - 128; }
    else              { si = 2; bb = b - 160; }
}
__device__ __forceinline__ u32 cell_cnt(const u32* startsM, int c, int wbits, int si) {
    u32 ci = (u32)c >> wbits, cj = (u32)c & ((1u << wbits) - 1u);
    u32 mb = morton2(ci, cj) << (2 * si);
    return startsM[mb + (1u << (2 * si))] - startsM[mb];
}

__global__ __launch_bounds__(256)
void scanB_partial(const u32* __restrict__ startsM, u32* __restrict__ bsumB) {
    int si, bb; blk_map(blockIdx.x, si, bb);
    int wbits = 9 - si, t = threadIdx.x;
    int base = bb * 2048 + t * 8;
    u32 s = 0;
#pragma unroll
    for (int k = 0; k < 8; ++k)
        s += (cell_cnt(startsM, base + k, wbits, si) > 0) ? 1u : 0u;
    __shared__ u32 red[256];
    red[t] = s; __syncthreads();
    for (int off = 128; off; off >>= 1) {
        if (t < off) red[t] += red[t + off];
        __syncthreads();
    }
    if (!t) bsumB[blockIdx.x] = red[0];
}

__global__ __launch_bounds__(256)
void scanB_bsum(const u32* __restrict__ bsumB, u32* __restrict__ bpreB,
                u32* __restrict__ ncells) {
    __shared__ u32 part[256];
    int t = threadIdx.x;
    u32 v = (t < NBLKB) ? bsumB[t] : 0u;
    int rid = (t < 128) ? 0 : ((t < 160) ? 1 : 2);
    part[t] = v; __syncthreads();
    for (int off = 1; off < 256; off <<= 1) {
        u32 x = part[t];
        int tp = t - off;
        int ridp = (tp < 128) ? 0 : ((tp < 160) ? 1 : 2);
        u32 a = (tp >= 0 && ridp == rid) ? part[tp] : 0u;
        __syncthreads(); part[t] = x + a; __syncthreads();
    }
    if (t < NBLKB) bpreB[t] = part[t] - v;
    if (t == 127) ncells[0] = part[t];
    if (t == 159) ncells[1] = part[t];
    if (t == 167) ncells[2] = part[t];
}

struct SegArgs {
    u32* segid[3]; float* lens[3]; float* canvas[3];
};
__global__ __launch_bounds__(256)
void scanB_final(const u32* __restrict__ startsM, const u32* __restrict__ bpreB,
                 SegArgs sa) {
    int si, bb; blk_map(blockIdx.x, si, bb);
    int wbits = 9 - si, t = threadIdx.x;
    int base = bb * 2048 + t * 8;
    u32 cnt[8], flg[8], tsum = 0;
#pragma unroll
    for (int k = 0; k < 8; ++k) {
        cnt[k] = cell_cnt(startsM, base + k, wbits, si);
        flg[k] = cnt[k] ? 1u : 0u;
        tsum += flg[k];
    }
    __shared__ u32 part[256];
    part[t] = tsum; __syncthreads();
    for (int off = 1; off < 256; off <<= 1) {
        u32 x = part[t];
        u32 ad = (t >= off) ? part[t - off] : 0u;
        __syncthreads(); part[t] = x + ad; __syncthreads();
    }
    u32 run = bpreB[blockIdx.x] + part[t] - tsum;
    u32* segid = sa.segid[si];
    float* lens = sa.lens[si];
    float* canvas = sa.canvas[si];
    u32 wmask = (1u << wbits) - 1u;
#pragma unroll
    for (int k = 0; k < 8; ++k) {
        int c = base + k;
        segid[c] = run;
        if (flg[k]) {
            u32 s = run;
            u32 len = cnt[k] < MAX_RAY ? cnt[k] : MAX_RAY;
            lens[s] = (float)len;
            canvas[2 * s]     = (float)((u32)c >> wbits);
            canvas[2 * s + 1] = (float)((u32)c & wmask);
            run += 1;
        }
    }
}

// ---------- K5: emit — grouped LDS-broadcast rank, coalesced full-coverage out ----------
struct CellRegs { ull k0, k1, k2, k3; u32 p0, p1, p2, p3; };
struct __attribute__((packed, aligned(8))) U2 { ull x, y; };
struct __attribute__((packed, aligned(4))) U4 { u32 x, y, z, w; };

template<int CAP>
__device__ __forceinline__ void loadCellG(const ull* __restrict__ keys,
                                          const u32* __restrict__ payg,
                                          const float* __restrict__ pm,
                                          u32 s0, u32 cnt, u32 li, CellRegs& c) {
    c.k0 = c.k1 = c.k2 = c.k3 = ~0ull;
    c.p0 = c.p1 = c.p2 = c.p3 = 0u;
    u32 m = li * 4u;
    if (cnt == 0u || cnt > (u32)CAP || m >= cnt) return;
    const U2* kp = (const U2*)(keys + s0 + m);
    U2 a = kp[0], b = kp[1];
    c.k0 = a.x; c.k1 = a.y; c.k2 = b.x; c.k3 = b.y;
    if (payg) {
        U4 pv = *(const U4*)(payg + s0 + m);
        c.p0 = pv.x; c.p1 = pv.y; c.p2 = pv.z; c.p3 = pv.w;
    } else {
        c.p0 = __float_as_uint(pm[(u32)(c.k0 & 0x1FFFFFull)]);
        if (m + 1 < cnt) c.p1 = __float_as_uint(pm[(u32)(c.k1 & 0x1FFFFFull)]);
        if (m + 2 < cnt) c.p2 = __float_as_uint(pm[(u32)(c.k2 & 0x1FFFFFull)]);
        if (m + 3 < cnt) c.p3 = __float_as_uint(pm[(u32)(c.k3 & 0x1FFFFFull)]);
    }
    if (m + 1 >= cnt) c.k1 = ~0ull;    // sentinel: never counts as "less"
    if (m + 2 >= cnt) c.k2 = ~0ull;
    if (m + 3 >= cnt) c.k3 = ~0ull;
}

template<int SI>
__device__ __forceinline__ void emit_body(
    const float* __restrict__ pm, const u32* __restrict__ payload,
    const u32* __restrict__ startsM, const ull* __restrict__ keys,
    const u32* __restrict__ segid, float* __restrict__ batch, int bb,
    float (&tile)[MAX_RAY][65], ull (&lkAll)[4][LKELEMS],
    u32 (&s_s0)[64], u32 (&s_cnt)[64], u32 (&s_seg)[64],
    u32 (&ovfl)[64], u32& ovflN)
{
    constexpr int WB   = 9 - SI;
    constexpr int G    = (SI == 0) ? 8 : (SI == 1) ? 16 : 64;   // lanes per cell
    constexpr int CAP  = G * 4;                                  // keys per cell
    constexpr int STRD = (SI == 0) ? 34 : (SI == 1) ? 66 : 256;  // padded stride (elems)
    constexpr int NG   = 64 / G;                                 // groups per wave
    constexpr int ROUNDS = 64 / (4 * NG);
    const int HW = 1 << (2 * WB);

    int t = threadIdx.x, wave = t >> 6, lane = t & 63;
    int gi = lane / G, li = lane % G;
    ull* lk = &lkAll[wave][0];

    if (t == 0) ovflN = 0;
    if (t < 64) {
        int cell = bb * 64 + t;
        u32 ci = (u32)cell >> WB, cj = (u32)cell & ((1u << WB) - 1u);
        u32 mb = morton2(ci, cj) << (2 * SI);
        u32 s0 = startsM[mb];
        s_s0[t]  = s0;
        s_cnt[t] = startsM[mb + (1u << (2 * SI))] - s0;
        s_seg[t] = segid[cell];
    }
    __syncthreads();

    CellRegs cur, nxt;
    {
        int lc0 = wave * NG + gi;
        loadCellG<CAP>(keys, payload, pm, s_s0[lc0], s_cnt[lc0], (u32)li, cur);
    }
#pragma unroll
    for (int rnd = 0; rnd < ROUNDS; ++rnd) {
        int lc = (rnd * 4 + wave) * NG + gi;
        u32 cnt = s_cnt[lc], m = (u32)li * 4u;
        bool fits = (cnt <= (u32)CAP);
        if (fits && m < cnt) {                 // stage keys to this group's LDS region
            ull* dst = lk + gi * STRD + m;
            dst[0] = cur.k0; dst[1] = cur.k1; dst[2] = cur.k2; dst[3] = cur.k3;
        }
        if (!fits && li == 0) {                // rare: defer to whole-wave pass
            u32 ix = atomicAdd(&ovflN, 1u);
            ovfl[ix] = (u32)lc;
        }
        if (rnd + 1 < ROUNDS) {                // prefetch next cell (hides latency)
            int lc2 = ((rnd + 1) * 4 + wave) * NG + gi;
            loadCellG<CAP>(keys, payload, pm, s_s0[lc2], s_cnt[lc2], (u32)li, nxt);
        }
        if (cnt && fits) {
            asm volatile("s_waitcnt lgkmcnt(0)" ::: "memory");
            u32 cntR = (cnt + 3u) & ~3u;
            u32 r0 = 0, r1 = 0, r2 = 0, r3 = 0;
            const ull* kb = lk + gi * STRD;
            for (u32 j = 0; j < cntR; j += 4) {
                U2 a  = *(const U2*)(kb + j);        // group-uniform -> broadcast/bank-split
                U2 b2 = *(const U2*)(kb + j + 2);
                r0 += (a.x < cur.k0) + (a.y < cur.k0) + (b2.x < cur.k0) + (b2.y < cur.k0);
                r1 += (a.x < cur.k1) + (a.y < cur.k1) + (b2.x < cur.k1) + (b2.y < cur.k1);
                r2 += (a.x < cur.k2) + (a.y < cur.k2) + (b2.x < cur.k2) + (b2.y < cur.k2);
                r3 += (a.x < cur.k3) + (a.y < cur.k3) + (b2.x < cur.k3) + (b2.y < cur.k3);
            }
            if (m < cnt) {
                if (r0 < MAX_RAY)                 tile[r0][lc] = __uint_as_float(cur.p0);
                if (m + 1 < cnt && r1 < MAX_RAY)  tile[r1][lc] = __uint_as_float(cur.p1);
                if (m + 2 < cnt && r2 < MAX_RAY)  tile[r2][lc] = __uint_as_float(cur.p2);
                if (m + 3 < cnt && r3 < MAX_RAY)  tile[r3][lc] = __uint_as_float(cur.p3);
            }
        }
        cur = nxt;
    }
    __syncthreads();

    // whole-wave fallback for overflow cells (statistically ~never)
    u32 no = ovflN;
    if (no && wave == 0) {
        for (u32 o = 0; o < no; ++o) {
            int lc = (int)ovfl[o];
            u32 s0 = s_s0[lc], cnt = s_cnt[lc];
            for (u32 i = lane; i < cnt; i += 64) {
                ull mk = keys[s0 + i];
                u32 r = 0;
                for (u32 j = 0; j < cnt; ++j) r += (keys[s0 + j] < mk) ? 1u : 0u;
                if (r < MAX_RAY) {
                    u32 pv = payload ? payload[s0 + i]
                                     : __float_as_uint(pm[(u32)(mk & 0x1FFFFFull)]);
                    tile[r][lc] = __uint_as_float(pv);
                }
            }
        }
    }
    __syncthreads();

    u32 myCnt = s_cnt[lane], mySeg = s_seg[lane];
    u32 lim = myCnt < MAX_RAY ? myCnt : MAX_RAY;
    for (int r = wave; r < MAX_RAY; r += 4) {
        if (myCnt) batch[(size_t)r * (size_t)HW + mySeg] = (r < (int)lim) ? tile[r][lane] : 0.0f;
    }
}

struct EmitArgs {
    const u32* segid[3]; float* batch[3];
};
__global__ __launch_bounds__(256)
void emit_kernel(const float* __restrict__ pm,
                 const u32* __restrict__ payload,
                 const u32* __restrict__ startsM,
                 const ull* __restrict__ keys,
                 EmitArgs ea) {
    __shared__ float tile[MAX_RAY][65];
    __shared__ __align__(16) ull lkAll[4][LKELEMS];
    __shared__ u32 s_s0[64], s_cnt[64], s_seg[64], ovfl[64], ovflN;

    // heavy scale first: [0,256)=si2, [256,1280)=si1, [1280,5376)=si0
    int b = blockIdx.x;
    if (b < 256)
        emit_body<2>(pm, payload, startsM, keys, ea.segid[2], ea.batch[2], b,
                     tile, lkAll, s_s0, s_cnt, s_seg, ovfl, ovflN);
    else if (b < 1280)
        emit_body<1>(pm, payload, startsM, keys, ea.segid[1], ea.batch[1], b - 256,
                     tile, lkAll, s_s0, s_cnt, s_seg, ovfl, ovflN);
    else
        emit_body<0>(pm, payload, startsM, keys, ea.segid[0], ea.batch[0], b - 1280,
                     tile, lkAll, s_s0, s_cnt, s_seg, ovfl, ovflN);
}

// ---------- K6: zero tails of batch + lens + canvas (replaces output memset) ----------
__global__ __launch_bounds__(256)
void zero_tail_kernel(const u32* __restrict__ ncells,
                      float* __restrict__ b0, float* __restrict__ b1,
                      float* __restrict__ b2,
                      float* __restrict__ l0, float* __restrict__ l1,
                      float* __restrict__ l2,
                      float* __restrict__ c0, float* __restrict__ c1,
                      float* __restrict__ c2) {
    int b = blockIdx.x, si, col; float* base; float* lens; float* canv; int HW;
    if (b < 1024)      { si = 0; base = b0; lens = l0; canv = c0; HW = 262144; col = b * 256 + (int)threadIdx.x; }
    else if (b < 1280) { si = 1; base = b1; lens = l1; canv = c1; HW = 65536;  col = (b - 1024) * 256 + (int)threadIdx.x; }
    else               { si = 2; base = b2; lens = l2; canv = c2; HW = 16384;  col = (b - 1280) * 256 + (int)threadIdx.x; }
    if ((u32)col >= ncells[si]) {
        lens[col] = 0.0f;
        canv[2 * col] = 0.0f; canv[2 * col + 1] = 0.0f;
        for (int r = 0; r < MAX_RAY; ++r)
            base[(size_t)r * (size_t)HW + col] = 0.0f;
    }
}

extern "C" void kernel_launch(void* const* d_in, const int* in_sizes, int n_in,
                              void* d_out, int out_size, void* d_ws, size_t ws_size,
                              hipStream_t stream) {
    const float2* coords = (const float2*)d_in[0];
    const float*  depth  = (const float*)d_in[1];
    const float*  pm     = (const float*)d_in[2];
    float* out = (float*)d_out;
    const int n = in_sizes[1];

    const int HWs[3] = {512 * 512, 256 * 256, 128 * 128};

    // ---- workspace (~27.6 MB with payload) ----
    char* ws = (char*)d_ws;
    size_t off = 0;
    ull* keys    = (ull*)(ws + off); off += (size_t)n * 8;
    u32* countsM = (u32*)(ws + off); off += (size_t)N0 * 4;
    u32* startsM = (u32*)(ws + off); off += (size_t)(N0 + 64) * 4;
    u32* segid[3];
    for (int i = 0; i < 3; ++i) { segid[i] = (u32*)(ws + off); off += (size_t)HWs[i] * 4; }
    u32* bsumA = (u32*)(ws + off); off += 256 * 4;
    u32* bpreA = (u32*)(ws + off); off += 256 * 4;
    u32* bsumB = (u32*)(ws + off); off += 256 * 4;
    u32* bpreB = (u32*)(ws + off); off += 256 * 4;
    u32* bucketCnt   = (u32*)(ws + off); off += NBUCK * 4;
    u32* bucketStart = (u32*)(ws + off); off += (NBUCK + 64) * 4;
    u32* bucketCur   = (u32*)(ws + off); off += NBUCK * 4;
    u32* ncells      = (u32*)(ws + off); off += 64 * 4;
    u32* payg        = (u32*)(ws + off);
    size_t needPay = off + (size_t)n * 4;
    if (ws_size < needPay) payg = nullptr;   // fallback: emit gathers pm by idx

    // ---- output offsets ----
    size_t offB[3], offL[3], offC[3];
    size_t o = 0;
    for (int i = 0; i < 3; ++i) { offB[i] = o; o += (size_t)MAX_RAY * HWs[i]; }
    for (int i = 0; i < 3; ++i) { offL[i] = o; o += (size_t)HWs[i]; }
    for (int i = 0; i < 3; ++i) { offC[i] = o; o += 2 * (size_t)HWs[i]; }

    hipMemsetAsync(bucketCnt, 0, NBUCK * 4, stream);

    const int nblkPts = (n + PTS_PER_BLK - 1) / PTS_PER_BLK;

    bucket_hist_kernel<<<nblkPts, 256, 0, stream>>>(coords, bucketCnt, n);
    bucket_scan_kernel<<<1, NBUCK, 0, stream>>>(bucketCnt, bucketStart, bucketCur, n);
    bucket_scatter_kernel<<<nblkPts, 256, 0, stream>>>(coords, depth, pm, bucketCur,
                                                       keys, payg, n);
    cell_hist_kernel<<<NBUCK, 256, 0, stream>>>(keys, bucketStart, countsM);
    scanA_partial<<<NBLK0, 256, 0, stream>>>(countsM, bsumA);
    scanA_bsum<<<1, NBLK0, 0, stream>>>(bsumA, bpreA, startsM);
    scanA_final<<<NBLK0, 256, 0, stream>>>(countsM, bpreA, startsM);
    place_kernel<<<NBUCK, 256, 0, stream>>>(keys, payg, bucketStart, startsM);

    SegArgs sa;
    for (int i = 0; i < 3; ++i) {
        sa.segid[i]  = segid[i];
        sa.lens[i]   = out + offL[i];
        sa.canvas[i] = out + offC[i];
    }
    scanB_partial<<<NBLKB, 256, 0, stream>>>(startsM, bsumB);
    scanB_bsum<<<1, 256, 0, stream>>>(bsumB, bpreB, ncells);
    scanB_final<<<NBLKB, 256, 0, stream>>>(startsM, bpreB, sa);

    EmitArgs ea;
    for (int i = 0; i < 3; ++i) {
        ea.segid[i] = segid[i];
        ea.batch[i] = out + offB[i];
    }
    emit_kernel<<<5376, 256, 0, stream>>>(pm, payg, startsM, keys, ea);
    zero_tail_kernel<<<1344, 256, 0, stream>>>(ncells,
        out + offB[0], out + offB[1], out + offB[2],
        out + offL[0], out + offL[1], out + offL[2],
        out + offC[0], out + offC[1], out + offC[2]);
}

// Round 10
// 188.474 us; speedup vs baseline: 3.0959x; 1.0343x over previous
//
#include <hip/hip_runtime.h>
#include <stdint.h>

#define MAX_RAY 100
#define NBUCK 512          // coarse buckets = top 9 Morton bits
#define PTS_PER_BLK 4096
#define PLACE_CAP 5120     // old-path LDS stage cap
#define CAPB 5120          // staging region capacity per bucket (mean 3906, sigma 62 -> 19 sigma)
typedef unsigned long long ull;
typedef uint32_t u32;

#define N0 262144          // finest cells
#define NBLK0 128          // N0 / 2048
#define NBLKB 168          // 128 + 32 + 8 segid-scan blocks (2048 cells each)
#define LKELEMS 272        // per-wave LDS key pool (emit)

// ---------- helpers ----------
__device__ __forceinline__ u32 spread1(u32 v) {
    v &= 0x1FF;
    v = (v | (v << 8)) & 0x00FF00FF;
    v = (v | (v << 4)) & 0x0F0F0F0F;
    v = (v | (v << 2)) & 0x33333333;
    v = (v | (v << 1)) & 0x55555555;
    return v;
}
__device__ __forceinline__ u32 morton2(u32 i, u32 j) { return (spread1(i) << 1) | spread1(j); }

__device__ __forceinline__ void px_of(const float2 cv, int& pi, int& pj) {
    float fi = fminf(fmaxf(cv.x * 512.0f, 0.0f), 511.0f);
    float fj = fminf(fmaxf(cv.y * 512.0f, 0.0f), 511.0f);
    pi = (int)fi;   // trunc == floor for non-negative; bit-identical to reference
    pj = (int)fj;
}

// ================= OLD PATH (fallback when ws too small) =================
__global__ __launch_bounds__(256)
void bucket_hist_kernel(const float2* __restrict__ coords,
                        u32* __restrict__ bucketCnt, int n) {
    __shared__ u32 lh[NBUCK];
    int t = threadIdx.x;
    for (int i = t; i < NBUCK; i += 256) lh[i] = 0;
    __syncthreads();
    int base = blockIdx.x * PTS_PER_BLK;
#pragma unroll
    for (int k = 0; k < 16; ++k) {
        int p = base + k * 256 + t;
        if (p < n) {
            int pi, pj; px_of(coords[p], pi, pj);
            atomicAdd(&lh[morton2(pi, pj) >> 9], 1u);
        }
    }
    __syncthreads();
    for (int i = t; i < NBUCK; i += 256)
        if (lh[i]) atomicAdd(&bucketCnt[i], lh[i]);
}

__global__ __launch_bounds__(NBUCK)
void bucket_scan_kernel(const u32* __restrict__ bucketCnt,
                        u32* __restrict__ bucketStart,
                        u32* __restrict__ bucketCur, int n) {
    __shared__ u32 part[NBUCK];
    int t = threadIdx.x;
    u32 v = bucketCnt[t];
    part[t] = v; __syncthreads();
    for (int off = 1; off < NBUCK; off <<= 1) {
        u32 x = part[t]; u32 a = (t >= off) ? part[t - off] : 0u;
        __syncthreads(); part[t] = x + a; __syncthreads();
    }
    u32 ex = part[t] - v;
    bucketStart[t] = ex; bucketCur[t] = ex;
    if (t == NBUCK - 1) bucketStart[NBUCK] = (u32)n;
}

__global__ __launch_bounds__(256)
void bucket_scatter_kernel(const float2* __restrict__ coords,
                           const float* __restrict__ depth,
                           const float* __restrict__ pm,
                           u32* __restrict__ bucketCur,
                           ull* __restrict__ keys,
                           u32* __restrict__ payg,     // may be null
                           int n) {
    __shared__ u32 lhist[NBUCK], lofs[NBUCK], lcur[NBUCK], gbase[NBUCK], temp[256];
    __shared__ ull stage[PTS_PER_BLK];
    int t = threadIdx.x;
    for (int i = t; i < NBUCK; i += 256) lhist[i] = 0;
    __syncthreads();
    int base = blockIdx.x * PTS_PER_BLK;
    ull ent[16]; u32 cb[16]; u32 pos[16];
#pragma unroll
    for (int k = 0; k < 16; ++k) {
        int p = base + k * 256 + t;
        cb[k] = 0xFFFFFFFFu;
        if (p < n) {
            int pi, pj; px_of(coords[p], pi, pj);
            u32 m = morton2(pi, pj);
            cb[k] = m >> 9;
            ent[k] = ((ull)__float_as_uint(depth[p]) << 32)
                   | ((ull)(m & 511u) << 21) | (ull)(u32)p;
            atomicAdd(&lhist[cb[k]], 1u);
        }
    }
    __syncthreads();
    u32 pv = lhist[2 * t] + lhist[2 * t + 1];
    temp[t] = pv; __syncthreads();
    for (int off = 1; off < 256; off <<= 1) {
        u32 x = temp[t]; u32 a = (t >= off) ? temp[t - off] : 0u;
        __syncthreads(); temp[t] = x + a; __syncthreads();
    }
    u32 pb = temp[t] - pv;
    lofs[2 * t] = pb;                  lofs[2 * t + 1] = pb + lhist[2 * t];
    lcur[2 * t] = pb;                  lcur[2 * t + 1] = pb + lhist[2 * t];
    __syncthreads();
#pragma unroll
    for (int k = 0; k < 16; ++k) {
        if (cb[k] != 0xFFFFFFFFu) {
            pos[k] = atomicAdd(&lcur[cb[k]], 1u);
            stage[pos[k]] = ent[k];
        }
    }
    __syncthreads();
    for (int b = t; b < NBUCK; b += 256) {
        u32 cnt = lhist[b];
        if (!cnt) continue;
        u32 gb = atomicAdd(&bucketCur[b], cnt);
        gbase[b] = gb;
        u32 lo = lofs[b];
        for (u32 i = 0; i < cnt; ++i) keys[gb + i] = stage[lo + i];
    }
    if (payg) {
        __syncthreads();
        u32* pstage = (u32*)stage;
#pragma unroll
        for (int k = 0; k < 16; ++k) {
            int p = base + k * 256 + t;
            if (cb[k] != 0xFFFFFFFFu) pstage[pos[k]] = __float_as_uint(pm[p]);
        }
        __syncthreads();
        for (int b = t; b < NBUCK; b += 256) {
            u32 cnt = lhist[b];
            if (!cnt) continue;
            u32 gb = gbase[b], lo = lofs[b];
            for (u32 i = 0; i < cnt; ++i) payg[gb + i] = pstage[lo + i];
        }
    }
}

__global__ __launch_bounds__(256)
void cell_hist_kernel(const ull* __restrict__ keys,
                      const u32* __restrict__ bucketStart,
                      u32* __restrict__ countsM) {
    __shared__ u32 lh[NBUCK];
    int b = blockIdx.x, t = threadIdx.x;
    for (int i = t; i < NBUCK; i += 256) lh[i] = 0;
    __syncthreads();
    u32 s = bucketStart[b], e = bucketStart[b + 1];
    for (u32 i = s + t; i < e; i += 256) {
        u32 mlow = (u32)(keys[i] >> 21) & 511u;
        atomicAdd(&lh[mlow], 1u);
    }
    __syncthreads();
    for (int i = t; i < NBUCK; i += 256) countsM[(b << 9) + i] = lh[i];
}

__global__ __launch_bounds__(256)
void place_kernel(ull* __restrict__ keys,
                  u32* __restrict__ payg,              // may be null
                  const u32* __restrict__ bucketStart,
                  const u32* __restrict__ startsM) {
    __shared__ ull stage[PLACE_CAP];
    __shared__ u32 pstage[PLACE_CAP];
    __shared__ u32 cur[NBUCK];
    int b = blockIdx.x, t = threadIdx.x;
    u32 s = bucketStart[b], e = bucketStart[b + 1];
    u32 cnt = e - s;
    u32 lim = cnt < PLACE_CAP ? cnt : PLACE_CAP;
    for (u32 i = t; i < lim; i += 256) stage[i] = keys[s + i];
    if (payg) for (u32 i = t; i < lim; i += 256) pstage[i] = payg[s + i];
    for (int i = t; i < NBUCK; i += 256) cur[i] = startsM[(b << 9) + i];
    __syncthreads();
    for (u32 i = t; i < lim; i += 256) {
        ull en = stage[i];
        u32 mlow = (u32)(en >> 21) & 511u;
        u32 slot = atomicAdd(&cur[mlow], 1u);
        keys[slot] = ((en >> 32) << 32) | (en & 0x1FFFFFull);
        if (payg) payg[slot] = pstage[i];
    }
}

// ================= NEW PATH: fixed-capacity staging =================
__global__ __launch_bounds__(256)
void bucket_scatter_fixed(const float2* __restrict__ coords,
                          const float* __restrict__ depth,
                          const float* __restrict__ pm,
                          u32* __restrict__ bucketCnt,
                          ull* __restrict__ stageK,
                          u32* __restrict__ stageP,
                          int n) {
    __shared__ u32 lhist[NBUCK], lofs[NBUCK], lcur[NBUCK], gbase[NBUCK], temp[256];
    __shared__ ull stage[PTS_PER_BLK];
    int t = threadIdx.x;
    for (int i = t; i < NBUCK; i += 256) lhist[i] = 0;
    __syncthreads();
    int base = blockIdx.x * PTS_PER_BLK;
    ull ent[16]; u32 cb[16]; u32 pos[16];
#pragma unroll
    for (int k = 0; k < 16; ++k) {
        int p = base + k * 256 + t;
        cb[k] = 0xFFFFFFFFu;
        if (p < n) {
            int pi, pj; px_of(coords[p], pi, pj);
            u32 m = morton2(pi, pj);
            cb[k] = m >> 9;
            ent[k] = ((ull)__float_as_uint(depth[p]) << 32)
                   | ((ull)(m & 511u) << 21) | (ull)(u32)p;
            atomicAdd(&lhist[cb[k]], 1u);
        }
    }
    __syncthreads();
    u32 pv = lhist[2 * t] + lhist[2 * t + 1];
    temp[t] = pv; __syncthreads();
    for (int off = 1; off < 256; off <<= 1) {
        u32 x = temp[t]; u32 a = (t >= off) ? temp[t - off] : 0u;
        __syncthreads(); temp[t] = x + a; __syncthreads();
    }
    u32 pb = temp[t] - pv;
    lofs[2 * t] = pb;                  lofs[2 * t + 1] = pb + lhist[2 * t];
    lcur[2 * t] = pb;                  lcur[2 * t + 1] = pb + lhist[2 * t];
    __syncthreads();
#pragma unroll
    for (int k = 0; k < 16; ++k) {
        if (cb[k] != 0xFFFFFFFFu) {
            pos[k] = atomicAdd(&lcur[cb[k]], 1u);
            stage[pos[k]] = ent[k];
        }
    }
    __syncthreads();
    for (int b = t; b < NBUCK; b += 256) {
        u32 cnt = lhist[b];
        if (!cnt) { gbase[b] = 0xFFFFFFFFu; continue; }
        u32 gb0 = atomicAdd(&bucketCnt[b], cnt);
        gbase[b] = gb0;
        u32 wr = (gb0 >= CAPB) ? 0u : ((cnt < CAPB - gb0) ? cnt : CAPB - gb0);
        u32 gb = b * CAPB + gb0, lo = lofs[b];
        for (u32 i = 0; i < wr; ++i) stageK[gb + i] = stage[lo + i];
    }
    __syncthreads();
    u32* pstage = (u32*)stage;
#pragma unroll
    for (int k = 0; k < 16; ++k) {
        int p = base + k * 256 + t;
        if (cb[k] != 0xFFFFFFFFu) pstage[pos[k]] = __float_as_uint(pm[p]);
    }
    __syncthreads();
    for (int b = t; b < NBUCK; b += 256) {
        u32 cnt = lhist[b], gb0 = gbase[b];
        if (!cnt || gb0 == 0xFFFFFFFFu) continue;
        u32 wr = (gb0 >= CAPB) ? 0u : ((cnt < CAPB - gb0) ? cnt : CAPB - gb0);
        u32 gb = b * CAPB + gb0, lo = lofs[b];
        for (u32 i = 0; i < wr; ++i) stageP[gb + i] = pstage[lo + i];
    }
}

__global__ __launch_bounds__(NBUCK)
void bucket_scan2(const u32* __restrict__ bucketCnt,
                  u32* __restrict__ bucketStart) {
    __shared__ u32 part[NBUCK];
    int t = threadIdx.x;
    u32 v = bucketCnt[t]; if (v > CAPB) v = CAPB;
    part[t] = v; __syncthreads();
    for (int off = 1; off < NBUCK; off <<= 1) {
        u32 x = part[t]; u32 a = (t >= off) ? part[t - off] : 0u;
        __syncthreads(); part[t] = x + a; __syncthreads();
    }
    bucketStart[t] = part[t] - v;
    if (t == NBUCK - 1) bucketStart[NBUCK] = part[t];
}

__global__ __launch_bounds__(256)
void cell_hist_staged(const ull* __restrict__ stageK,
                      const u32* __restrict__ bucketCnt,
                      u32* __restrict__ countsM) {
    __shared__ u32 lh[NBUCK];
    int b = blockIdx.x, t = threadIdx.x;
    for (int i = t; i < NBUCK; i += 256) lh[i] = 0;
    __syncthreads();
    u32 cnt = bucketCnt[b]; if (cnt > CAPB) cnt = CAPB;
    u32 s = (u32)b * CAPB;
    for (u32 i = t; i < cnt; i += 256) {
        u32 mlow = (u32)(stageK[s + i] >> 21) & 511u;
        atomicAdd(&lh[mlow], 1u);
    }
    __syncthreads();
    for (int i = t; i < NBUCK; i += 256) countsM[(b << 9) + i] = lh[i];
}

// placement: coalesced read from staging, LDS cursors, region-local writes
__global__ __launch_bounds__(256)
void place_staged(const ull* __restrict__ stageK,
                  const u32* __restrict__ stageP,
                  const u32* __restrict__ bucketCnt,
                  const u32* __restrict__ startsM,
                  ull* __restrict__ keysF,
                  u32* __restrict__ payF) {
    __shared__ u32 cur[NBUCK];
    int b = blockIdx.x, t = threadIdx.x;
    u32 cnt = bucketCnt[b]; if (cnt > CAPB) cnt = CAPB;
    for (int i = t; i < NBUCK; i += 256) cur[i] = startsM[(b << 9) + i];
    __syncthreads();
    u32 s = (u32)b * CAPB;
    for (u32 i = t; i < cnt; i += 256) {
        ull en = stageK[s + i];
        u32 mlow = (u32)(en >> 21) & 511u;
        u32 slot = atomicAdd(&cur[mlow], 1u);
        keysF[slot] = en;            // same-cell keys share mlow bits -> compare-safe
        payF[slot] = stageP[s + i];
    }
}

// ---------- scanA (single kernel; prefix comes from bucketStart) ----------
__global__ __launch_bounds__(256)
void scanA_final2(const u32* __restrict__ countsM,
                  const u32* __restrict__ bucketStart,
                  u32* __restrict__ startsM) {
    int b = blockIdx.x, t = threadIdx.x;
    const uint4* src = (const uint4*)(countsM + b * 2048);
    uint4 a = src[t * 2], c = src[t * 2 + 1];
    u32 e[8] = {a.x, a.y, a.z, a.w, c.x, c.y, c.z, c.w};
    u32 tsum = 0;
#pragma unroll
    for (int k = 0; k < 8; ++k) tsum += e[k];
    __shared__ u32 part[256];
    part[t] = tsum; __syncthreads();
    for (int off = 1; off < 256; off <<= 1) {
        u32 x = part[t];
        u32 ad = (t >= off) ? part[t - off] : 0;
        __syncthreads(); part[t] = x + ad; __syncthreads();
    }
    u32 run = bucketStart[b * 4] + part[t] - tsum;   // block b = buckets 4b..4b+3
    u32 o[8];
#pragma unroll
    for (int k = 0; k < 8; ++k) { o[k] = run; run += e[k]; }
    uint4* d1 = (uint4*)(startsM + b * 2048);
    d1[t * 2]     = make_uint4(o[0], o[1], o[2], o[3]);
    d1[t * 2 + 1] = make_uint4(o[4], o[5], o[6], o[7]);
    if (b == NBLK0 - 1 && t == 255) startsM[N0] = run;   // sentinel = n
}

// ---------- segid scans ----------
__device__ __forceinline__ void blk_map(int b, int& si, int& bb) {
    if (b < 128)      { si = 0; bb = b; }
    else if (b < 160) { si = 1; bb = b - 128; }
    else              { si = 2; bb = b - 160; }
}
__device__ __forceinline__ u32 cell_cnt(const u32* startsM, int c, int wbits, int si) {
    u32 ci = (u32)c >> wbits, cj = (u32)c & ((1u << wbits) - 1u);
    u32 mb = morton2(ci, cj) << (2 * si);
    return startsM[mb + (1u << (2 * si))] - startsM[mb];
}

__global__ __launch_bounds__(256)
void scanB_partial(const u32* __restrict__ startsM, u32* __restrict__ bsumB) {
    int si, bb; blk_map(blockIdx.x, si, bb);
    int wbits = 9 - si, t = threadIdx.x;
    int base = bb * 2048 + t * 8;
    u32 s = 0;
#pragma unroll
    for (int k = 0; k < 8; ++k)
        s += (cell_cnt(startsM, base + k, wbits, si) > 0) ? 1u : 0u;
    __shared__ u32 red[256];
    red[t] = s; __syncthreads();
    for (int off = 128; off; off >>= 1) {
        if (t < off) red[t] += red[t + off];
        __syncthreads();
    }
    if (!t) bsumB[blockIdx.x] = red[0];
}

__global__ __launch_bounds__(256)
void scanB_bsum(const u32* __restrict__ bsumB, u32* __restrict__ bpreB,
                u32* __restrict__ ncells) {
    __shared__ u32 part[256];
    int t = threadIdx.x;
    u32 v = (t < NBLKB) ? bsumB[t] : 0u;
    int rid = (t < 128) ? 0 : ((t < 160) ? 1 : 2);
    part[t] = v; __syncthreads();
    for (int off = 1; off < 256; off <<= 1) {
        u32 x = part[t];
        int tp = t - off;
        int ridp = (tp < 128) ? 0 : ((tp < 160) ? 1 : 2);
        u32 a = (tp >= 0 && ridp == rid) ? part[tp] : 0u;
        __syncthreads(); part[t] = x + a; __syncthreads();
    }
    if (t < NBLKB) bpreB[t] = part[t] - v;
    if (t == 127) ncells[0] = part[t];
    if (t == 159) ncells[1] = part[t];
    if (t == 167) ncells[2] = part[t];
}

struct SegArgs {
    u32* segid[3]; float* lens[3]; float* canvas[3];
};
__global__ __launch_bounds__(256)
void scanB_final(const u32* __restrict__ startsM, const u32* __restrict__ bpreB,
                 SegArgs sa) {
    int si, bb; blk_map(blockIdx.x, si, bb);
    int wbits = 9 - si, t = threadIdx.x;
    int base = bb * 2048 + t * 8;
    u32 cnt[8], flg[8], tsum = 0;
#pragma unroll
    for (int k = 0; k < 8; ++k) {
        cnt[k] = cell_cnt(startsM, base + k, wbits, si);
        flg[k] = cnt[k] ? 1u : 0u;
        tsum += flg[k];
    }
    __shared__ u32 part[256];
    part[t] = tsum; __syncthreads();
    for (int off = 1; off < 256; off <<= 1) {
        u32 x = part[t];
        u32 ad = (t >= off) ? part[t - off] : 0u;
        __syncthreads(); part[t] = x + ad; __syncthreads();
    }
    u32 run = bpreB[blockIdx.x] + part[t] - tsum;
    u32* segid = sa.segid[si];
    float* lens = sa.lens[si];
    float* canvas = sa.canvas[si];
    u32 wmask = (1u << wbits) - 1u;
#pragma unroll
    for (int k = 0; k < 8; ++k) {
        int c = base + k;
        segid[c] = run;
        if (flg[k]) {
            u32 s = run;
            u32 len = cnt[k] < MAX_RAY ? cnt[k] : MAX_RAY;
            lens[s] = (float)len;
            canvas[2 * s]     = (float)((u32)c >> wbits);
            canvas[2 * s + 1] = (float)((u32)c & wmask);
            run += 1;
        }
    }
}

// ---------- emit: grouped LDS-broadcast rank, coalesced full-coverage out ----------
struct CellRegs { ull k0, k1, k2, k3; u32 p0, p1, p2, p3; };
struct __attribute__((packed, aligned(8))) U2 { ull x, y; };
struct __attribute__((packed, aligned(4))) U4 { u32 x, y, z, w; };

template<int CAP>
__device__ __forceinline__ void loadCellG(const ull* __restrict__ keys,
                                          const u32* __restrict__ payg,
                                          const float* __restrict__ pm,
                                          u32 s0, u32 cnt, u32 li, CellRegs& c) {
    c.k0 = c.k1 = c.k2 = c.k3 = ~0ull;
    c.p0 = c.p1 = c.p2 = c.p3 = 0u;
    u32 m = li * 4u;
    if (cnt == 0u || cnt > (u32)CAP || m >= cnt) return;
    const U2* kp = (const U2*)(keys + s0 + m);
    U2 a = kp[0], b = kp[1];
    c.k0 = a.x; c.k1 = a.y; c.k2 = b.x; c.k3 = b.y;
    if (payg) {
        U4 pv = *(const U4*)(payg + s0 + m);
        c.p0 = pv.x; c.p1 = pv.y; c.p2 = pv.z; c.p3 = pv.w;
    } else {
        c.p0 = __float_as_uint(pm[(u32)(c.k0 & 0x1FFFFFull)]);
        if (m + 1 < cnt) c.p1 = __float_as_uint(pm[(u32)(c.k1 & 0x1FFFFFull)]);
        if (m + 2 < cnt) c.p2 = __float_as_uint(pm[(u32)(c.k2 & 0x1FFFFFull)]);
        if (m + 3 < cnt) c.p3 = __float_as_uint(pm[(u32)(c.k3 & 0x1FFFFFull)]);
    }
    if (m + 1 >= cnt) c.k1 = ~0ull;
    if (m + 2 >= cnt) c.k2 = ~0ull;
    if (m + 3 >= cnt) c.k3 = ~0ull;
}

template<int SI>
__device__ __forceinline__ void emit_body(
    const float* __restrict__ pm, const u32* __restrict__ payload,
    const u32* __restrict__ startsM, const ull* __restrict__ keys,
    const u32* __restrict__ segid, float* __restrict__ batch, int bb,
    float (&tile)[MAX_RAY][65], ull (&lkAll)[4][LKELEMS],
    u32 (&s_s0)[64], u32 (&s_cnt)[64], u32 (&s_seg)[64],
    u32 (&ovfl)[64], u32& ovflN)
{
    constexpr int WB   = 9 - SI;
    constexpr int G    = (SI == 0) ? 8 : (SI == 1) ? 16 : 64;
    constexpr int CAP  = G * 4;
    constexpr int STRD = (SI == 0) ? 34 : (SI == 1) ? 66 : 256;
    constexpr int NG   = 64 / G;
    constexpr int ROUNDS = 64 / (4 * NG);
    const int HW = 1 << (2 * WB);

    int t = threadIdx.x, wave = t >> 6, lane = t & 63;
    int gi = lane / G, li = lane % G;
    ull* lk = &lkAll[wave][0];

    if (t == 0) ovflN = 0;
    if (t < 64) {
        int cell = bb * 64 + t;
        u32 ci = (u32)cell >> WB, cj = (u32)cell & ((1u << WB) - 1u);
        u32 mb = morton2(ci, cj) << (2 * SI);
        u32 s0 = startsM[mb];
        s_s0[t]  = s0;
        s_cnt[t] = startsM[mb + (1u << (2 * SI))] - s0;
        s_seg[t] = segid[cell];
    }
    __syncthreads();

    CellRegs cur, nxt;
    {
        int lc0 = wave * NG + gi;
        loadCellG<CAP>(keys, payload, pm, s_s0[lc0], s_cnt[lc0], (u32)li, cur);
    }
#pragma unroll
    for (int rnd = 0; rnd < ROUNDS; ++rnd) {
        int lc = (rnd * 4 + wave) * NG + gi;
        u32 cnt = s_cnt[lc], m = (u32)li * 4u;
        bool fits = (cnt <= (u32)CAP);
        if (fits && m < cnt) {
            ull* dst = lk + gi * STRD + m;
            dst[0] = cur.k0; dst[1] = cur.k1; dst[2] = cur.k2; dst[3] = cur.k3;
        }
        if (!fits && li == 0) {
            u32 ix = atomicAdd(&ovflN, 1u);
            ovfl[ix] = (u32)lc;
        }
        if (rnd + 1 < ROUNDS) {
            int lc2 = ((rnd + 1) * 4 + wave) * NG + gi;
            loadCellG<CAP>(keys, payload, pm, s_s0[lc2], s_cnt[lc2], (u32)li, nxt);
        }
        if (cnt && fits) {
            asm volatile("s_waitcnt lgkmcnt(0)" ::: "memory");
            u32 cntR = (cnt + 3u) & ~3u;
            u32 r0 = 0, r1 = 0, r2 = 0, r3 = 0;
            const ull* kb = lk + gi * STRD;
            for (u32 j = 0; j < cntR; j += 4) {
                U2 a  = *(const U2*)(kb + j);
                U2 b2 = *(const U2*)(kb + j + 2);
                r0 += (a.x < cur.k0) + (a.y < cur.k0) + (b2.x < cur.k0) + (b2.y < cur.k0);
                r1 += (a.x < cur.k1) + (a.y < cur.k1) + (b2.x < cur.k1) + (b2.y < cur.k1);
                r2 += (a.x < cur.k2) + (a.y < cur.k2) + (b2.x < cur.k2) + (b2.y < cur.k2);
                r3 += (a.x < cur.k3) + (a.y < cur.k3) + (b2.x < cur.k3) + (b2.y < cur.k3);
            }
            if (m < cnt) {
                if (r0 < MAX_RAY)                 tile[r0][lc] = __uint_as_float(cur.p0);
                if (m + 1 < cnt && r1 < MAX_RAY)  tile[r1][lc] = __uint_as_float(cur.p1);
                if (m + 2 < cnt && r2 < MAX_RAY)  tile[r2][lc] = __uint_as_float(cur.p2);
                if (m + 3 < cnt && r3 < MAX_RAY)  tile[r3][lc] = __uint_as_float(cur.p3);
            }
        }
        cur = nxt;
    }
    __syncthreads();

    u32 no = ovflN;
    if (no && wave == 0) {
        for (u32 o = 0; o < no; ++o) {
            int lc = (int)ovfl[o];
            u32 s0 = s_s0[lc], cnt = s_cnt[lc];
            for (u32 i = lane; i < cnt; i += 64) {
                ull mk = keys[s0 + i];
                u32 r = 0;
                for (u32 j = 0; j < cnt; ++j) r += (keys[s0 + j] < mk) ? 1u : 0u;
                if (r < MAX_RAY) {
                    u32 pv = payload ? payload[s0 + i]
                                     : __float_as_uint(pm[(u32)(mk & 0x1FFFFFull)]);
                    tile[r][lc] = __uint_as_float(pv);
                }
            }
        }
    }
    __syncthreads();

    u32 myCnt = s_cnt[lane], mySeg = s_seg[lane];
    u32 lim = myCnt < MAX_RAY ? myCnt : MAX_RAY;
    for (int r = wave; r < MAX_RAY; r += 4) {
        if (myCnt) batch[(size_t)r * (size_t)HW + mySeg] = (r < (int)lim) ? tile[r][lane] : 0.0f;
    }
}

struct EmitArgs {
    const u32* segid[3]; float* batch[3];
};
__global__ __launch_bounds__(256)
void emit_kernel(const float* __restrict__ pm,
                 const u32* __restrict__ payload,
                 const u32* __restrict__ startsM,
                 const ull* __restrict__ keys,
                 EmitArgs ea) {
    __shared__ float tile[MAX_RAY][65];
    __shared__ __align__(16) ull lkAll[4][LKELEMS];
    __shared__ u32 s_s0[64], s_cnt[64], s_seg[64], ovfl[64], ovflN;

    int b = blockIdx.x;
    if (b < 256)
        emit_body<2>(pm, payload, startsM, keys, ea.segid[2], ea.batch[2], b,
                     tile, lkAll, s_s0, s_cnt, s_seg, ovfl, ovflN);
    else if (b < 1280)
        emit_body<1>(pm, payload, startsM, keys, ea.segid[1], ea.batch[1], b - 256,
                     tile, lkAll, s_s0, s_cnt, s_seg, ovfl, ovflN);
    else
        emit_body<0>(pm, payload, startsM, keys, ea.segid[0], ea.batch[0], b - 1280,
                     tile, lkAll, s_s0, s_cnt, s_seg, ovfl, ovflN);
}

// ---------- zero tails of batch + lens + canvas ----------
__global__ __launch_bounds__(256)
void zero_tail_kernel(const u32* __restrict__ ncells,
                      float* __restrict__ b0, float* __restrict__ b1,
                      float* __restrict__ b2,
                      float* __restrict__ l0, float* __restrict__ l1,
                      float* __restrict__ l2,
                      float* __restrict__ c0, float* __restrict__ c1,
                      float* __restrict__ c2) {
    int b = blockIdx.x, si, col; float* base; float* lens; float* canv; int HW;
    if (b < 1024)      { si = 0; base = b0; lens = l0; canv = c0; HW = 262144; col = b * 256 + (int)threadIdx.x; }
    else if (b < 1280) { si = 1; base = b1; lens = l1; canv = c1; HW = 65536;  col = (b - 1024) * 256 + (int)threadIdx.x; }
    else               { si = 2; base = b2; lens = l2; canv = c2; HW = 16384;  col = (b - 1280) * 256 + (int)threadIdx.x; }
    if ((u32)col >= ncells[si]) {
        lens[col] = 0.0f;
        canv[2 * col] = 0.0f; canv[2 * col + 1] = 0.0f;
        for (int r = 0; r < MAX_RAY; ++r)
            base[(size_t)r * (size_t)HW + col] = 0.0f;
    }
}

extern "C" void kernel_launch(void* const* d_in, const int* in_sizes, int n_in,
                              void* d_out, int out_size, void* d_ws, size_t ws_size,
                              hipStream_t stream) {
    const float2* coords = (const float2*)d_in[0];
    const float*  depth  = (const float*)d_in[1];
    const float*  pm     = (const float*)d_in[2];
    float* out = (float*)d_out;
    const int n = in_sizes[1];

    const int HWs[3] = {512 * 512, 256 * 256, 128 * 128};

    // ---- workspace layout ----
    char* ws = (char*)d_ws;
    size_t off = 0;
    ull* keysF   = (ull*)(ws + off); off += (size_t)n * 8;
    u32* countsM = (u32*)(ws + off); off += (size_t)N0 * 4;
    u32* startsM = (u32*)(ws + off); off += (size_t)(N0 + 64) * 4;
    u32* segid[3];
    for (int i = 0; i < 3; ++i) { segid[i] = (u32*)(ws + off); off += (size_t)HWs[i] * 4; }
    u32* bsumB = (u32*)(ws + off); off += 256 * 4;
    u32* bpreB = (u32*)(ws + off); off += 256 * 4;
    u32* bucketCnt   = (u32*)(ws + off); off += NBUCK * 4;
    u32* bucketStart = (u32*)(ws + off); off += (NBUCK + 64) * 4;
    u32* bucketCur   = (u32*)(ws + off); off += NBUCK * 4;
    u32* ncells      = (u32*)(ws + off); off += 64 * 4;
    u32* payF        = (u32*)(ws + off);
    size_t needPay = off + (size_t)n * 4;
    size_t offStage = needPay;
    ull* stageK = (ull*)(ws + offStage);
    u32* stageP = (u32*)(ws + offStage + (size_t)NBUCK * CAPB * 8);
    size_t needStaged = offStage + (size_t)NBUCK * CAPB * 12;

    bool haveStage = (ws_size >= needStaged);
    u32* payg = (ws_size >= needPay) ? payF : nullptr;

    // ---- output offsets ----
    size_t offB[3], offL[3], offC[3];
    size_t o = 0;
    for (int i = 0; i < 3; ++i) { offB[i] = o; o += (size_t)MAX_RAY * HWs[i]; }
    for (int i = 0; i < 3; ++i) { offL[i] = o; o += (size_t)HWs[i]; }
    for (int i = 0; i < 3; ++i) { offC[i] = o; o += 2 * (size_t)HWs[i]; }

    hipMemsetAsync(bucketCnt, 0, NBUCK * 4, stream);

    const int nblkPts = (n + PTS_PER_BLK - 1) / PTS_PER_BLK;

    if (haveStage) {
        // fixed-capacity staging path: no coords pre-pass, no cursor copy
        bucket_scatter_fixed<<<nblkPts, 256, 0, stream>>>(coords, depth, pm, bucketCnt,
                                                          stageK, stageP, n);
        bucket_scan2<<<1, NBUCK, 0, stream>>>(bucketCnt, bucketStart);
        cell_hist_staged<<<NBUCK, 256, 0, stream>>>(stageK, bucketCnt, countsM);
        scanA_final2<<<NBLK0, 256, 0, stream>>>(countsM, bucketStart, startsM);
        place_staged<<<NBUCK, 256, 0, stream>>>(stageK, stageP, bucketCnt, startsM,
                                                keysF, payF);
        payg = payF;
    } else {
        bucket_hist_kernel<<<nblkPts, 256, 0, stream>>>(coords, bucketCnt, n);
        bucket_scan_kernel<<<1, NBUCK, 0, stream>>>(bucketCnt, bucketStart, bucketCur, n);
        bucket_scatter_kernel<<<nblkPts, 256, 0, stream>>>(coords, depth, pm, bucketCur,
                                                           keysF, payg, n);
        cell_hist_kernel<<<NBUCK, 256, 0, stream>>>(keysF, bucketStart, countsM);
        scanA_final2<<<NBLK0, 256, 0, stream>>>(countsM, bucketStart, startsM);
        place_kernel<<<NBUCK, 256, 0, stream>>>(keysF, payg, bucketStart, startsM);
    }

    SegArgs sa;
    for (int i = 0; i < 3; ++i) {
        sa.segid[i]  = segid[i];
        sa.lens[i]   = out + offL[i];
        sa.canvas[i] = out + offC[i];
    }
    scanB_partial<<<NBLKB, 256, 0, stream>>>(startsM, bsumB);
    scanB_bsum<<<1, 256, 0, stream>>>(bsumB, bpreB, ncells);
    scanB_final<<<NBLKB, 256, 0, stream>>>(startsM, bpreB, sa);

    EmitArgs ea;
    for (int i = 0; i < 3; ++i) {
        ea.segid[i] = segid[i];
        ea.batch[i] = out + offB[i];
    }
    emit_kernel<<<5376, 256, 0, stream>>>(pm, payg, startsM, keysF, ea);
    zero_tail_kernel<<<1344, 256, 0, stream>>>(ncells,
        out + offB[0], out + offB[1], out + offB[2],
        out + offL[0], out + offL[1], out + offL[2],
        out + offC[0], out + offC[1], out + offC[2]);
}

// Round 11
// 188.313 us; speedup vs baseline: 3.0986x; 1.0009x over previous
//
#include <hip/hip_runtime.h>
#include <stdint.h>

#define MAX_RAY 100
#define NBUCK 512          // coarse buckets = top 9 Morton bits
#define PTS_PER_BLK 4096
#define PLACE_CAP 5120     // old-path LDS stage cap
#define CAPB 5120          // staging region capacity per bucket (mean 3906, sigma 62 -> 19 sigma)
typedef unsigned long long ull;
typedef uint32_t u32;

#define N0 262144          // finest cells
#define NBLK0 128          // N0 / 2048
#define NBLKB 168          // 128 + 32 + 8 segid-scan blocks (2048 cells each)
#define LKELEMS 272        // per-wave LDS key pool (emit)

// ---------- helpers ----------
__device__ __forceinline__ u32 spread1(u32 v) {
    v &= 0x1FF;
    v = (v | (v << 8)) & 0x00FF00FF;
    v = (v | (v << 4)) & 0x0F0F0F0F;
    v = (v | (v << 2)) & 0x33333333;
    v = (v | (v << 1)) & 0x55555555;
    return v;
}
__device__ __forceinline__ u32 morton2(u32 i, u32 j) { return (spread1(i) << 1) | spread1(j); }

__device__ __forceinline__ void px_of(const float2 cv, int& pi, int& pj) {
    float fi = fminf(fmaxf(cv.x * 512.0f, 0.0f), 511.0f);
    float fj = fminf(fmaxf(cv.y * 512.0f, 0.0f), 511.0f);
    pi = (int)fi;   // trunc == floor for non-negative; bit-identical to reference
    pj = (int)fj;
}

// ================= OLD PATH (fallback when ws too small) =================
__global__ __launch_bounds__(256)
void bucket_hist_kernel(const float2* __restrict__ coords,
                        u32* __restrict__ bucketCnt, int n) {
    __shared__ u32 lh[NBUCK];
    int t = threadIdx.x;
    for (int i = t; i < NBUCK; i += 256) lh[i] = 0;
    __syncthreads();
    int base = blockIdx.x * PTS_PER_BLK;
#pragma unroll
    for (int k = 0; k < 16; ++k) {
        int p = base + k * 256 + t;
        if (p < n) {
            int pi, pj; px_of(coords[p], pi, pj);
            atomicAdd(&lh[morton2(pi, pj) >> 9], 1u);
        }
    }
    __syncthreads();
    for (int i = t; i < NBUCK; i += 256)
        if (lh[i]) atomicAdd(&bucketCnt[i], lh[i]);
}

__global__ __launch_bounds__(NBUCK)
void bucket_scan_kernel(const u32* __restrict__ bucketCnt,
                        u32* __restrict__ bucketStart,
                        u32* __restrict__ bucketCur, int n) {
    __shared__ u32 part[NBUCK];
    int t = threadIdx.x;
    u32 v = bucketCnt[t];
    part[t] = v; __syncthreads();
    for (int off = 1; off < NBUCK; off <<= 1) {
        u32 x = part[t]; u32 a = (t >= off) ? part[t - off] : 0u;
        __syncthreads(); part[t] = x + a; __syncthreads();
    }
    u32 ex = part[t] - v;
    bucketStart[t] = ex; bucketCur[t] = ex;
    if (t == NBUCK - 1) bucketStart[NBUCK] = (u32)n;
}

__global__ __launch_bounds__(256)
void bucket_scatter_kernel(const float2* __restrict__ coords,
                           const float* __restrict__ depth,
                           const float* __restrict__ pm,
                           u32* __restrict__ bucketCur,
                           ull* __restrict__ keys,
                           u32* __restrict__ payg,     // may be null
                           int n) {
    __shared__ u32 lhist[NBUCK], lofs[NBUCK], lcur[NBUCK], gbase[NBUCK], temp[256];
    __shared__ ull stage[PTS_PER_BLK];
    int t = threadIdx.x;
    for (int i = t; i < NBUCK; i += 256) lhist[i] = 0;
    __syncthreads();
    int base = blockIdx.x * PTS_PER_BLK;
    ull ent[16]; u32 cb[16]; u32 pos[16];
#pragma unroll
    for (int k = 0; k < 16; ++k) {
        int p = base + k * 256 + t;
        cb[k] = 0xFFFFFFFFu;
        if (p < n) {
            int pi, pj; px_of(coords[p], pi, pj);
            u32 m = morton2(pi, pj);
            cb[k] = m >> 9;
            ent[k] = ((ull)__float_as_uint(depth[p]) << 32)
                   | ((ull)(m & 511u) << 21) | (ull)(u32)p;
            atomicAdd(&lhist[cb[k]], 1u);
        }
    }
    __syncthreads();
    u32 pv = lhist[2 * t] + lhist[2 * t + 1];
    temp[t] = pv; __syncthreads();
    for (int off = 1; off < 256; off <<= 1) {
        u32 x = temp[t]; u32 a = (t >= off) ? temp[t - off] : 0u;
        __syncthreads(); temp[t] = x + a; __syncthreads();
    }
    u32 pb = temp[t] - pv;
    lofs[2 * t] = pb;                  lofs[2 * t + 1] = pb + lhist[2 * t];
    lcur[2 * t] = pb;                  lcur[2 * t + 1] = pb + lhist[2 * t];
    __syncthreads();
#pragma unroll
    for (int k = 0; k < 16; ++k) {
        if (cb[k] != 0xFFFFFFFFu) {
            pos[k] = atomicAdd(&lcur[cb[k]], 1u);
            stage[pos[k]] = ent[k];
        }
    }
    __syncthreads();
    for (int b = t; b < NBUCK; b += 256) {
        u32 cnt = lhist[b];
        if (!cnt) continue;
        u32 gb = atomicAdd(&bucketCur[b], cnt);
        gbase[b] = gb;
        u32 lo = lofs[b];
        for (u32 i = 0; i < cnt; ++i) keys[gb + i] = stage[lo + i];
    }
    if (payg) {
        __syncthreads();
        u32* pstage = (u32*)stage;
#pragma unroll
        for (int k = 0; k < 16; ++k) {
            int p = base + k * 256 + t;
            if (cb[k] != 0xFFFFFFFFu) pstage[pos[k]] = __float_as_uint(pm[p]);
        }
        __syncthreads();
        for (int b = t; b < NBUCK; b += 256) {
            u32 cnt = lhist[b];
            if (!cnt) continue;
            u32 gb = gbase[b], lo = lofs[b];
            for (u32 i = 0; i < cnt; ++i) payg[gb + i] = pstage[lo + i];
        }
    }
}

__global__ __launch_bounds__(256)
void cell_hist_kernel(const ull* __restrict__ keys,
                      const u32* __restrict__ bucketStart,
                      u32* __restrict__ countsM) {
    __shared__ u32 lh[NBUCK];
    int b = blockIdx.x, t = threadIdx.x;
    for (int i = t; i < NBUCK; i += 256) lh[i] = 0;
    __syncthreads();
    u32 s = bucketStart[b], e = bucketStart[b + 1];
    for (u32 i = s + t; i < e; i += 256) {
        u32 mlow = (u32)(keys[i] >> 21) & 511u;
        atomicAdd(&lh[mlow], 1u);
    }
    __syncthreads();
    for (int i = t; i < NBUCK; i += 256) countsM[(b << 9) + i] = lh[i];
}

__global__ __launch_bounds__(256)
void place_kernel(ull* __restrict__ keys,
                  u32* __restrict__ payg,              // may be null
                  const u32* __restrict__ bucketStart,
                  const u32* __restrict__ startsM) {
    __shared__ ull stage[PLACE_CAP];
    __shared__ u32 pstage[PLACE_CAP];
    __shared__ u32 cur[NBUCK];
    int b = blockIdx.x, t = threadIdx.x;
    u32 s = bucketStart[b], e = bucketStart[b + 1];
    u32 cnt = e - s;
    u32 lim = cnt < PLACE_CAP ? cnt : PLACE_CAP;
    for (u32 i = t; i < lim; i += 256) stage[i] = keys[s + i];
    if (payg) for (u32 i = t; i < lim; i += 256) pstage[i] = payg[s + i];
    for (int i = t; i < NBUCK; i += 256) cur[i] = startsM[(b << 9) + i];
    __syncthreads();
    for (u32 i = t; i < lim; i += 256) {
        ull en = stage[i];
        u32 mlow = (u32)(en >> 21) & 511u;
        u32 slot = atomicAdd(&cur[mlow], 1u);
        keys[slot] = ((en >> 32) << 32) | (en & 0x1FFFFFull);
        if (payg) payg[slot] = pstage[i];
    }
}

// ================= NEW PATH: fixed-capacity staging =================
__global__ __launch_bounds__(256)
void bucket_scatter_fixed(const float2* __restrict__ coords,
                          const float* __restrict__ depth,
                          const float* __restrict__ pm,
                          u32* __restrict__ bucketCnt,
                          ull* __restrict__ stageK,
                          u32* __restrict__ stageP,
                          int n) {
    __shared__ u32 lhist[NBUCK], lofs[NBUCK], lcur[NBUCK], gbase[NBUCK], temp[256];
    __shared__ ull stage[PTS_PER_BLK];
    int t = threadIdx.x;
    for (int i = t; i < NBUCK; i += 256) lhist[i] = 0;
    __syncthreads();
    int base = blockIdx.x * PTS_PER_BLK;
    ull ent[16]; u32 cb[16]; u32 pos[16];
#pragma unroll
    for (int k = 0; k < 16; ++k) {
        int p = base + k * 256 + t;
        cb[k] = 0xFFFFFFFFu;
        if (p < n) {
            int pi, pj; px_of(coords[p], pi, pj);
            u32 m = morton2(pi, pj);
            cb[k] = m >> 9;
            ent[k] = ((ull)__float_as_uint(depth[p]) << 32)
                   | ((ull)(m & 511u) << 21) | (ull)(u32)p;
            atomicAdd(&lhist[cb[k]], 1u);
        }
    }
    __syncthreads();
    u32 pv = lhist[2 * t] + lhist[2 * t + 1];
    temp[t] = pv; __syncthreads();
    for (int off = 1; off < 256; off <<= 1) {
        u32 x = temp[t]; u32 a = (t >= off) ? temp[t - off] : 0u;
        __syncthreads(); temp[t] = x + a; __syncthreads();
    }
    u32 pb = temp[t] - pv;
    lofs[2 * t] = pb;                  lofs[2 * t + 1] = pb + lhist[2 * t];
    lcur[2 * t] = pb;                  lcur[2 * t + 1] = pb + lhist[2 * t];
    __syncthreads();
#pragma unroll
    for (int k = 0; k < 16; ++k) {
        if (cb[k] != 0xFFFFFFFFu) {
            pos[k] = atomicAdd(&lcur[cb[k]], 1u);
            stage[pos[k]] = ent[k];
        }
    }
    __syncthreads();
    for (int b = t; b < NBUCK; b += 256) {
        u32 cnt = lhist[b];
        if (!cnt) { gbase[b] = 0xFFFFFFFFu; continue; }
        u32 gb0 = atomicAdd(&bucketCnt[b], cnt);
        gbase[b] = gb0;
        u32 wr = (gb0 >= CAPB) ? 0u : ((cnt < CAPB - gb0) ? cnt : CAPB - gb0);
        u32 gb = b * CAPB + gb0, lo = lofs[b];
        for (u32 i = 0; i < wr; ++i) stageK[gb + i] = stage[lo + i];
    }
    __syncthreads();
    u32* pstage = (u32*)stage;
#pragma unroll
    for (int k = 0; k < 16; ++k) {
        int p = base + k * 256 + t;
        if (cb[k] != 0xFFFFFFFFu) pstage[pos[k]] = __float_as_uint(pm[p]);
    }
    __syncthreads();
    for (int b = t; b < NBUCK; b += 256) {
        u32 cnt = lhist[b], gb0 = gbase[b];
        if (!cnt || gb0 == 0xFFFFFFFFu) continue;
        u32 wr = (gb0 >= CAPB) ? 0u : ((cnt < CAPB - gb0) ? cnt : CAPB - gb0);
        u32 gb = b * CAPB + gb0, lo = lofs[b];
        for (u32 i = 0; i < wr; ++i) stageP[gb + i] = pstage[lo + i];
    }
}

__global__ __launch_bounds__(NBUCK)
void bucket_scan2(const u32* __restrict__ bucketCnt,
                  u32* __restrict__ bucketStart) {
    __shared__ u32 part[NBUCK];
    int t = threadIdx.x;
    u32 v = bucketCnt[t]; if (v > CAPB) v = CAPB;
    part[t] = v; __syncthreads();
    for (int off = 1; off < NBUCK; off <<= 1) {
        u32 x = part[t]; u32 a = (t >= off) ? part[t - off] : 0u;
        __syncthreads(); part[t] = x + a; __syncthreads();
    }
    bucketStart[t] = part[t] - v;
    if (t == NBUCK - 1) bucketStart[NBUCK] = part[t];
}

__global__ __launch_bounds__(256)
void cell_hist_staged(const ull* __restrict__ stageK,
                      const u32* __restrict__ bucketCnt,
                      u32* __restrict__ countsM) {
    __shared__ u32 lh[NBUCK];
    int b = blockIdx.x, t = threadIdx.x;
    for (int i = t; i < NBUCK; i += 256) lh[i] = 0;
    __syncthreads();
    u32 cnt = bucketCnt[b]; if (cnt > CAPB) cnt = CAPB;
    u32 s = (u32)b * CAPB;
    for (u32 i = t; i < cnt; i += 256) {
        u32 mlow = (u32)(stageK[s + i] >> 21) & 511u;
        atomicAdd(&lh[mlow], 1u);
    }
    __syncthreads();
    for (int i = t; i < NBUCK; i += 256) countsM[(b << 9) + i] = lh[i];
}

// placement: coalesced read from staging, LDS cursors, region-local writes.
// CRITICAL: strip the mlow bits (bits 21..29) before storing — rank keys must be
// exactly (depth<<32 | idx) so coarse-scale ties break on original index, not cell.
__global__ __launch_bounds__(256)
void place_staged(const ull* __restrict__ stageK,
                  const u32* __restrict__ stageP,
                  const u32* __restrict__ bucketCnt,
                  const u32* __restrict__ startsM,
                  ull* __restrict__ keysF,
                  u32* __restrict__ payF) {
    __shared__ u32 cur[NBUCK];
    int b = blockIdx.x, t = threadIdx.x;
    u32 cnt = bucketCnt[b]; if (cnt > CAPB) cnt = CAPB;
    for (int i = t; i < NBUCK; i += 256) cur[i] = startsM[(b << 9) + i];
    __syncthreads();
    u32 s = (u32)b * CAPB;
    for (u32 i = t; i < cnt; i += 256) {
        ull en = stageK[s + i];
        u32 mlow = (u32)(en >> 21) & 511u;
        u32 slot = atomicAdd(&cur[mlow], 1u);
        keysF[slot] = ((en >> 32) << 32) | (en & 0x1FFFFFull);   // strip mlow (bug fix R11)
        payF[slot] = stageP[s + i];
    }
}

// ---------- scanA (single kernel; prefix comes from bucketStart) ----------
__global__ __launch_bounds__(256)
void scanA_final2(const u32* __restrict__ countsM,
                  const u32* __restrict__ bucketStart,
                  u32* __restrict__ startsM) {
    int b = blockIdx.x, t = threadIdx.x;
    const uint4* src = (const uint4*)(countsM + b * 2048);
    uint4 a = src[t * 2], c = src[t * 2 + 1];
    u32 e[8] = {a.x, a.y, a.z, a.w, c.x, c.y, c.z, c.w};
    u32 tsum = 0;
#pragma unroll
    for (int k = 0; k < 8; ++k) tsum += e[k];
    __shared__ u32 part[256];
    part[t] = tsum; __syncthreads();
    for (int off = 1; off < 256; off <<= 1) {
        u32 x = part[t];
        u32 ad = (t >= off) ? part[t - off] : 0;
        __syncthreads(); part[t] = x + ad; __syncthreads();
    }
    u32 run = bucketStart[b * 4] + part[t] - tsum;   // block b = buckets 4b..4b+3
    u32 o[8];
#pragma unroll
    for (int k = 0; k < 8; ++k) { o[k] = run; run += e[k]; }
    uint4* d1 = (uint4*)(startsM + b * 2048);
    d1[t * 2]     = make_uint4(o[0], o[1], o[2], o[3]);
    d1[t * 2 + 1] = make_uint4(o[4], o[5], o[6], o[7]);
    if (b == NBLK0 - 1 && t == 255) startsM[N0] = run;   // sentinel = n
}

// ---------- segid scans ----------
__device__ __forceinline__ void blk_map(int b, int& si, int& bb) {
    if (b < 128)      { si = 0; bb = b; }
    else if (b < 160) { si = 1; bb = b - 128; }
    else              { si = 2; bb = b - 160; }
}
__device__ __forceinline__ u32 cell_cnt(const u32* startsM, int c, int wbits, int si) {
    u32 ci = (u32)c >> wbits, cj = (u32)c & ((1u << wbits) - 1u);
    u32 mb = morton2(ci, cj) << (2 * si);
    return startsM[mb + (1u << (2 * si))] - startsM[mb];
}

__global__ __launch_bounds__(256)
void scanB_partial(const u32* __restrict__ startsM, u32* __restrict__ bsumB) {
    int si, bb; blk_map(blockIdx.x, si, bb);
    int wbits = 9 - si, t = threadIdx.x;
    int base = bb * 2048 + t * 8;
    u32 s = 0;
#pragma unroll
    for (int k = 0; k < 8; ++k)
        s += (cell_cnt(startsM, base + k, wbits, si) > 0) ? 1u : 0u;
    __shared__ u32 red[256];
    red[t] = s; __syncthreads();
    for (int off = 128; off; off >>= 1) {
        if (t < off) red[t] += red[t + off];
        __syncthreads();
    }
    if (!t) bsumB[blockIdx.x] = red[0];
}

__global__ __launch_bounds__(256)
void scanB_bsum(const u32* __restrict__ bsumB, u32* __restrict__ bpreB,
                u32* __restrict__ ncells) {
    __shared__ u32 part[256];
    int t = threadIdx.x;
    u32 v = (t < NBLKB) ? bsumB[t] : 0u;
    int rid = (t < 128) ? 0 : ((t < 160) ? 1 : 2);
    part[t] = v; __syncthreads();
    for (int off = 1; off < 256; off <<= 1) {
        u32 x = part[t];
        int tp = t - off;
        int ridp = (tp < 128) ? 0 : ((tp < 160) ? 1 : 2);
        u32 a = (tp >= 0 && ridp == rid) ? part[tp] : 0u;
        __syncthreads(); part[t] = x + a; __syncthreads();
    }
    if (t < NBLKB) bpreB[t] = part[t] - v;
    if (t == 127) ncells[0] = part[t];
    if (t == 159) ncells[1] = part[t];
    if (t == 167) ncells[2] = part[t];
}

struct SegArgs {
    u32* segid[3]; float* lens[3]; float* canvas[3];
};
__global__ __launch_bounds__(256)
void scanB_final(const u32* __restrict__ startsM, const u32* __restrict__ bpreB,
                 SegArgs sa) {
    int si, bb; blk_map(blockIdx.x, si, bb);
    int wbits = 9 - si, t = threadIdx.x;
    int base = bb * 2048 + t * 8;
    u32 cnt[8], flg[8], tsum = 0;
#pragma unroll
    for (int k = 0; k < 8; ++k) {
        cnt[k] = cell_cnt(startsM, base + k, wbits, si);
        flg[k] = cnt[k] ? 1u : 0u;
        tsum += flg[k];
    }
    __shared__ u32 part[256];
    part[t] = tsum; __syncthreads();
    for (int off = 1; off < 256; off <<= 1) {
        u32 x = part[t];
        u32 ad = (t >= off) ? part[t - off] : 0u;
        __syncthreads(); part[t] = x + ad; __syncthreads();
    }
    u32 run = bpreB[blockIdx.x] + part[t] - tsum;
    u32* segid = sa.segid[si];
    float* lens = sa.lens[si];
    float* canvas = sa.canvas[si];
    u32 wmask = (1u << wbits) - 1u;
#pragma unroll
    for (int k = 0; k < 8; ++k) {
        int c = base + k;
        segid[c] = run;
        if (flg[k]) {
            u32 s = run;
            u32 len = cnt[k] < MAX_RAY ? cnt[k] : MAX_RAY;
            lens[s] = (float)len;
            canvas[2 * s]     = (float)((u32)c >> wbits);
            canvas[2 * s + 1] = (float)((u32)c & wmask);
            run += 1;
        }
    }
}

// ---------- emit: grouped LDS-broadcast rank, coalesced full-coverage out ----------
struct CellRegs { ull k0, k1, k2, k3; u32 p0, p1, p2, p3; };
struct __attribute__((packed, aligned(8))) U2 { ull x, y; };
struct __attribute__((packed, aligned(4))) U4 { u32 x, y, z, w; };

template<int CAP>
__device__ __forceinline__ void loadCellG(const ull* __restrict__ keys,
                                          const u32* __restrict__ payg,
                                          const float* __restrict__ pm,
                                          u32 s0, u32 cnt, u32 li, CellRegs& c) {
    c.k0 = c.k1 = c.k2 = c.k3 = ~0ull;
    c.p0 = c.p1 = c.p2 = c.p3 = 0u;
    u32 m = li * 4u;
    if (cnt == 0u || cnt > (u32)CAP || m >= cnt) return;
    const U2* kp = (const U2*)(keys + s0 + m);
    U2 a = kp[0], b = kp[1];
    c.k0 = a.x; c.k1 = a.y; c.k2 = b.x; c.k3 = b.y;
    if (payg) {
        U4 pv = *(const U4*)(payg + s0 + m);
        c.p0 = pv.x; c.p1 = pv.y; c.p2 = pv.z; c.p3 = pv.w;
    } else {
        c.p0 = __float_as_uint(pm[(u32)(c.k0 & 0x1FFFFFull)]);
        if (m + 1 < cnt) c.p1 = __float_as_uint(pm[(u32)(c.k1 & 0x1FFFFFull)]);
        if (m + 2 < cnt) c.p2 = __float_as_uint(pm[(u32)(c.k2 & 0x1FFFFFull)]);
        if (m + 3 < cnt) c.p3 = __float_as_uint(pm[(u32)(c.k3 & 0x1FFFFFull)]);
    }
    if (m + 1 >= cnt) c.k1 = ~0ull;
    if (m + 2 >= cnt) c.k2 = ~0ull;
    if (m + 3 >= cnt) c.k3 = ~0ull;
}

template<int SI>
__device__ __forceinline__ void emit_body(
    const float* __restrict__ pm, const u32* __restrict__ payload,
    const u32* __restrict__ startsM, const ull* __restrict__ keys,
    const u32* __restrict__ segid, float* __restrict__ batch, int bb,
    float (&tile)[MAX_RAY][65], ull (&lkAll)[4][LKELEMS],
    u32 (&s_s0)[64], u32 (&s_cnt)[64], u32 (&s_seg)[64],
    u32 (&ovfl)[64], u32& ovflN)
{
    constexpr int WB   = 9 - SI;
    constexpr int G    = (SI == 0) ? 8 : (SI == 1) ? 16 : 64;
    constexpr int CAP  = G * 4;
    constexpr int STRD = (SI == 0) ? 34 : (SI == 1) ? 66 : 256;
    constexpr int NG   = 64 / G;
    constexpr int ROUNDS = 64 / (4 * NG);
    const int HW = 1 << (2 * WB);

    int t = threadIdx.x, wave = t >> 6, lane = t & 63;
    int gi = lane / G, li = lane % G;
    ull* lk = &lkAll[wave][0];

    if (t == 0) ovflN = 0;
    if (t < 64) {
        int cell = bb * 64 + t;
        u32 ci = (u32)cell >> WB, cj = (u32)cell & ((1u << WB) - 1u);
        u32 mb = morton2(ci, cj) << (2 * SI);
        u32 s0 = startsM[mb];
        s_s0[t]  = s0;
        s_cnt[t] = startsM[mb + (1u << (2 * SI))] - s0;
        s_seg[t] = segid[cell];
    }
    __syncthreads();

    CellRegs cur, nxt;
    {
        int lc0 = wave * NG + gi;
        loadCellG<CAP>(keys, payload, pm, s_s0[lc0], s_cnt[lc0], (u32)li, cur);
    }
#pragma unroll
    for (int rnd = 0; rnd < ROUNDS; ++rnd) {
        int lc = (rnd * 4 + wave) * NG + gi;
        u32 cnt = s_cnt[lc], m = (u32)li * 4u;
        bool fits = (cnt <= (u32)CAP);
        if (fits && m < cnt) {
            ull* dst = lk + gi * STRD + m;
            dst[0] = cur.k0; dst[1] = cur.k1; dst[2] = cur.k2; dst[3] = cur.k3;
        }
        if (!fits && li == 0) {
            u32 ix = atomicAdd(&ovflN, 1u);
            ovfl[ix] = (u32)lc;
        }
        if (rnd + 1 < ROUNDS) {
            int lc2 = ((rnd + 1) * 4 + wave) * NG + gi;
            loadCellG<CAP>(keys, payload, pm, s_s0[lc2], s_cnt[lc2], (u32)li, nxt);
        }
        if (cnt && fits) {
            asm volatile("s_waitcnt lgkmcnt(0)" ::: "memory");
            u32 cntR = (cnt + 3u) & ~3u;
            u32 r0 = 0, r1 = 0, r2 = 0, r3 = 0;
            const ull* kb = lk + gi * STRD;
            for (u32 j = 0; j < cntR; j += 4) {
                U2 a  = *(const U2*)(kb + j);
                U2 b2 = *(const U2*)(kb + j + 2);
                r0 += (a.x < cur.k0) + (a.y < cur.k0) + (b2.x < cur.k0) + (b2.y < cur.k0);
                r1 += (a.x < cur.k1) + (a.y < cur.k1) + (b2.x < cur.k1) + (b2.y < cur.k1);
                r2 += (a.x < cur.k2) + (a.y < cur.k2) + (b2.x < cur.k2) + (b2.y < cur.k2);
                r3 += (a.x < cur.k3) + (a.y < cur.k3) + (b2.x < cur.k3) + (b2.y < cur.k3);
            }
            if (m < cnt) {
                if (r0 < MAX_RAY)                 tile[r0][lc] = __uint_as_float(cur.p0);
                if (m + 1 < cnt && r1 < MAX_RAY)  tile[r1][lc] = __uint_as_float(cur.p1);
                if (m + 2 < cnt && r2 < MAX_RAY)  tile[r2][lc] = __uint_as_float(cur.p2);
                if (m + 3 < cnt && r3 < MAX_RAY)  tile[r3][lc] = __uint_as_float(cur.p3);
            }
        }
        cur = nxt;
    }
    __syncthreads();

    u32 no = ovflN;
    if (no && wave == 0) {
        for (u32 o = 0; o < no; ++o) {
            int lc = (int)ovfl[o];
            u32 s0 = s_s0[lc], cnt = s_cnt[lc];
            for (u32 i = lane; i < cnt; i += 64) {
                ull mk = keys[s0 + i];
                u32 r = 0;
                for (u32 j = 0; j < cnt; ++j) r += (keys[s0 + j] < mk) ? 1u : 0u;
                if (r < MAX_RAY) {
                    u32 pv = payload ? payload[s0 + i]
                                     : __float_as_uint(pm[(u32)(mk & 0x1FFFFFull)]);
                    tile[r][lc] = __uint_as_float(pv);
                }
            }
        }
    }
    __syncthreads();

    u32 myCnt = s_cnt[lane], mySeg = s_seg[lane];
    u32 lim = myCnt < MAX_RAY ? myCnt : MAX_RAY;
    for (int r = wave; r < MAX_RAY; r += 4) {
        if (myCnt) batch[(size_t)r * (size_t)HW + mySeg] = (r < (int)lim) ? tile[r][lane] : 0.0f;
    }
}

struct EmitArgs {
    const u32* segid[3]; float* batch[3];
};
__global__ __launch_bounds__(256)
void emit_kernel(const float* __restrict__ pm,
                 const u32* __restrict__ payload,
                 const u32* __restrict__ startsM,
                 const ull* __restrict__ keys,
                 EmitArgs ea) {
    __shared__ float tile[MAX_RAY][65];
    __shared__ __align__(16) ull lkAll[4][LKELEMS];
    __shared__ u32 s_s0[64], s_cnt[64], s_seg[64], ovfl[64], ovflN;

    int b = blockIdx.x;
    if (b < 256)
        emit_body<2>(pm, payload, startsM, keys, ea.segid[2], ea.batch[2], b,
                     tile, lkAll, s_s0, s_cnt, s_seg, ovfl, ovflN);
    else if (b < 1280)
        emit_body<1>(pm, payload, startsM, keys, ea.segid[1], ea.batch[1], b - 256,
                     tile, lkAll, s_s0, s_cnt, s_seg, ovfl, ovflN);
    else
        emit_body<0>(pm, payload, startsM, keys, ea.segid[0], ea.batch[0], b - 1280,
                     tile, lkAll, s_s0, s_cnt, s_seg, ovfl, ovflN);
}

// ---------- zero tails of batch + lens + canvas ----------
__global__ __launch_bounds__(256)
void zero_tail_kernel(const u32* __restrict__ ncells,
                      float* __restrict__ b0, float* __restrict__ b1,
                      float* __restrict__ b2,
                      float* __restrict__ l0, float* __restrict__ l1,
                      float* __restrict__ l2,
                      float* __restrict__ c0, float* __restrict__ c1,
                      float* __restrict__ c2) {
    int b = blockIdx.x, si, col; float* base; float* lens; float* canv; int HW;
    if (b < 1024)      { si = 0; base = b0; lens = l0; canv = c0; HW = 262144; col = b * 256 + (int)threadIdx.x; }
    else if (b < 1280) { si = 1; base = b1; lens = l1; canv = c1; HW = 65536;  col = (b - 1024) * 256 + (int)threadIdx.x; }
    else               { si = 2; base = b2; lens = l2; canv = c2; HW = 16384;  col = (b - 1280) * 256 + (int)threadIdx.x; }
    if ((u32)col >= ncells[si]) {
        lens[col] = 0.0f;
        canv[2 * col] = 0.0f; canv[2 * col + 1] = 0.0f;
        for (int r = 0; r < MAX_RAY; ++r)
            base[(size_t)r * (size_t)HW + col] = 0.0f;
    }
}

extern "C" void kernel_launch(void* const* d_in, const int* in_sizes, int n_in,
                              void* d_out, int out_size, void* d_ws, size_t ws_size,
                              hipStream_t stream) {
    const float2* coords = (const float2*)d_in[0];
    const float*  depth  = (const float*)d_in[1];
    const float*  pm     = (const float*)d_in[2];
    float* out = (float*)d_out;
    const int n = in_sizes[1];

    const int HWs[3] = {512 * 512, 256 * 256, 128 * 128};

    // ---- workspace layout ----
    char* ws = (char*)d_ws;
    size_t off = 0;
    ull* keysF   = (ull*)(ws + off); off += (size_t)n * 8;
    u32* countsM = (u32*)(ws + off); off += (size_t)N0 * 4;
    u32* startsM = (u32*)(ws + off); off += (size_t)(N0 + 64) * 4;
    u32* segid[3];
    for (int i = 0; i < 3; ++i) { segid[i] = (u32*)(ws + off); off += (size_t)HWs[i] * 4; }
    u32* bsumB = (u32*)(ws + off); off += 256 * 4;
    u32* bpreB = (u32*)(ws + off); off += 256 * 4;
    u32* bucketCnt   = (u32*)(ws + off); off += NBUCK * 4;
    u32* bucketStart = (u32*)(ws + off); off += (NBUCK + 64) * 4;
    u32* bucketCur   = (u32*)(ws + off); off += NBUCK * 4;
    u32* ncells      = (u32*)(ws + off); off += 64 * 4;
    u32* payF        = (u32*)(ws + off);
    size_t needPay = off + (size_t)n * 4;
    size_t offStage = needPay;
    ull* stageK = (ull*)(ws + offStage);
    u32* stageP = (u32*)(ws + offStage + (size_t)NBUCK * CAPB * 8);
    size_t needStaged = offStage + (size_t)NBUCK * CAPB * 12;

    bool haveStage = (ws_size >= needStaged);
    u32* payg = (ws_size >= needPay) ? payF : nullptr;

    // ---- output offsets ----
    size_t offB[3], offL[3], offC[3];
    size_t o = 0;
    for (int i = 0; i < 3; ++i) { offB[i] = o; o += (size_t)MAX_RAY * HWs[i]; }
    for (int i = 0; i < 3; ++i) { offL[i] = o; o += (size_t)HWs[i]; }
    for (int i = 0; i < 3; ++i) { offC[i] = o; o += 2 * (size_t)HWs[i]; }

    hipMemsetAsync(bucketCnt, 0, NBUCK * 4, stream);

    const int nblkPts = (n + PTS_PER_BLK - 1) / PTS_PER_BLK;

    if (haveStage) {
        // fixed-capacity staging path: no coords pre-pass, no cursor copy
        bucket_scatter_fixed<<<nblkPts, 256, 0, stream>>>(coords, depth, pm, bucketCnt,
                                                          stageK, stageP, n);
        bucket_scan2<<<1, NBUCK, 0, stream>>>(bucketCnt, bucketStart);
        cell_hist_staged<<<NBUCK, 256, 0, stream>>>(stageK, bucketCnt, countsM);
        scanA_final2<<<NBLK0, 256, 0, stream>>>(countsM, bucketStart, startsM);
        place_staged<<<NBUCK, 256, 0, stream>>>(stageK, stageP, bucketCnt, startsM,
                                                keysF, payF);
        payg = payF;
    } else {
        bucket_hist_kernel<<<nblkPts, 256, 0, stream>>>(coords, bucketCnt, n);
        bucket_scan_kernel<<<1, NBUCK, 0, stream>>>(bucketCnt, bucketStart, bucketCur, n);
        bucket_scatter_kernel<<<nblkPts, 256, 0, stream>>>(coords, depth, pm, bucketCur,
                                                           keysF, payg, n);
        cell_hist_kernel<<<NBUCK, 256, 0, stream>>>(keysF, bucketStart, countsM);
        scanA_final2<<<NBLK0, 256, 0, stream>>>(countsM, bucketStart, startsM);
        place_kernel<<<NBUCK, 256, 0, stream>>>(keysF, payg, bucketStart, startsM);
    }

    SegArgs sa;
    for (int i = 0; i < 3; ++i) {
        sa.segid[i]  = segid[i];
        sa.lens[i]   = out + offL[i];
        sa.canvas[i] = out + offC[i];
    }
    scanB_partial<<<NBLKB, 256, 0, stream>>>(startsM, bsumB);
    scanB_bsum<<<1, 256, 0, stream>>>(bsumB, bpreB, ncells);
    scanB_final<<<NBLKB, 256, 0, stream>>>(startsM, bpreB, sa);

    EmitArgs ea;
    for (int i = 0; i < 3; ++i) {
        ea.segid[i] = segid[i];
        ea.batch[i] = out + offB[i];
    }
    emit_kernel<<<5376, 256, 0, stream>>>(pm, payg, startsM, keysF, ea);
    zero_tail_kernel<<<1344, 256, 0, stream>>>(ncells,
        out + offB[0], out + offB[1], out + offB[2],
        out + offL[0], out + offL[1], out + offL[2],
        out + offC[0], out + offC[1], out + offC[2]);
}

// Round 12
// 178.544 us; speedup vs baseline: 3.2681x; 1.0547x over previous
//
#include <hip/hip_runtime.h>
#include <stdint.h>

#define MAX_RAY 100
#define NBUCK 512          // coarse buckets = top 9 Morton bits
#define PTS_PER_BLK 4096
#define PLACE_CAP 5120     // old-path LDS stage cap
#define CAPB 5120          // staging region capacity per bucket (mean 3906, sigma 62 -> 19 sigma)
typedef unsigned long long ull;
typedef uint32_t u32;

#define N0 262144          // finest cells
#define NBLK0 128          // N0 / 2048
#define NBLKB 168          // 128 + 32 + 8 segid-scan blocks (2048 cells each)
#define LKELEMS 272        // per-wave LDS key pool (emit)

// ---------- helpers ----------
__device__ __forceinline__ u32 spread1(u32 v) {
    v &= 0x1FF;
    v = (v | (v << 8)) & 0x00FF00FF;
    v = (v | (v << 4)) & 0x0F0F0F0F;
    v = (v | (v << 2)) & 0x33333333;
    v = (v | (v << 1)) & 0x55555555;
    return v;
}
__device__ __forceinline__ u32 morton2(u32 i, u32 j) { return (spread1(i) << 1) | spread1(j); }

__device__ __forceinline__ void px_of(const float2 cv, int& pi, int& pj) {
    float fi = fminf(fmaxf(cv.x * 512.0f, 0.0f), 511.0f);
    float fj = fminf(fmaxf(cv.y * 512.0f, 0.0f), 511.0f);
    pi = (int)fi;   // trunc == floor for non-negative; bit-identical to reference
    pj = (int)fj;
}

// ================= OLD PATH (fallback when ws too small) =================
__global__ __launch_bounds__(256)
void bucket_hist_kernel(const float2* __restrict__ coords,
                        u32* __restrict__ bucketCnt, int n) {
    __shared__ u32 lh[NBUCK];
    int t = threadIdx.x;
    for (int i = t; i < NBUCK; i += 256) lh[i] = 0;
    __syncthreads();
    int base = blockIdx.x * PTS_PER_BLK;
#pragma unroll
    for (int k = 0; k < 16; ++k) {
        int p = base + k * 256 + t;
        if (p < n) {
            int pi, pj; px_of(coords[p], pi, pj);
            atomicAdd(&lh[morton2(pi, pj) >> 9], 1u);
        }
    }
    __syncthreads();
    for (int i = t; i < NBUCK; i += 256)
        if (lh[i]) atomicAdd(&bucketCnt[i], lh[i]);
}

__global__ __launch_bounds__(NBUCK)
void bucket_scan_kernel(const u32* __restrict__ bucketCnt,
                        u32* __restrict__ bucketStart,
                        u32* __restrict__ bucketCur, int n) {
    __shared__ u32 part[NBUCK];
    int t = threadIdx.x;
    u32 v = bucketCnt[t];
    part[t] = v; __syncthreads();
    for (int off = 1; off < NBUCK; off <<= 1) {
        u32 x = part[t]; u32 a = (t >= off) ? part[t - off] : 0u;
        __syncthreads(); part[t] = x + a; __syncthreads();
    }
    u32 ex = part[t] - v;
    bucketStart[t] = ex; bucketCur[t] = ex;
    if (t == NBUCK - 1) bucketStart[NBUCK] = (u32)n;
}

__global__ __launch_bounds__(256)
void bucket_scatter_kernel(const float2* __restrict__ coords,
                           const float* __restrict__ depth,
                           const float* __restrict__ pm,
                           u32* __restrict__ bucketCur,
                           ull* __restrict__ keys,
                           u32* __restrict__ payg,     // may be null
                           int n) {
    __shared__ u32 lhist[NBUCK], lofs[NBUCK], lcur[NBUCK], gbase[NBUCK], temp[256];
    __shared__ ull stage[PTS_PER_BLK];
    int t = threadIdx.x;
    for (int i = t; i < NBUCK; i += 256) lhist[i] = 0;
    __syncthreads();
    int base = blockIdx.x * PTS_PER_BLK;
    ull ent[16]; u32 cb[16]; u32 pos[16];
#pragma unroll
    for (int k = 0; k < 16; ++k) {
        int p = base + k * 256 + t;
        cb[k] = 0xFFFFFFFFu;
        if (p < n) {
            int pi, pj; px_of(coords[p], pi, pj);
            u32 m = morton2(pi, pj);
            cb[k] = m >> 9;
            ent[k] = ((ull)__float_as_uint(depth[p]) << 32)
                   | ((ull)(m & 511u) << 21) | (ull)(u32)p;
            atomicAdd(&lhist[cb[k]], 1u);
        }
    }
    __syncthreads();
    u32 pv = lhist[2 * t] + lhist[2 * t + 1];
    temp[t] = pv; __syncthreads();
    for (int off = 1; off < 256; off <<= 1) {
        u32 x = temp[t]; u32 a = (t >= off) ? temp[t - off] : 0u;
        __syncthreads(); temp[t] = x + a; __syncthreads();
    }
    u32 pb = temp[t] - pv;
    lofs[2 * t] = pb;                  lofs[2 * t + 1] = pb + lhist[2 * t];
    lcur[2 * t] = pb;                  lcur[2 * t + 1] = pb + lhist[2 * t];
    __syncthreads();
#pragma unroll
    for (int k = 0; k < 16; ++k) {
        if (cb[k] != 0xFFFFFFFFu) {
            pos[k] = atomicAdd(&lcur[cb[k]], 1u);
            stage[pos[k]] = ent[k];
        }
    }
    __syncthreads();
    for (int b = t; b < NBUCK; b += 256) {
        u32 cnt = lhist[b];
        if (!cnt) continue;
        u32 gb = atomicAdd(&bucketCur[b], cnt);
        gbase[b] = gb;
        u32 lo = lofs[b];
        for (u32 i = 0; i < cnt; ++i) keys[gb + i] = stage[lo + i];
    }
    if (payg) {
        __syncthreads();
        u32* pstage = (u32*)stage;
#pragma unroll
        for (int k = 0; k < 16; ++k) {
            int p = base + k * 256 + t;
            if (cb[k] != 0xFFFFFFFFu) pstage[pos[k]] = __float_as_uint(pm[p]);
        }
        __syncthreads();
        for (int b = t; b < NBUCK; b += 256) {
            u32 cnt = lhist[b];
            if (!cnt) continue;
            u32 gb = gbase[b], lo = lofs[b];
            for (u32 i = 0; i < cnt; ++i) payg[gb + i] = pstage[lo + i];
        }
    }
}

__global__ __launch_bounds__(256)
void cell_hist_kernel(const ull* __restrict__ keys,
                      const u32* __restrict__ bucketStart,
                      u32* __restrict__ countsM) {
    __shared__ u32 lh[NBUCK];
    int b = blockIdx.x, t = threadIdx.x;
    for (int i = t; i < NBUCK; i += 256) lh[i] = 0;
    __syncthreads();
    u32 s = bucketStart[b], e = bucketStart[b + 1];
    for (u32 i = s + t; i < e; i += 256) {
        u32 mlow = (u32)(keys[i] >> 21) & 511u;
        atomicAdd(&lh[mlow], 1u);
    }
    __syncthreads();
    for (int i = t; i < NBUCK; i += 256) countsM[(b << 9) + i] = lh[i];
}

__global__ __launch_bounds__(256)
void scanA_final2(const u32* __restrict__ countsM,
                  const u32* __restrict__ bucketStart,
                  u32* __restrict__ startsM) {
    int b = blockIdx.x, t = threadIdx.x;
    const uint4* src = (const uint4*)(countsM + b * 2048);
    uint4 a = src[t * 2], c = src[t * 2 + 1];
    u32 e[8] = {a.x, a.y, a.z, a.w, c.x, c.y, c.z, c.w};
    u32 tsum = 0;
#pragma unroll
    for (int k = 0; k < 8; ++k) tsum += e[k];
    __shared__ u32 part[256];
    part[t] = tsum; __syncthreads();
    for (int off = 1; off < 256; off <<= 1) {
        u32 x = part[t];
        u32 ad = (t >= off) ? part[t - off] : 0;
        __syncthreads(); part[t] = x + ad; __syncthreads();
    }
    u32 run = bucketStart[b * 4] + part[t] - tsum;
    u32 o[8];
#pragma unroll
    for (int k = 0; k < 8; ++k) { o[k] = run; run += e[k]; }
    uint4* d1 = (uint4*)(startsM + b * 2048);
    d1[t * 2]     = make_uint4(o[0], o[1], o[2], o[3]);
    d1[t * 2 + 1] = make_uint4(o[4], o[5], o[6], o[7]);
    if (b == NBLK0 - 1 && t == 255) startsM[N0] = run;
}

__global__ __launch_bounds__(256)
void place_kernel(ull* __restrict__ keys,
                  u32* __restrict__ payg,              // may be null
                  const u32* __restrict__ bucketStart,
                  const u32* __restrict__ startsM) {
    __shared__ ull stage[PLACE_CAP];
    __shared__ u32 pstage[PLACE_CAP];
    __shared__ u32 cur[NBUCK];
    int b = blockIdx.x, t = threadIdx.x;
    u32 s = bucketStart[b], e = bucketStart[b + 1];
    u32 cnt = e - s;
    u32 lim = cnt < PLACE_CAP ? cnt : PLACE_CAP;
    for (u32 i = t; i < lim; i += 256) stage[i] = keys[s + i];
    if (payg) for (u32 i = t; i < lim; i += 256) pstage[i] = payg[s + i];
    for (int i = t; i < NBUCK; i += 256) cur[i] = startsM[(b << 9) + i];
    __syncthreads();
    for (u32 i = t; i < lim; i += 256) {
        ull en = stage[i];
        u32 mlow = (u32)(en >> 21) & 511u;
        u32 slot = atomicAdd(&cur[mlow], 1u);
        keys[slot] = ((en >> 32) << 32) | (en & 0x1FFFFFull);
        if (payg) payg[slot] = pstage[i];
    }
}

// ================= NEW PATH: fixed-capacity staging =================
__global__ __launch_bounds__(256)
void bucket_scatter_fixed(const float2* __restrict__ coords,
                          const float* __restrict__ depth,
                          const float* __restrict__ pm,
                          u32* __restrict__ bucketCnt,
                          ull* __restrict__ stageK,
                          u32* __restrict__ stageP,
                          int n) {
    __shared__ u32 lhist[NBUCK], lofs[NBUCK], lcur[NBUCK], gbase[NBUCK], temp[256];
    __shared__ ull stage[PTS_PER_BLK];
    int t = threadIdx.x;
    for (int i = t; i < NBUCK; i += 256) lhist[i] = 0;
    __syncthreads();
    int base = blockIdx.x * PTS_PER_BLK;
    ull ent[16]; u32 cb[16]; u32 pos[16];
#pragma unroll
    for (int k = 0; k < 16; ++k) {
        int p = base + k * 256 + t;
        cb[k] = 0xFFFFFFFFu;
        if (p < n) {
            int pi, pj; px_of(coords[p], pi, pj);
            u32 m = morton2(pi, pj);
            cb[k] = m >> 9;
            ent[k] = ((ull)__float_as_uint(depth[p]) << 32)
                   | ((ull)(m & 511u) << 21) | (ull)(u32)p;
            atomicAdd(&lhist[cb[k]], 1u);
        }
    }
    __syncthreads();
    u32 pv = lhist[2 * t] + lhist[2 * t + 1];
    temp[t] = pv; __syncthreads();
    for (int off = 1; off < 256; off <<= 1) {
        u32 x = temp[t]; u32 a = (t >= off) ? temp[t - off] : 0u;
        __syncthreads(); temp[t] = x + a; __syncthreads();
    }
    u32 pb = temp[t] - pv;
    lofs[2 * t] = pb;                  lofs[2 * t + 1] = pb + lhist[2 * t];
    lcur[2 * t] = pb;                  lcur[2 * t + 1] = pb + lhist[2 * t];
    __syncthreads();
#pragma unroll
    for (int k = 0; k < 16; ++k) {
        if (cb[k] != 0xFFFFFFFFu) {
            pos[k] = atomicAdd(&lcur[cb[k]], 1u);
            stage[pos[k]] = ent[k];
        }
    }
    __syncthreads();
    for (int b = t; b < NBUCK; b += 256) {
        u32 cnt = lhist[b];
        if (!cnt) { gbase[b] = 0xFFFFFFFFu; continue; }
        u32 gb0 = atomicAdd(&bucketCnt[b], cnt);
        gbase[b] = gb0;
        u32 wr = (gb0 >= CAPB) ? 0u : ((cnt < CAPB - gb0) ? cnt : CAPB - gb0);
        u32 gb = b * CAPB + gb0, lo = lofs[b];
        for (u32 i = 0; i < wr; ++i) stageK[gb + i] = stage[lo + i];
    }
    __syncthreads();
    u32* pstage = (u32*)stage;
#pragma unroll
    for (int k = 0; k < 16; ++k) {
        int p = base + k * 256 + t;
        if (cb[k] != 0xFFFFFFFFu) pstage[pos[k]] = __float_as_uint(pm[p]);
    }
    __syncthreads();
    for (int b = t; b < NBUCK; b += 256) {
        u32 cnt = lhist[b], gb0 = gbase[b];
        if (!cnt || gb0 == 0xFFFFFFFFu) continue;
        u32 wr = (gb0 >= CAPB) ? 0u : ((cnt < CAPB - gb0) ? cnt : CAPB - gb0);
        u32 gb = b * CAPB + gb0, lo = lofs[b];
        for (u32 i = 0; i < wr; ++i) stageP[gb + i] = pstage[lo + i];
    }
}

__global__ __launch_bounds__(NBUCK)
void bucket_scan2(const u32* __restrict__ bucketCnt,
                  u32* __restrict__ bucketStart,
                  u32* __restrict__ startsM) {
    __shared__ u32 part[NBUCK];
    int t = threadIdx.x;
    u32 v = bucketCnt[t]; if (v > CAPB) v = CAPB;
    part[t] = v; __syncthreads();
    for (int off = 1; off < NBUCK; off <<= 1) {
        u32 x = part[t]; u32 a = (t >= off) ? part[t - off] : 0u;
        __syncthreads(); part[t] = x + a; __syncthreads();
    }
    bucketStart[t] = part[t] - v;
    if (t == NBUCK - 1) { bucketStart[NBUCK] = part[t]; startsM[N0] = part[t]; }
}

// fused: cell-hist -> in-block scan -> write startsM slice -> place (L2-hot re-read)
__global__ __launch_bounds__(256)
void place_fused(const ull* __restrict__ stageK,
                 const u32* __restrict__ stageP,
                 const u32* __restrict__ bucketCnt,
                 const u32* __restrict__ bucketStart,
                 u32* __restrict__ startsM,
                 ull* __restrict__ keysF,
                 u32* __restrict__ payF) {
    __shared__ u32 lh[NBUCK], cur[NBUCK], temp[256];
    int b = blockIdx.x, t = threadIdx.x;
    u32 cnt = bucketCnt[b]; if (cnt > CAPB) cnt = CAPB;
    u32 s = (u32)b * CAPB;
    for (int i = t; i < NBUCK; i += 256) lh[i] = 0;
    __syncthreads();
    // phase 1: cell histogram of this bucket
    for (u32 i = t; i < cnt; i += 256) {
        u32 mlow = (u32)(stageK[s + i] >> 21) & 511u;
        atomicAdd(&lh[mlow], 1u);
    }
    __syncthreads();
    // phase 2: scan 512 counts with 256 threads (pair trick); write startsM slice
    u32 bs = bucketStart[b];
    u32 pv = lh[2 * t] + lh[2 * t + 1];
    temp[t] = pv; __syncthreads();
    for (int off = 1; off < 256; off <<= 1) {
        u32 x = temp[t]; u32 a = (t >= off) ? temp[t - off] : 0u;
        __syncthreads(); temp[t] = x + a; __syncthreads();
    }
    u32 pb = temp[t] - pv;
    u32 st0 = bs + pb, st1 = bs + pb + lh[2 * t];
    cur[2 * t] = st0; cur[2 * t + 1] = st1;
    uint2* d = (uint2*)(startsM + (b << 9));
    d[t] = make_uint2(st0, st1);                    // coalesced 2KB startsM slice
    __syncthreads();
    // phase 3: place into exact cell slots (strip mlow: key = depth<<32 | idx)
    for (u32 i = t; i < cnt; i += 256) {
        ull en = stageK[s + i];
        u32 mlow = (u32)(en >> 21) & 511u;
        u32 slot = atomicAdd(&cur[mlow], 1u);
        keysF[slot] = ((en >> 32) << 32) | (en & 0x1FFFFFull);
        payF[slot] = stageP[s + i];
    }
}

// ---------- segid scans ----------
__device__ __forceinline__ void blk_map(int b, int& si, int& bb) {
    if (b < 128)      { si = 0; bb = b; }
    else if (b < 160) { si = 1; bb = b - 128; }
    else              { si = 2; bb = b - 160; }
}
__device__ __forceinline__ u32 cell_cnt(const u32* startsM, int c, int wbits, int si) {
    u32 ci = (u32)c >> wbits, cj = (u32)c & ((1u << wbits) - 1u);
    u32 mb = morton2(ci, cj) << (2 * si);
    return startsM[mb + (1u << (2 * si))] - startsM[mb];
}

__global__ __launch_bounds__(256)
void scanB_partial(const u32* __restrict__ startsM, u32* __restrict__ bsumB) {
    int si, bb; blk_map(blockIdx.x, si, bb);
    int wbits = 9 - si, t = threadIdx.x;
    int base = bb * 2048 + t * 8;
    u32 s = 0;
#pragma unroll
    for (int k = 0; k < 8; ++k)
        s += (cell_cnt(startsM, base + k, wbits, si) > 0) ? 1u : 0u;
    __shared__ u32 red[256];
    red[t] = s; __syncthreads();
    for (int off = 128; off; off >>= 1) {
        if (t < off) red[t] += red[t + off];
        __syncthreads();
    }
    if (!t) bsumB[blockIdx.x] = red[0];
}

struct SegArgs {
    u32* segid[3]; float* lens[3]; float* canvas[3];
};
// fused: computes its own segment-prefix from bsumB (no scanB_bsum dispatch);
// last block of each segment writes ncells.
__global__ __launch_bounds__(256)
void scanB_final(const u32* __restrict__ startsM, const u32* __restrict__ bsumB,
                 SegArgs sa, u32* __restrict__ ncells) {
    int si, bb; blk_map(blockIdx.x, si, bb);
    int wbits = 9 - si, t = threadIdx.x;
    int segStart = (si == 0) ? 0 : (si == 1) ? 128 : 160;
    __shared__ u32 s_bpre;
    if (t < 64) {
        u32 acc = 0;
        for (int j = segStart + t; j < (int)blockIdx.x; j += 64) acc += bsumB[j];
        for (int o = 32; o; o >>= 1) acc += __shfl_down(acc, o);
        if (t == 0) s_bpre = acc;
    }
    int base = bb * 2048 + t * 8;
    u32 cnt[8], flg[8], tsum = 0;
#pragma unroll
    for (int k = 0; k < 8; ++k) {
        cnt[k] = cell_cnt(startsM, base + k, wbits, si);
        flg[k] = cnt[k] ? 1u : 0u;
        tsum += flg[k];
    }
    __shared__ u32 part[256];
    part[t] = tsum; __syncthreads();        // also publishes s_bpre
    for (int off = 1; off < 256; off <<= 1) {
        u32 x = part[t];
        u32 ad = (t >= off) ? part[t - off] : 0u;
        __syncthreads(); part[t] = x + ad; __syncthreads();
    }
    u32 run = s_bpre + part[t] - tsum;
    u32* segid = sa.segid[si];
    float* lens = sa.lens[si];
    float* canvas = sa.canvas[si];
    u32 wmask = (1u << wbits) - 1u;
#pragma unroll
    for (int k = 0; k < 8; ++k) {
        int c = base + k;
        segid[c] = run;
        if (flg[k]) {
            u32 s = run;
            u32 len = cnt[k] < MAX_RAY ? cnt[k] : MAX_RAY;
            lens[s] = (float)len;
            canvas[2 * s]     = (float)((u32)c >> wbits);
            canvas[2 * s + 1] = (float)((u32)c & wmask);
            run += 1;
        }
    }
    if (t == 255 && (blockIdx.x == 127 || blockIdx.x == 159 || blockIdx.x == 167))
        ncells[si] = run;                   // segment total occupied cells
}

// ---------- emit: grouped LDS-broadcast rank; tile transposed [64][101] ----------
struct CellRegs { ull k0, k1, k2, k3; u32 p0, p1, p2, p3; };
struct __attribute__((packed, aligned(8))) U2 { ull x, y; };
struct __attribute__((packed, aligned(4))) U4 { u32 x, y, z, w; };

template<int CAP>
__device__ __forceinline__ void loadCellG(const ull* __restrict__ keys,
                                          const u32* __restrict__ payg,
                                          const float* __restrict__ pm,
                                          u32 s0, u32 cnt, u32 li, CellRegs& c) {
    c.k0 = c.k1 = c.k2 = c.k3 = ~0ull;
    c.p0 = c.p1 = c.p2 = c.p3 = 0u;
    u32 m = li * 4u;
    if (cnt == 0u || cnt > (u32)CAP || m >= cnt) return;
    const U2* kp = (const U2*)(keys + s0 + m);
    U2 a = kp[0], b = kp[1];
    c.k0 = a.x; c.k1 = a.y; c.k2 = b.x; c.k3 = b.y;
    if (payg) {
        U4 pv = *(const U4*)(payg + s0 + m);
        c.p0 = pv.x; c.p1 = pv.y; c.p2 = pv.z; c.p3 = pv.w;
    } else {
        c.p0 = __float_as_uint(pm[(u32)(c.k0 & 0x1FFFFFull)]);
        if (m + 1 < cnt) c.p1 = __float_as_uint(pm[(u32)(c.k1 & 0x1FFFFFull)]);
        if (m + 2 < cnt) c.p2 = __float_as_uint(pm[(u32)(c.k2 & 0x1FFFFFull)]);
        if (m + 3 < cnt) c.p3 = __float_as_uint(pm[(u32)(c.k3 & 0x1FFFFFull)]);
    }
    if (m + 1 >= cnt) c.k1 = ~0ull;
    if (m + 2 >= cnt) c.k2 = ~0ull;
    if (m + 3 >= cnt) c.k3 = ~0ull;
}

template<int SI>
__device__ __forceinline__ void emit_body(
    const float* __restrict__ pm, const u32* __restrict__ payload,
    const u32* __restrict__ startsM, const ull* __restrict__ keys,
    const u32* __restrict__ segid, float* __restrict__ batch, int bb,
    float (&tile)[64][101], ull (&lkAll)[4][LKELEMS],
    u32 (&s_s0)[64], u32 (&s_cnt)[64], u32 (&s_seg)[64],
    u32 (&ovfl)[64], u32& ovflN)
{
    constexpr int WB   = 9 - SI;
    constexpr int G    = (SI == 0) ? 8 : (SI == 1) ? 16 : 64;
    constexpr int CAP  = G * 4;
    constexpr int STRD = (SI == 0) ? 34 : (SI == 1) ? 66 : 256;
    constexpr int NG   = 64 / G;
    constexpr int ROUNDS = 64 / (4 * NG);
    const int HW = 1 << (2 * WB);

    int t = threadIdx.x, wave = t >> 6, lane = t & 63;
    int gi = lane / G, li = lane % G;
    ull* lk = &lkAll[wave][0];

    if (t == 0) ovflN = 0;
    if (t < 64) {
        int cell = bb * 64 + t;
        u32 ci = (u32)cell >> WB, cj = (u32)cell & ((1u << WB) - 1u);
        u32 mb = morton2(ci, cj) << (2 * SI);
        u32 s0 = startsM[mb];
        s_s0[t]  = s0;
        s_cnt[t] = startsM[mb + (1u << (2 * SI))] - s0;
        s_seg[t] = segid[cell];
    }
    __syncthreads();

    CellRegs cur, nxt;
    {
        int lc0 = wave * NG + gi;
        loadCellG<CAP>(keys, payload, pm, s_s0[lc0], s_cnt[lc0], (u32)li, cur);
    }
#pragma unroll
    for (int rnd = 0; rnd < ROUNDS; ++rnd) {
        int lc = (rnd * 4 + wave) * NG + gi;
        u32 cnt = s_cnt[lc], m = (u32)li * 4u;
        bool fits = (cnt <= (u32)CAP);
        if (fits && m < cnt) {
            ull* dst = lk + gi * STRD + m;
            dst[0] = cur.k0; dst[1] = cur.k1; dst[2] = cur.k2; dst[3] = cur.k3;
        }
        if (!fits && li == 0) {
            u32 ix = atomicAdd(&ovflN, 1u);
            ovfl[ix] = (u32)lc;
        }
        if (rnd + 1 < ROUNDS) {
            int lc2 = ((rnd + 1) * 4 + wave) * NG + gi;
            loadCellG<CAP>(keys, payload, pm, s_s0[lc2], s_cnt[lc2], (u32)li, nxt);
        }
        if (cnt && fits) {
            asm volatile("s_waitcnt lgkmcnt(0)" ::: "memory");
            u32 cntR = (cnt + 3u) & ~3u;
            u32 r0 = 0, r1 = 0, r2 = 0, r3 = 0;
            const ull* kb = lk + gi * STRD;
            for (u32 j = 0; j < cntR; j += 4) {
                U2 a  = *(const U2*)(kb + j);
                U2 b2 = *(const U2*)(kb + j + 2);
                r0 += (a.x < cur.k0) + (a.y < cur.k0) + (b2.x < cur.k0) + (b2.y < cur.k0);
                r1 += (a.x < cur.k1) + (a.y < cur.k1) + (b2.x < cur.k1) + (b2.y < cur.k1);
                r2 += (a.x < cur.k2) + (a.y < cur.k2) + (b2.x < cur.k2) + (b2.y < cur.k2);
                r3 += (a.x < cur.k3) + (a.y < cur.k3) + (b2.x < cur.k3) + (b2.y < cur.k3);
            }
            if (m < cnt) {
                if (r0 < MAX_RAY)                 tile[lc][r0] = __uint_as_float(cur.p0);
                if (m + 1 < cnt && r1 < MAX_RAY)  tile[lc][r1] = __uint_as_float(cur.p1);
                if (m + 2 < cnt && r2 < MAX_RAY)  tile[lc][r2] = __uint_as_float(cur.p2);
                if (m + 3 < cnt && r3 < MAX_RAY)  tile[lc][r3] = __uint_as_float(cur.p3);
            }
        }
        cur = nxt;
    }
    __syncthreads();

    u32 no = ovflN;
    if (no && wave == 0) {
        for (u32 o = 0; o < no; ++o) {
            int lc = (int)ovfl[o];
            u32 s0 = s_s0[lc], cnt = s_cnt[lc];
            for (u32 i = lane; i < cnt; i += 64) {
                ull mk = keys[s0 + i];
                u32 r = 0;
                for (u32 j = 0; j < cnt; ++j) r += (keys[s0 + j] < mk) ? 1u : 0u;
                if (r < MAX_RAY) {
                    u32 pv = payload ? payload[s0 + i]
                                     : __float_as_uint(pm[(u32)(mk & 0x1FFFFFull)]);
                    tile[lc][r] = __uint_as_float(pv);
                }
            }
        }
    }
    __syncthreads();

    u32 myCnt = s_cnt[lane], mySeg = s_seg[lane];
    u32 lim = myCnt < MAX_RAY ? myCnt : MAX_RAY;
    for (int r = wave; r < MAX_RAY; r += 4) {
        if (myCnt) batch[(size_t)r * (size_t)HW + mySeg] = (r < (int)lim) ? tile[lane][r] : 0.0f;
    }
}

struct EmitArgs {
    const u32* segid[3]; float* batch[3];
};
__global__ __launch_bounds__(256)
void emit_kernel(const float* __restrict__ pm,
                 const u32* __restrict__ payload,
                 const u32* __restrict__ startsM,
                 const ull* __restrict__ keys,
                 EmitArgs ea) {
    __shared__ float tile[64][101];
    __shared__ __align__(16) ull lkAll[4][LKELEMS];
    __shared__ u32 s_s0[64], s_cnt[64], s_seg[64], ovfl[64], ovflN;

    int b = blockIdx.x;
    if (b < 256)
        emit_body<2>(pm, payload, startsM, keys, ea.segid[2], ea.batch[2], b,
                     tile, lkAll, s_s0, s_cnt, s_seg, ovfl, ovflN);
    else if (b < 1280)
        emit_body<1>(pm, payload, startsM, keys, ea.segid[1], ea.batch[1], b - 256,
                     tile, lkAll, s_s0, s_cnt, s_seg, ovfl, ovflN);
    else
        emit_body<0>(pm, payload, startsM, keys, ea.segid[0], ea.batch[0], b - 1280,
                     tile, lkAll, s_s0, s_cnt, s_seg, ovfl, ovflN);
}

// ---------- zero tails of batch + lens + canvas ----------
__global__ __launch_bounds__(256)
void zero_tail_kernel(const u32* __restrict__ ncells,
                      float* __restrict__ b0, float* __restrict__ b1,
                      float* __restrict__ b2,
                      float* __restrict__ l0, float* __restrict__ l1,
                      float* __restrict__ l2,
                      float* __restrict__ c0, float* __restrict__ c1,
                      float* __restrict__ c2) {
    int b = blockIdx.x, si, col; float* base; float* lens; float* canv; int HW;
    if (b < 1024)      { si = 0; base = b0; lens = l0; canv = c0; HW = 262144; col = b * 256 + (int)threadIdx.x; }
    else if (b < 1280) { si = 1; base = b1; lens = l1; canv = c1; HW = 65536;  col = (b - 1024) * 256 + (int)threadIdx.x; }
    else               { si = 2; base = b2; lens = l2; canv = c2; HW = 16384;  col = (b - 1280) * 256 + (int)threadIdx.x; }
    if ((u32)col >= ncells[si]) {
        lens[col] = 0.0f;
        canv[2 * col] = 0.0f; canv[2 * col + 1] = 0.0f;
        for (int r = 0; r < MAX_RAY; ++r)
            base[(size_t)r * (size_t)HW + col] = 0.0f;
    }
}

extern "C" void kernel_launch(void* const* d_in, const int* in_sizes, int n_in,
                              void* d_out, int out_size, void* d_ws, size_t ws_size,
                              hipStream_t stream) {
    const float2* coords = (const float2*)d_in[0];
    const float*  depth  = (const float*)d_in[1];
    const float*  pm     = (const float*)d_in[2];
    float* out = (float*)d_out;
    const int n = in_sizes[1];

    const int HWs[3] = {512 * 512, 256 * 256, 128 * 128};

    // ---- workspace layout ----
    char* ws = (char*)d_ws;
    size_t off = 0;
    ull* keysF   = (ull*)(ws + off); off += (size_t)n * 8;
    u32* countsM = (u32*)(ws + off); off += (size_t)N0 * 4;
    u32* startsM = (u32*)(ws + off); off += (size_t)(N0 + 64) * 4;
    u32* segid[3];
    for (int i = 0; i < 3; ++i) { segid[i] = (u32*)(ws + off); off += (size_t)HWs[i] * 4; }
    u32* bsumB = (u32*)(ws + off); off += 256 * 4;
    u32* bucketCnt   = (u32*)(ws + off); off += NBUCK * 4;
    u32* bucketStart = (u32*)(ws + off); off += (NBUCK + 64) * 4;
    u32* bucketCur   = (u32*)(ws + off); off += NBUCK * 4;
    u32* ncells      = (u32*)(ws + off); off += 64 * 4;
    u32* payF        = (u32*)(ws + off);
    size_t needPay = off + (size_t)n * 4;
    size_t offStage = needPay;
    ull* stageK = (ull*)(ws + offStage);
    u32* stageP = (u32*)(ws + offStage + (size_t)NBUCK * CAPB * 8);
    size_t needStaged = offStage + (size_t)NBUCK * CAPB * 12;

    bool haveStage = (ws_size >= needStaged);
    u32* payg = (ws_size >= needPay) ? payF : nullptr;

    // ---- output offsets ----
    size_t offB[3], offL[3], offC[3];
    size_t o = 0;
    for (int i = 0; i < 3; ++i) { offB[i] = o; o += (size_t)MAX_RAY * HWs[i]; }
    for (int i = 0; i < 3; ++i) { offL[i] = o; o += (size_t)HWs[i]; }
    for (int i = 0; i < 3; ++i) { offC[i] = o; o += 2 * (size_t)HWs[i]; }

    hipMemsetAsync(bucketCnt, 0, NBUCK * 4, stream);

    const int nblkPts = (n + PTS_PER_BLK - 1) / PTS_PER_BLK;

    if (haveStage) {
        bucket_scatter_fixed<<<nblkPts, 256, 0, stream>>>(coords, depth, pm, bucketCnt,
                                                          stageK, stageP, n);
        bucket_scan2<<<1, NBUCK, 0, stream>>>(bucketCnt, bucketStart, startsM);
        place_fused<<<NBUCK, 256, 0, stream>>>(stageK, stageP, bucketCnt, bucketStart,
                                               startsM, keysF, payF);
        payg = payF;
    } else {
        bucket_hist_kernel<<<nblkPts, 256, 0, stream>>>(coords, bucketCnt, n);
        bucket_scan_kernel<<<1, NBUCK, 0, stream>>>(bucketCnt, bucketStart, bucketCur, n);
        bucket_scatter_kernel<<<nblkPts, 256, 0, stream>>>(coords, depth, pm, bucketCur,
                                                           keysF, payg, n);
        cell_hist_kernel<<<NBUCK, 256, 0, stream>>>(keysF, bucketStart, countsM);
        scanA_final2<<<NBLK0, 256, 0, stream>>>(countsM, bucketStart, startsM);
        place_kernel<<<NBUCK, 256, 0, stream>>>(keysF, payg, bucketStart, startsM);
    }

    SegArgs sa;
    for (int i = 0; i < 3; ++i) {
        sa.segid[i]  = segid[i];
        sa.lens[i]   = out + offL[i];
        sa.canvas[i] = out + offC[i];
    }
    scanB_partial<<<NBLKB, 256, 0, stream>>>(startsM, bsumB);
    scanB_final<<<NBLKB, 256, 0, stream>>>(startsM, bsumB, sa, ncells);

    EmitArgs ea;
    for (int i = 0; i < 3; ++i) {
        ea.segid[i] = segid[i];
        ea.batch[i] = out + offB[i];
    }
    emit_kernel<<<5376, 256, 0, stream>>>(pm, payg, startsM, keysF, ea);
    zero_tail_kernel<<<1344, 256, 0, stream>>>(ncells,
        out + offB[0], out + offB[1], out + offB[2],
        out + offL[0], out + offL[1], out + offL[2],
        out + offC[0], out + offC[1], out + offC[2]);
}

// Round 13
// 172.116 us; speedup vs baseline: 3.3902x; 1.0373x over previous
//
#include <hip/hip_runtime.h>
#include <stdint.h>

#define MAX_RAY 100
#define NBUCK 512          // coarse buckets = top 9 Morton bits
#define PTS_PER_BLK 4096
#define PLACE_CAP 5120     // old-path LDS stage cap
#define CAPB 5120          // staging region capacity per bucket (mean 3906, sigma 62 -> 19 sigma)
typedef unsigned long long ull;
typedef uint32_t u32;

#define N0 262144          // finest cells
#define NBLK0 128          // N0 / 2048
#define NBLKB2 1344        // 1024 + 256 + 64 segid-scan blocks (256 cells each)
#define LKELEMS 288        // per-wave LDS key pool (emit): max(16*18, 4*66, 256)

// ---------- helpers ----------
__device__ __forceinline__ u32 spread1(u32 v) {
    v &= 0x1FF;
    v = (v | (v << 8)) & 0x00FF00FF;
    v = (v | (v << 4)) & 0x0F0F0F0F;
    v = (v | (v << 2)) & 0x33333333;
    v = (v | (v << 1)) & 0x55555555;
    return v;
}
__device__ __forceinline__ u32 morton2(u32 i, u32 j) { return (spread1(i) << 1) | spread1(j); }

__device__ __forceinline__ void px_of(const float2 cv, int& pi, int& pj) {
    float fi = fminf(fmaxf(cv.x * 512.0f, 0.0f), 511.0f);
    float fj = fminf(fmaxf(cv.y * 512.0f, 0.0f), 511.0f);
    pi = (int)fi;   // trunc == floor for non-negative; bit-identical to reference
    pj = (int)fj;
}

// ================= OLD PATH (fallback when ws too small) =================
__global__ __launch_bounds__(256)
void bucket_hist_kernel(const float2* __restrict__ coords,
                        u32* __restrict__ bucketCnt, int n) {
    __shared__ u32 lh[NBUCK];
    int t = threadIdx.x;
    for (int i = t; i < NBUCK; i += 256) lh[i] = 0;
    __syncthreads();
    int base = blockIdx.x * PTS_PER_BLK;
#pragma unroll
    for (int k = 0; k < 16; ++k) {
        int p = base + k * 256 + t;
        if (p < n) {
            int pi, pj; px_of(coords[p], pi, pj);
            atomicAdd(&lh[morton2(pi, pj) >> 9], 1u);
        }
    }
    __syncthreads();
    for (int i = t; i < NBUCK; i += 256)
        if (lh[i]) atomicAdd(&bucketCnt[i], lh[i]);
}

__global__ __launch_bounds__(NBUCK)
void bucket_scan_kernel(const u32* __restrict__ bucketCnt,
                        u32* __restrict__ bucketStart,
                        u32* __restrict__ bucketCur, int n) {
    __shared__ u32 part[NBUCK];
    int t = threadIdx.x;
    u32 v = bucketCnt[t];
    part[t] = v; __syncthreads();
    for (int off = 1; off < NBUCK; off <<= 1) {
        u32 x = part[t]; u32 a = (t >= off) ? part[t - off] : 0u;
        __syncthreads(); part[t] = x + a; __syncthreads();
    }
    u32 ex = part[t] - v;
    bucketStart[t] = ex; bucketCur[t] = ex;
    if (t == NBUCK - 1) bucketStart[NBUCK] = (u32)n;
}

__global__ __launch_bounds__(256)
void bucket_scatter_kernel(const float2* __restrict__ coords,
                           const float* __restrict__ depth,
                           const float* __restrict__ pm,
                           u32* __restrict__ bucketCur,
                           ull* __restrict__ keys,
                           u32* __restrict__ payg,     // may be null
                           int n) {
    __shared__ u32 lhist[NBUCK], lofs[NBUCK], lcur[NBUCK], gbase[NBUCK], temp[256];
    __shared__ ull stage[PTS_PER_BLK];
    int t = threadIdx.x;
    for (int i = t; i < NBUCK; i += 256) lhist[i] = 0;
    __syncthreads();
    int base = blockIdx.x * PTS_PER_BLK;
    ull ent[16]; u32 cb[16]; u32 pos[16];
#pragma unroll
    for (int k = 0; k < 16; ++k) {
        int p = base + k * 256 + t;
        cb[k] = 0xFFFFFFFFu;
        if (p < n) {
            int pi, pj; px_of(coords[p], pi, pj);
            u32 m = morton2(pi, pj);
            cb[k] = m >> 9;
            ent[k] = ((ull)__float_as_uint(depth[p]) << 32)
                   | ((ull)(m & 511u) << 21) | (ull)(u32)p;
            atomicAdd(&lhist[cb[k]], 1u);
        }
    }
    __syncthreads();
    u32 pv = lhist[2 * t] + lhist[2 * t + 1];
    temp[t] = pv; __syncthreads();
    for (int off = 1; off < 256; off <<= 1) {
        u32 x = temp[t]; u32 a = (t >= off) ? temp[t - off] : 0u;
        __syncthreads(); temp[t] = x + a; __syncthreads();
    }
    u32 pb = temp[t] - pv;
    lofs[2 * t] = pb;                  lofs[2 * t + 1] = pb + lhist[2 * t];
    lcur[2 * t] = pb;                  lcur[2 * t + 1] = pb + lhist[2 * t];
    __syncthreads();
#pragma unroll
    for (int k = 0; k < 16; ++k) {
        if (cb[k] != 0xFFFFFFFFu) {
            pos[k] = atomicAdd(&lcur[cb[k]], 1u);
            stage[pos[k]] = ent[k];
        }
    }
    __syncthreads();
    for (int b = t; b < NBUCK; b += 256) {
        u32 cnt = lhist[b];
        if (!cnt) continue;
        u32 gb = atomicAdd(&bucketCur[b], cnt);
        gbase[b] = gb;
        u32 lo = lofs[b];
        for (u32 i = 0; i < cnt; ++i) keys[gb + i] = stage[lo + i];
    }
    if (payg) {
        __syncthreads();
        u32* pstage = (u32*)stage;
#pragma unroll
        for (int k = 0; k < 16; ++k) {
            int p = base + k * 256 + t;
            if (cb[k] != 0xFFFFFFFFu) pstage[pos[k]] = __float_as_uint(pm[p]);
        }
        __syncthreads();
        for (int b = t; b < NBUCK; b += 256) {
            u32 cnt = lhist[b];
            if (!cnt) continue;
            u32 gb = gbase[b], lo = lofs[b];
            for (u32 i = 0; i < cnt; ++i) payg[gb + i] = pstage[lo + i];
        }
    }
}

__global__ __launch_bounds__(256)
void cell_hist_kernel(const ull* __restrict__ keys,
                      const u32* __restrict__ bucketStart,
                      u32* __restrict__ countsM) {
    __shared__ u32 lh[NBUCK];
    int b = blockIdx.x, t = threadIdx.x;
    for (int i = t; i < NBUCK; i += 256) lh[i] = 0;
    __syncthreads();
    u32 s = bucketStart[b], e = bucketStart[b + 1];
    for (u32 i = s + t; i < e; i += 256) {
        u32 mlow = (u32)(keys[i] >> 21) & 511u;
        atomicAdd(&lh[mlow], 1u);
    }
    __syncthreads();
    for (int i = t; i < NBUCK; i += 256) countsM[(b << 9) + i] = lh[i];
}

__global__ __launch_bounds__(256)
void scanA_final2(const u32* __restrict__ countsM,
                  const u32* __restrict__ bucketStart,
                  u32* __restrict__ startsM) {
    int b = blockIdx.x, t = threadIdx.x;
    const uint4* src = (const uint4*)(countsM + b * 2048);
    uint4 a = src[t * 2], c = src[t * 2 + 1];
    u32 e[8] = {a.x, a.y, a.z, a.w, c.x, c.y, c.z, c.w};
    u32 tsum = 0;
#pragma unroll
    for (int k = 0; k < 8; ++k) tsum += e[k];
    __shared__ u32 part[256];
    part[t] = tsum; __syncthreads();
    for (int off = 1; off < 256; off <<= 1) {
        u32 x = part[t];
        u32 ad = (t >= off) ? part[t - off] : 0;
        __syncthreads(); part[t] = x + ad; __syncthreads();
    }
    u32 run = bucketStart[b * 4] + part[t] - tsum;
    u32 o[8];
#pragma unroll
    for (int k = 0; k < 8; ++k) { o[k] = run; run += e[k]; }
    uint4* d1 = (uint4*)(startsM + b * 2048);
    d1[t * 2]     = make_uint4(o[0], o[1], o[2], o[3]);
    d1[t * 2 + 1] = make_uint4(o[4], o[5], o[6], o[7]);
    if (b == NBLK0 - 1 && t == 255) startsM[N0] = run;
}

__global__ __launch_bounds__(256)
void place_kernel(ull* __restrict__ keys,
                  u32* __restrict__ payg,              // may be null
                  const u32* __restrict__ bucketStart,
                  const u32* __restrict__ startsM) {
    __shared__ ull stage[PLACE_CAP];
    __shared__ u32 pstage[PLACE_CAP];
    __shared__ u32 cur[NBUCK];
    int b = blockIdx.x, t = threadIdx.x;
    u32 s = bucketStart[b], e = bucketStart[b + 1];
    u32 cnt = e - s;
    u32 lim = cnt < PLACE_CAP ? cnt : PLACE_CAP;
    for (u32 i = t; i < lim; i += 256) stage[i] = keys[s + i];
    if (payg) for (u32 i = t; i < lim; i += 256) pstage[i] = payg[s + i];
    for (int i = t; i < NBUCK; i += 256) cur[i] = startsM[(b << 9) + i];
    __syncthreads();
    for (u32 i = t; i < lim; i += 256) {
        ull en = stage[i];
        u32 mlow = (u32)(en >> 21) & 511u;
        u32 slot = atomicAdd(&cur[mlow], 1u);
        keys[slot] = ((en >> 32) << 32) | (en & 0x1FFFFFull);
        if (payg) payg[slot] = pstage[i];
    }
}

// ================= NEW PATH: fixed-capacity staging =================
__global__ __launch_bounds__(256)
void bucket_scatter_fixed(const float2* __restrict__ coords,
                          const float* __restrict__ depth,
                          const float* __restrict__ pm,
                          u32* __restrict__ bucketCnt,
                          ull* __restrict__ stageK,
                          u32* __restrict__ stageP,
                          int n) {
    __shared__ u32 lhist[NBUCK], lofs[NBUCK], lcur[NBUCK], gbase[NBUCK], temp[256];
    __shared__ ull stage[PTS_PER_BLK];
    int t = threadIdx.x;
    for (int i = t; i < NBUCK; i += 256) lhist[i] = 0;
    __syncthreads();
    int base = blockIdx.x * PTS_PER_BLK;
    ull ent[16]; u32 cb[16]; u32 pos[16];
#pragma unroll
    for (int k = 0; k < 16; ++k) {
        int p = base + k * 256 + t;
        cb[k] = 0xFFFFFFFFu;
        if (p < n) {
            int pi, pj; px_of(coords[p], pi, pj);
            u32 m = morton2(pi, pj);
            cb[k] = m >> 9;
            ent[k] = ((ull)__float_as_uint(depth[p]) << 32)
                   | ((ull)(m & 511u) << 21) | (ull)(u32)p;
            atomicAdd(&lhist[cb[k]], 1u);
        }
    }
    __syncthreads();
    u32 pv = lhist[2 * t] + lhist[2 * t + 1];
    temp[t] = pv; __syncthreads();
    for (int off = 1; off < 256; off <<= 1) {
        u32 x = temp[t]; u32 a = (t >= off) ? temp[t - off] : 0u;
        __syncthreads(); temp[t] = x + a; __syncthreads();
    }
    u32 pb = temp[t] - pv;
    lofs[2 * t] = pb;                  lofs[2 * t + 1] = pb + lhist[2 * t];
    lcur[2 * t] = pb;                  lcur[2 * t + 1] = pb + lhist[2 * t];
    __syncthreads();
#pragma unroll
    for (int k = 0; k < 16; ++k) {
        if (cb[k] != 0xFFFFFFFFu) {
            pos[k] = atomicAdd(&lcur[cb[k]], 1u);
            stage[pos[k]] = ent[k];
        }
    }
    __syncthreads();
    for (int b = t; b < NBUCK; b += 256) {
        u32 cnt = lhist[b];
        if (!cnt) { gbase[b] = 0xFFFFFFFFu; continue; }
        u32 gb0 = atomicAdd(&bucketCnt[b], cnt);
        gbase[b] = gb0;
        u32 wr = (gb0 >= CAPB) ? 0u : ((cnt < CAPB - gb0) ? cnt : CAPB - gb0);
        u32 gb = b * CAPB + gb0, lo = lofs[b];
        for (u32 i = 0; i < wr; ++i) stageK[gb + i] = stage[lo + i];
    }
    __syncthreads();
    u32* pstage = (u32*)stage;
#pragma unroll
    for (int k = 0; k < 16; ++k) {
        int p = base + k * 256 + t;
        if (cb[k] != 0xFFFFFFFFu) pstage[pos[k]] = __float_as_uint(pm[p]);
    }
    __syncthreads();
    for (int b = t; b < NBUCK; b += 256) {
        u32 cnt = lhist[b], gb0 = gbase[b];
        if (!cnt || gb0 == 0xFFFFFFFFu) continue;
        u32 wr = (gb0 >= CAPB) ? 0u : ((cnt < CAPB - gb0) ? cnt : CAPB - gb0);
        u32 gb = b * CAPB + gb0, lo = lofs[b];
        for (u32 i = 0; i < wr; ++i) stageP[gb + i] = pstage[lo + i];
    }
}

__global__ __launch_bounds__(NBUCK)
void bucket_scan2(const u32* __restrict__ bucketCnt,
                  u32* __restrict__ bucketStart,
                  u32* __restrict__ startsM) {
    __shared__ u32 part[NBUCK];
    int t = threadIdx.x;
    u32 v = bucketCnt[t]; if (v > CAPB) v = CAPB;
    part[t] = v; __syncthreads();
    for (int off = 1; off < NBUCK; off <<= 1) {
        u32 x = part[t]; u32 a = (t >= off) ? part[t - off] : 0u;
        __syncthreads(); part[t] = x + a; __syncthreads();
    }
    bucketStart[t] = part[t] - v;
    if (t == NBUCK - 1) { bucketStart[NBUCK] = part[t]; startsM[N0] = part[t]; }
}

// fused: cell-hist -> in-block scan -> write startsM slice -> place (L2-hot re-read)
__global__ __launch_bounds__(256)
void place_fused(const ull* __restrict__ stageK,
                 const u32* __restrict__ stageP,
                 const u32* __restrict__ bucketCnt,
                 const u32* __restrict__ bucketStart,
                 u32* __restrict__ startsM,
                 ull* __restrict__ keysF,
                 u32* __restrict__ payF) {
    __shared__ u32 lh[NBUCK], cur[NBUCK], temp[256];
    int b = blockIdx.x, t = threadIdx.x;
    u32 cnt = bucketCnt[b]; if (cnt > CAPB) cnt = CAPB;
    u32 s = (u32)b * CAPB;
    for (int i = t; i < NBUCK; i += 256) lh[i] = 0;
    __syncthreads();
    for (u32 i = t; i < cnt; i += 256) {
        u32 mlow = (u32)(stageK[s + i] >> 21) & 511u;
        atomicAdd(&lh[mlow], 1u);
    }
    __syncthreads();
    u32 bs = bucketStart[b];
    u32 pv = lh[2 * t] + lh[2 * t + 1];
    temp[t] = pv; __syncthreads();
    for (int off = 1; off < 256; off <<= 1) {
        u32 x = temp[t]; u32 a = (t >= off) ? temp[t - off] : 0u;
        __syncthreads(); temp[t] = x + a; __syncthreads();
    }
    u32 pb = temp[t] - pv;
    u32 st0 = bs + pb, st1 = bs + pb + lh[2 * t];
    cur[2 * t] = st0; cur[2 * t + 1] = st1;
    uint2* d = (uint2*)(startsM + (b << 9));
    d[t] = make_uint2(st0, st1);
    __syncthreads();
    for (u32 i = t; i < cnt; i += 256) {
        ull en = stageK[s + i];
        u32 mlow = (u32)(en >> 21) & 511u;
        u32 slot = atomicAdd(&cur[mlow], 1u);
        keysF[slot] = ((en >> 32) << 32) | (en & 0x1FFFFFull);   // strip mlow
        payF[slot] = stageP[s + i];
    }
}

// ---------- segid scans (256 cells per block, 1 cell/thread) ----------
__device__ __forceinline__ void blk_map2(int b, int& si, int& bb) {
    if (b < 1024)      { si = 0; bb = b; }
    else if (b < 1280) { si = 1; bb = b - 1024; }
    else               { si = 2; bb = b - 1280; }
}
__device__ __forceinline__ u32 cell_cnt(const u32* startsM, int c, int wbits, int si) {
    u32 ci = (u32)c >> wbits, cj = (u32)c & ((1u << wbits) - 1u);
    u32 mb = morton2(ci, cj) << (2 * si);
    return startsM[mb + (1u << (2 * si))] - startsM[mb];
}

__global__ __launch_bounds__(256)
void scanB_partial(const u32* __restrict__ startsM, u32* __restrict__ bsumB) {
    int si, bb; blk_map2(blockIdx.x, si, bb);
    int wbits = 9 - si, t = threadIdx.x;
    int c = bb * 256 + t;
    u32 flg = (cell_cnt(startsM, c, wbits, si) > 0) ? 1u : 0u;
    __shared__ u32 red[256];
    red[t] = flg; __syncthreads();
    for (int off = 128; off; off >>= 1) {
        if (t < off) red[t] += red[t + off];
        __syncthreads();
    }
    if (!t) bsumB[blockIdx.x] = red[0];
}

struct SegArgs {
    u32* segid[3]; float* lens[3]; float* canvas[3];
};
// fused: computes its own segment-prefix from bsumB; last block per segment -> ncells.
__global__ __launch_bounds__(256)
void scanB_final(const u32* __restrict__ startsM, const u32* __restrict__ bsumB,
                 SegArgs sa, u32* __restrict__ ncells) {
    int si, bb; blk_map2(blockIdx.x, si, bb);
    int wbits = 9 - si, t = threadIdx.x;
    int segStart = (si == 0) ? 0 : (si == 1) ? 1024 : 1280;
    __shared__ u32 s_bpre;
    if (t < 64) {
        u32 acc = 0;
        for (int j = segStart + t; j < (int)blockIdx.x; j += 64) acc += bsumB[j];
        for (int o = 32; o; o >>= 1) acc += __shfl_down(acc, o);
        if (t == 0) s_bpre = acc;
    }
    int c = bb * 256 + t;
    u32 cnt = cell_cnt(startsM, c, wbits, si);
    u32 flg = cnt ? 1u : 0u;
    __shared__ u32 part[256];
    part[t] = flg; __syncthreads();          // also publishes s_bpre
    for (int off = 1; off < 256; off <<= 1) {
        u32 x = part[t];
        u32 ad = (t >= off) ? part[t - off] : 0u;
        __syncthreads(); part[t] = x + ad; __syncthreads();
    }
    u32 run = s_bpre + part[t] - flg;
    u32* segid = sa.segid[si];
    float* lens = sa.lens[si];
    float* canvas = sa.canvas[si];
    u32 wmask = (1u << wbits) - 1u;
    segid[c] = run;
    if (flg) {
        u32 len = cnt < MAX_RAY ? cnt : MAX_RAY;
        lens[run] = (float)len;
        canvas[2 * run]     = (float)((u32)c >> wbits);
        canvas[2 * run + 1] = (float)((u32)c & wmask);
    }
    if (t == 255 && (blockIdx.x == 1023 || blockIdx.x == 1279 || blockIdx.x == 1343))
        ncells[si] = run + flg;              // segment total occupied cells
}

// ---------- emit: grouped LDS-broadcast rank; tile [64][101] ----------
struct CellRegs { ull k0, k1, k2, k3; u32 p0, p1, p2, p3; };
struct __attribute__((packed, aligned(8))) U2 { ull x, y; };
struct __attribute__((packed, aligned(4))) U4 { u32 x, y, z, w; };

template<int CAP>
__device__ __forceinline__ void loadCellG(const ull* __restrict__ keys,
                                          const u32* __restrict__ payg,
                                          const float* __restrict__ pm,
                                          u32 s0, u32 cnt, u32 li, CellRegs& c) {
    c.k0 = c.k1 = c.k2 = c.k3 = ~0ull;
    c.p0 = c.p1 = c.p2 = c.p3 = 0u;
    u32 m = li * 4u;
    if (cnt == 0u || cnt > (u32)CAP || m >= cnt) return;
    const U2* kp = (const U2*)(keys + s0 + m);
    U2 a = kp[0], b = kp[1];
    c.k0 = a.x; c.k1 = a.y; c.k2 = b.x; c.k3 = b.y;
    if (payg) {
        U4 pv = *(const U4*)(payg + s0 + m);
        c.p0 = pv.x; c.p1 = pv.y; c.p2 = pv.z; c.p3 = pv.w;
    } else {
        c.p0 = __float_as_uint(pm[(u32)(c.k0 & 0x1FFFFFull)]);
        if (m + 1 < cnt) c.p1 = __float_as_uint(pm[(u32)(c.k1 & 0x1FFFFFull)]);
        if (m + 2 < cnt) c.p2 = __float_as_uint(pm[(u32)(c.k2 & 0x1FFFFFull)]);
        if (m + 3 < cnt) c.p3 = __float_as_uint(pm[(u32)(c.k3 & 0x1FFFFFull)]);
    }
    if (m + 1 >= cnt) c.k1 = ~0ull;
    if (m + 2 >= cnt) c.k2 = ~0ull;
    if (m + 3 >= cnt) c.k3 = ~0ull;
}

template<int SI>
__device__ __forceinline__ void emit_body(
    const float* __restrict__ pm, const u32* __restrict__ payload,
    const u32* __restrict__ startsM, const ull* __restrict__ keys,
    const u32* __restrict__ segid, float* __restrict__ batch, int bb,
    float (&tile)[64][101], ull (&lkAll)[4][LKELEMS],
    u32 (&s_s0)[64], u32 (&s_cnt)[64], u32 (&s_seg)[64],
    u32 (&ovfl)[64], u32& ovflN)
{
    constexpr int WB   = 9 - SI;
    constexpr int G    = (SI == 0) ? 4 : (SI == 1) ? 16 : 64;    // lanes per cell
    constexpr int CAP  = G * 4;                                   // si0: 16 keys
    constexpr int STRD = (SI == 0) ? 18 : (SI == 1) ? 66 : 256;   // padded stride
    constexpr int NG   = 64 / G;
    constexpr int ROUNDS = 64 / (4 * NG);                         // si0: 1 round
    const int HW = 1 << (2 * WB);

    int t = threadIdx.x, wave = t >> 6, lane = t & 63;
    int gi = lane / G, li = lane % G;
    ull* lk = &lkAll[wave][0];

    if (t == 0) ovflN = 0;
    if (t < 64) {
        int cell = bb * 64 + t;
        u32 ci = (u32)cell >> WB, cj = (u32)cell & ((1u << WB) - 1u);
        u32 mb = morton2(ci, cj) << (2 * SI);
        u32 s0 = startsM[mb];
        s_s0[t]  = s0;
        s_cnt[t] = startsM[mb + (1u << (2 * SI))] - s0;
        s_seg[t] = segid[cell];
    }
    __syncthreads();

    CellRegs cur, nxt;
    {
        int lc0 = wave * NG + gi;
        loadCellG<CAP>(keys, payload, pm, s_s0[lc0], s_cnt[lc0], (u32)li, cur);
    }
#pragma unroll
    for (int rnd = 0; rnd < ROUNDS; ++rnd) {
        int lc = (rnd * 4 + wave) * NG + gi;
        u32 cnt = s_cnt[lc], m = (u32)li * 4u;
        bool fits = (cnt <= (u32)CAP);
        if (fits && m < cnt) {
            ull* dst = lk + gi * STRD + m;
            dst[0] = cur.k0; dst[1] = cur.k1; dst[2] = cur.k2; dst[3] = cur.k3;
        }
        if (!fits && li == 0) {
            u32 ix = atomicAdd(&ovflN, 1u);
            ovfl[ix] = (u32)lc;
        }
        if (rnd + 1 < ROUNDS) {
            int lc2 = ((rnd + 1) * 4 + wave) * NG + gi;
            loadCellG<CAP>(keys, payload, pm, s_s0[lc2], s_cnt[lc2], (u32)li, nxt);
        }
        if (cnt && fits) {
            asm volatile("s_waitcnt lgkmcnt(0)" ::: "memory");
            u32 cntR = (cnt + 3u) & ~3u;
            u32 r0 = 0, r1 = 0, r2 = 0, r3 = 0;
            const ull* kb = lk + gi * STRD;
            for (u32 j = 0; j < cntR; j += 4) {
                U2 a  = *(const U2*)(kb + j);
                U2 b2 = *(const U2*)(kb + j + 2);
                r0 += (a.x < cur.k0) + (a.y < cur.k0) + (b2.x < cur.k0) + (b2.y < cur.k0);
                r1 += (a.x < cur.k1) + (a.y < cur.k1) + (b2.x < cur.k1) + (b2.y < cur.k1);
                r2 += (a.x < cur.k2) + (a.y < cur.k2) + (b2.x < cur.k2) + (b2.y < cur.k2);
                r3 += (a.x < cur.k3) + (a.y < cur.k3) + (b2.x < cur.k3) + (b2.y < cur.k3);
            }
            if (m < cnt) {
                if (r0 < MAX_RAY)                 tile[lc][r0] = __uint_as_float(cur.p0);
                if (m + 1 < cnt && r1 < MAX_RAY)  tile[lc][r1] = __uint_as_float(cur.p1);
                if (m + 2 < cnt && r2 < MAX_RAY)  tile[lc][r2] = __uint_as_float(cur.p2);
                if (m + 3 < cnt && r3 < MAX_RAY)  tile[lc][r3] = __uint_as_float(cur.p3);
            }
        }
        cur = nxt;
    }
    __syncthreads();

    u32 no = ovflN;
    if (no && wave == 0) {
        for (u32 o = 0; o < no; ++o) {
            int lc = (int)ovfl[o];
            u32 s0 = s_s0[lc], cnt = s_cnt[lc];
            for (u32 i = lane; i < cnt; i += 64) {
                ull mk = keys[s0 + i];
                u32 r = 0;
                for (u32 j = 0; j < cnt; ++j) r += (keys[s0 + j] < mk) ? 1u : 0u;
                if (r < MAX_RAY) {
                    u32 pv = payload ? payload[s0 + i]
                                     : __float_as_uint(pm[(u32)(mk & 0x1FFFFFull)]);
                    tile[lc][r] = __uint_as_float(pv);
                }
            }
        }
    }
    __syncthreads();

    u32 myCnt = s_cnt[lane], mySeg = s_seg[lane];
    u32 lim = myCnt < MAX_RAY ? myCnt : MAX_RAY;
    for (int r = wave; r < MAX_RAY; r += 4) {
        if (myCnt) batch[(size_t)r * (size_t)HW + mySeg] = (r < (int)lim) ? tile[lane][r] : 0.0f;
    }
}

struct EmitArgs {
    const u32* segid[3]; float* batch[3];
};
__global__ __launch_bounds__(256)
void emit_kernel(const float* __restrict__ pm,
                 const u32* __restrict__ payload,
                 const u32* __restrict__ startsM,
                 const ull* __restrict__ keys,
                 EmitArgs ea) {
    __shared__ float tile[64][101];
    __shared__ __align__(16) ull lkAll[4][LKELEMS];
    __shared__ u32 s_s0[64], s_cnt[64], s_seg[64], ovfl[64], ovflN;

    int b = blockIdx.x;
    if (b < 256)
        emit_body<2>(pm, payload, startsM, keys, ea.segid[2], ea.batch[2], b,
                     tile, lkAll, s_s0, s_cnt, s_seg, ovfl, ovflN);
    else if (b < 1280)
        emit_body<1>(pm, payload, startsM, keys, ea.segid[1], ea.batch[1], b - 256,
                     tile, lkAll, s_s0, s_cnt, s_seg, ovfl, ovflN);
    else
        emit_body<0>(pm, payload, startsM, keys, ea.segid[0], ea.batch[0], b - 1280,
                     tile, lkAll, s_s0, s_cnt, s_seg, ovfl, ovflN);
}

// ---------- zero tails of batch + lens + canvas ----------
__global__ __launch_bounds__(256)
void zero_tail_kernel(const u32* __restrict__ ncells,
                      float* __restrict__ b0, float* __restrict__ b1,
                      float* __restrict__ b2,
                      float* __restrict__ l0, float* __restrict__ l1,
                      float* __restrict__ l2,
                      float* __restrict__ c0, float* __restrict__ c1,
                      float* __restrict__ c2) {
    int b = blockIdx.x, si, col; float* base; float* lens; float* canv; int HW;
    if (b < 1024)      { si = 0; base = b0; lens = l0; canv = c0; HW = 262144; col = b * 256 + (int)threadIdx.x; }
    else if (b < 1280) { si = 1; base = b1; lens = l1; canv = c1; HW = 65536;  col = (b - 1024) * 256 + (int)threadIdx.x; }
    else               { si = 2; base = b2; lens = l2; canv = c2; HW = 16384;  col = (b - 1280) * 256 + (int)threadIdx.x; }
    if ((u32)col >= ncells[si]) {
        lens[col] = 0.0f;
        canv[2 * col] = 0.0f; canv[2 * col + 1] = 0.0f;
        for (int r = 0; r < MAX_RAY; ++r)
            base[(size_t)r * (size_t)HW + col] = 0.0f;
    }
}

extern "C" void kernel_launch(void* const* d_in, const int* in_sizes, int n_in,
                              void* d_out, int out_size, void* d_ws, size_t ws_size,
                              hipStream_t stream) {
    const float2* coords = (const float2*)d_in[0];
    const float*  depth  = (const float*)d_in[1];
    const float*  pm     = (const float*)d_in[2];
    float* out = (float*)d_out;
    const int n = in_sizes[1];

    const int HWs[3] = {512 * 512, 256 * 256, 128 * 128};

    // ---- workspace layout ----
    char* ws = (char*)d_ws;
    size_t off = 0;
    ull* keysF   = (ull*)(ws + off); off += (size_t)n * 8;
    u32* countsM = (u32*)(ws + off); off += (size_t)N0 * 4;
    u32* startsM = (u32*)(ws + off); off += (size_t)(N0 + 64) * 4;
    u32* segid[3];
    for (int i = 0; i < 3; ++i) { segid[i] = (u32*)(ws + off); off += (size_t)HWs[i] * 4; }
    u32* bsumB = (u32*)(ws + off); off += 2048 * 4;
    u32* bucketCnt   = (u32*)(ws + off); off += NBUCK * 4;
    u32* bucketStart = (u32*)(ws + off); off += (NBUCK + 64) * 4;
    u32* bucketCur   = (u32*)(ws + off); off += NBUCK * 4;
    u32* ncells      = (u32*)(ws + off); off += 64 * 4;
    u32* payF        = (u32*)(ws + off);
    size_t needPay = off + (size_t)n * 4;
    size_t offStage = needPay;
    ull* stageK = (ull*)(ws + offStage);
    u32* stageP = (u32*)(ws + offStage + (size_t)NBUCK * CAPB * 8);
    size_t needStaged = offStage + (size_t)NBUCK * CAPB * 12;

    bool haveStage = (ws_size >= needStaged);
    u32* payg = (ws_size >= needPay) ? payF : nullptr;

    // ---- output offsets ----
    size_t offB[3], offL[3], offC[3];
    size_t o = 0;
    for (int i = 0; i < 3; ++i) { offB[i] = o; o += (size_t)MAX_RAY * HWs[i]; }
    for (int i = 0; i < 3; ++i) { offL[i] = o; o += (size_t)HWs[i]; }
    for (int i = 0; i < 3; ++i) { offC[i] = o; o += 2 * (size_t)HWs[i]; }

    hipMemsetAsync(bucketCnt, 0, NBUCK * 4, stream);

    const int nblkPts = (n + PTS_PER_BLK - 1) / PTS_PER_BLK;

    if (haveStage) {
        bucket_scatter_fixed<<<nblkPts, 256, 0, stream>>>(coords, depth, pm, bucketCnt,
                                                          stageK, stageP, n);
        bucket_scan2<<<1, NBUCK, 0, stream>>>(bucketCnt, bucketStart, startsM);
        place_fused<<<NBUCK, 256, 0, stream>>>(stageK, stageP, bucketCnt, bucketStart,
                                               startsM, keysF, payF);
        payg = payF;
    } else {
        bucket_hist_kernel<<<nblkPts, 256, 0, stream>>>(coords, bucketCnt, n);
        bucket_scan_kernel<<<1, NBUCK, 0, stream>>>(bucketCnt, bucketStart, bucketCur, n);
        bucket_scatter_kernel<<<nblkPts, 256, 0, stream>>>(coords, depth, pm, bucketCur,
                                                           keysF, payg, n);
        cell_hist_kernel<<<NBUCK, 256, 0, stream>>>(keysF, bucketStart, countsM);
        scanA_final2<<<NBLK0, 256, 0, stream>>>(countsM, bucketStart, startsM);
        place_kernel<<<NBUCK, 256, 0, stream>>>(keysF, payg, bucketStart, startsM);
    }

    SegArgs sa;
    for (int i = 0; i < 3; ++i) {
        sa.segid[i]  = segid[i];
        sa.lens[i]   = out + offL[i];
        sa.canvas[i] = out + offC[i];
    }
    scanB_partial<<<NBLKB2, 256, 0, stream>>>(startsM, bsumB);
    scanB_final<<<NBLKB2, 256, 0, stream>>>(startsM, bsumB, sa, ncells);

    EmitArgs ea;
    for (int i = 0; i < 3; ++i) {
        ea.segid[i] = segid[i];
        ea.batch[i] = out + offB[i];
    }
    emit_kernel<<<5376, 256, 0, stream>>>(pm, payg, startsM, keysF, ea);
    zero_tail_kernel<<<1344, 256, 0, stream>>>(ncells,
        out + offB[0], out + offB[1], out + offB[2],
        out + offL[0], out + offL[1], out + offL[2],
        out + offC[0], out + offC[1], out + offC[2]);
}

// Round 14
// 166.787 us; speedup vs baseline: 3.4985x; 1.0320x over previous
//
#include <hip/hip_runtime.h>
#include <stdint.h>

#define MAX_RAY 100
#define NBUCK 512          // coarse buckets = top 9 Morton bits
#define PTS_PER_BLK 4096
#define PLACE_CAP 5120     // old-path LDS stage cap
#define CAPB 5120          // staging region capacity per bucket (mean 3906, sigma 62 -> 19 sigma)
typedef unsigned long long ull;
typedef uint32_t u32;

#define N0 262144          // finest cells
#define NBLK0 128          // N0 / 2048
#define NBLKB2 1344        // 1024 + 256 + 64 segid-scan blocks (256 cells each)
#define NTAIL 64           // tail-zero blocks appended to emit grid
#define LKELEMS 288        // per-wave LDS key pool (emit)

// ---------- helpers ----------
__device__ __forceinline__ u32 spread1(u32 v) {
    v &= 0x1FF;
    v = (v | (v << 8)) & 0x00FF00FF;
    v = (v | (v << 4)) & 0x0F0F0F0F;
    v = (v | (v << 2)) & 0x33333333;
    v = (v | (v << 1)) & 0x55555555;
    return v;
}
__device__ __forceinline__ u32 morton2(u32 i, u32 j) { return (spread1(i) << 1) | spread1(j); }

__device__ __forceinline__ void px_of(const float2 cv, int& pi, int& pj) {
    float fi = fminf(fmaxf(cv.x * 512.0f, 0.0f), 511.0f);
    float fj = fminf(fmaxf(cv.y * 512.0f, 0.0f), 511.0f);
    pi = (int)fi;   // trunc == floor for non-negative; bit-identical to reference
    pj = (int)fj;
}

// ================= OLD PATH (fallback when ws too small) =================
__global__ __launch_bounds__(256)
void bucket_hist_kernel(const float2* __restrict__ coords,
                        u32* __restrict__ bucketCnt, int n) {
    __shared__ u32 lh[NBUCK];
    int t = threadIdx.x;
    for (int i = t; i < NBUCK; i += 256) lh[i] = 0;
    __syncthreads();
    int base = blockIdx.x * PTS_PER_BLK;
#pragma unroll
    for (int k = 0; k < 16; ++k) {
        int p = base + k * 256 + t;
        if (p < n) {
            int pi, pj; px_of(coords[p], pi, pj);
            atomicAdd(&lh[morton2(pi, pj) >> 9], 1u);
        }
    }
    __syncthreads();
    for (int i = t; i < NBUCK; i += 256)
        if (lh[i]) atomicAdd(&bucketCnt[i], lh[i]);
}

__global__ __launch_bounds__(NBUCK)
void bucket_scan_kernel(const u32* __restrict__ bucketCnt,
                        u32* __restrict__ bucketStart,
                        u32* __restrict__ bucketCur, int n) {
    __shared__ u32 part[NBUCK];
    int t = threadIdx.x;
    u32 v = bucketCnt[t];
    part[t] = v; __syncthreads();
    for (int off = 1; off < NBUCK; off <<= 1) {
        u32 x = part[t]; u32 a = (t >= off) ? part[t - off] : 0u;
        __syncthreads(); part[t] = x + a; __syncthreads();
    }
    u32 ex = part[t] - v;
    bucketStart[t] = ex; bucketCur[t] = ex;
    if (t == NBUCK - 1) bucketStart[NBUCK] = (u32)n;
}

__global__ __launch_bounds__(256)
void bucket_scatter_kernel(const float2* __restrict__ coords,
                           const float* __restrict__ depth,
                           const float* __restrict__ pm,
                           u32* __restrict__ bucketCur,
                           ull* __restrict__ keys,
                           u32* __restrict__ payg,     // may be null
                           int n) {
    __shared__ u32 lhist[NBUCK], lofs[NBUCK], lcur[NBUCK], gbase[NBUCK], temp[256];
    __shared__ ull stage[PTS_PER_BLK];
    int t = threadIdx.x;
    for (int i = t; i < NBUCK; i += 256) lhist[i] = 0;
    __syncthreads();
    int base = blockIdx.x * PTS_PER_BLK;
    ull ent[16]; u32 cb[16]; u32 pos[16];
#pragma unroll
    for (int k = 0; k < 16; ++k) {
        int p = base + k * 256 + t;
        cb[k] = 0xFFFFFFFFu;
        if (p < n) {
            int pi, pj; px_of(coords[p], pi, pj);
            u32 m = morton2(pi, pj);
            cb[k] = m >> 9;
            ent[k] = ((ull)__float_as_uint(depth[p]) << 32)
                   | ((ull)(m & 511u) << 21) | (ull)(u32)p;
            atomicAdd(&lhist[cb[k]], 1u);
        }
    }
    __syncthreads();
    u32 pv = lhist[2 * t] + lhist[2 * t + 1];
    temp[t] = pv; __syncthreads();
    for (int off = 1; off < 256; off <<= 1) {
        u32 x = temp[t]; u32 a = (t >= off) ? temp[t - off] : 0u;
        __syncthreads(); temp[t] = x + a; __syncthreads();
    }
    u32 pb = temp[t] - pv;
    lofs[2 * t] = pb;                  lofs[2 * t + 1] = pb + lhist[2 * t];
    lcur[2 * t] = pb;                  lcur[2 * t + 1] = pb + lhist[2 * t];
    __syncthreads();
#pragma unroll
    for (int k = 0; k < 16; ++k) {
        if (cb[k] != 0xFFFFFFFFu) {
            pos[k] = atomicAdd(&lcur[cb[k]], 1u);
            stage[pos[k]] = ent[k];
        }
    }
    __syncthreads();
    for (int b = t; b < NBUCK; b += 256) {
        u32 cnt = lhist[b];
        if (!cnt) continue;
        u32 gb = atomicAdd(&bucketCur[b], cnt);
        gbase[b] = gb;
        u32 lo = lofs[b];
        for (u32 i = 0; i < cnt; ++i) keys[gb + i] = stage[lo + i];
    }
    if (payg) {
        __syncthreads();
        u32* pstage = (u32*)stage;
#pragma unroll
        for (int k = 0; k < 16; ++k) {
            int p = base + k * 256 + t;
            if (cb[k] != 0xFFFFFFFFu) pstage[pos[k]] = __float_as_uint(pm[p]);
        }
        __syncthreads();
        for (int b = t; b < NBUCK; b += 256) {
            u32 cnt = lhist[b];
            if (!cnt) continue;
            u32 gb = gbase[b], lo = lofs[b];
            for (u32 i = 0; i < cnt; ++i) payg[gb + i] = pstage[lo + i];
        }
    }
}

__global__ __launch_bounds__(256)
void cell_hist_kernel(const ull* __restrict__ keys,
                      const u32* __restrict__ bucketStart,
                      u32* __restrict__ countsM) {
    __shared__ u32 lh[NBUCK];
    int b = blockIdx.x, t = threadIdx.x;
    for (int i = t; i < NBUCK; i += 256) lh[i] = 0;
    __syncthreads();
    u32 s = bucketStart[b], e = bucketStart[b + 1];
    for (u32 i = s + t; i < e; i += 256) {
        u32 mlow = (u32)(keys[i] >> 21) & 511u;
        atomicAdd(&lh[mlow], 1u);
    }
    __syncthreads();
    for (int i = t; i < NBUCK; i += 256) countsM[(b << 9) + i] = lh[i];
}

__global__ __launch_bounds__(256)
void scanA_final2(const u32* __restrict__ countsM,
                  const u32* __restrict__ bucketStart,
                  u32* __restrict__ startsM) {
    int b = blockIdx.x, t = threadIdx.x;
    const uint4* src = (const uint4*)(countsM + b * 2048);
    uint4 a = src[t * 2], c = src[t * 2 + 1];
    u32 e[8] = {a.x, a.y, a.z, a.w, c.x, c.y, c.z, c.w};
    u32 tsum = 0;
#pragma unroll
    for (int k = 0; k < 8; ++k) tsum += e[k];
    __shared__ u32 part[256];
    part[t] = tsum; __syncthreads();
    for (int off = 1; off < 256; off <<= 1) {
        u32 x = part[t];
        u32 ad = (t >= off) ? part[t - off] : 0;
        __syncthreads(); part[t] = x + ad; __syncthreads();
    }
    u32 run = bucketStart[b * 4] + part[t] - tsum;
    u32 o[8];
#pragma unroll
    for (int k = 0; k < 8; ++k) { o[k] = run; run += e[k]; }
    uint4* d1 = (uint4*)(startsM + b * 2048);
    d1[t * 2]     = make_uint4(o[0], o[1], o[2], o[3]);
    d1[t * 2 + 1] = make_uint4(o[4], o[5], o[6], o[7]);
    if (b == NBLK0 - 1 && t == 255) startsM[N0] = run;
}

__global__ __launch_bounds__(256)
void place_kernel(ull* __restrict__ keys,
                  u32* __restrict__ payg,              // may be null
                  const u32* __restrict__ bucketStart,
                  const u32* __restrict__ startsM) {
    __shared__ ull stage[PLACE_CAP];
    __shared__ u32 pstage[PLACE_CAP];
    __shared__ u32 cur[NBUCK];
    int b = blockIdx.x, t = threadIdx.x;
    u32 s = bucketStart[b], e = bucketStart[b + 1];
    u32 cnt = e - s;
    u32 lim = cnt < PLACE_CAP ? cnt : PLACE_CAP;
    for (u32 i = t; i < lim; i += 256) stage[i] = keys[s + i];
    if (payg) for (u32 i = t; i < lim; i += 256) pstage[i] = payg[s + i];
    for (int i = t; i < NBUCK; i += 256) cur[i] = startsM[(b << 9) + i];
    __syncthreads();
    for (u32 i = t; i < lim; i += 256) {
        ull en = stage[i];
        u32 mlow = (u32)(en >> 21) & 511u;
        u32 slot = atomicAdd(&cur[mlow], 1u);
        keys[slot] = ((en >> 32) << 32) | (en & 0x1FFFFFull);
        if (payg) payg[slot] = pstage[i];
    }
}

// ================= NEW PATH: fixed-capacity staging =================
__global__ __launch_bounds__(256)
void bucket_scatter_fixed(const float2* __restrict__ coords,
                          const float* __restrict__ depth,
                          const float* __restrict__ pm,
                          u32* __restrict__ bucketCnt,
                          ull* __restrict__ stageK,
                          u32* __restrict__ stageP,
                          int n) {
    __shared__ u32 lhist[NBUCK], lofs[NBUCK], lcur[NBUCK], gbase[NBUCK], temp[256];
    __shared__ ull stage[PTS_PER_BLK];
    int t = threadIdx.x;
    for (int i = t; i < NBUCK; i += 256) lhist[i] = 0;
    __syncthreads();
    int base = blockIdx.x * PTS_PER_BLK;
    ull ent[16]; u32 cb[16]; u32 pos[16];
#pragma unroll
    for (int k = 0; k < 16; ++k) {
        int p = base + k * 256 + t;
        cb[k] = 0xFFFFFFFFu;
        if (p < n) {
            int pi, pj; px_of(coords[p], pi, pj);
            u32 m = morton2(pi, pj);
            cb[k] = m >> 9;
            ent[k] = ((ull)__float_as_uint(depth[p]) << 32)
                   | ((ull)(m & 511u) << 21) | (ull)(u32)p;
            atomicAdd(&lhist[cb[k]], 1u);
        }
    }
    __syncthreads();
    u32 pv = lhist[2 * t] + lhist[2 * t + 1];
    temp[t] = pv; __syncthreads();
    for (int off = 1; off < 256; off <<= 1) {
        u32 x = temp[t]; u32 a = (t >= off) ? temp[t - off] : 0u;
        __syncthreads(); temp[t] = x + a; __syncthreads();
    }
    u32 pb = temp[t] - pv;
    lofs[2 * t] = pb;                  lofs[2 * t + 1] = pb + lhist[2 * t];
    lcur[2 * t] = pb;                  lcur[2 * t + 1] = pb + lhist[2 * t];
    __syncthreads();
#pragma unroll
    for (int k = 0; k < 16; ++k) {
        if (cb[k] != 0xFFFFFFFFu) {
            pos[k] = atomicAdd(&lcur[cb[k]], 1u);
            stage[pos[k]] = ent[k];
        }
    }
    __syncthreads();
    for (int b = t; b < NBUCK; b += 256) {
        u32 cnt = lhist[b];
        if (!cnt) { gbase[b] = 0xFFFFFFFFu; continue; }
        u32 gb0 = atomicAdd(&bucketCnt[b], cnt);
        gbase[b] = gb0;
        u32 wr = (gb0 >= CAPB) ? 0u : ((cnt < CAPB - gb0) ? cnt : CAPB - gb0);
        u32 gb = b * CAPB + gb0, lo = lofs[b];
        for (u32 i = 0; i < wr; ++i) stageK[gb + i] = stage[lo + i];
    }
    __syncthreads();
    u32* pstage = (u32*)stage;
#pragma unroll
    for (int k = 0; k < 16; ++k) {
        int p = base + k * 256 + t;
        if (cb[k] != 0xFFFFFFFFu) pstage[pos[k]] = __float_as_uint(pm[p]);
    }
    __syncthreads();
    for (int b = t; b < NBUCK; b += 256) {
        u32 cnt = lhist[b], gb0 = gbase[b];
        if (!cnt || gb0 == 0xFFFFFFFFu) continue;
        u32 wr = (gb0 >= CAPB) ? 0u : ((cnt < CAPB - gb0) ? cnt : CAPB - gb0);
        u32 gb = b * CAPB + gb0, lo = lofs[b];
        for (u32 i = 0; i < wr; ++i) stageP[gb + i] = pstage[lo + i];
    }
}

// fused: inline bucket-prefix -> cell-hist -> in-block scan -> startsM -> place.
// (no bucket_scan2 dispatch; block 511 writes the startsM[N0] sentinel)
__global__ __launch_bounds__(256)
void place_fused2(const ull* __restrict__ stageK,
                  const u32* __restrict__ stageP,
                  const u32* __restrict__ bucketCnt,
                  u32* __restrict__ startsM,
                  ull* __restrict__ keysF,
                  u32* __restrict__ payF) {
    __shared__ u32 lh[NBUCK], cur[NBUCK], temp[256];
    __shared__ u32 s_bs;
    int b = blockIdx.x, t = threadIdx.x;
    u32 cnt = bucketCnt[b]; if (cnt > CAPB) cnt = CAPB;
    u32 s = (u32)b * CAPB;
    for (int i = t; i < NBUCK; i += 256) lh[i] = 0;
    __syncthreads();
    // phase 1: cell histogram of this bucket
    for (u32 i = t; i < cnt; i += 256) {
        u32 mlow = (u32)(stageK[s + i] >> 21) & 511u;
        atomicAdd(&lh[mlow], 1u);
    }
    // phase 1b (overlapped): bucket prefix bs = sum_{i<b} min(bucketCnt[i],CAPB)
    {
        u32 acc = 0;
        for (int i = t; i < b; i += 256) {
            u32 v = bucketCnt[i]; acc += (v > CAPB ? CAPB : v);
        }
        temp[t] = acc; __syncthreads();          // also fences the lh atomics
        for (int off = 128; off; off >>= 1) {
            if (t < off) temp[t] += temp[t + off];
            __syncthreads();
        }
        if (t == 0) s_bs = temp[0];
        __syncthreads();
    }
    u32 bs = s_bs;
    if (b == NBUCK - 1 && t == 0) startsM[N0] = bs + cnt;   // sentinel = total
    // phase 2: scan 512 cell counts (pair trick); write startsM slice
    u32 pv = lh[2 * t] + lh[2 * t + 1];
    temp[t] = pv; __syncthreads();
    for (int off = 1; off < 256; off <<= 1) {
        u32 x = temp[t]; u32 a = (t >= off) ? temp[t - off] : 0u;
        __syncthreads(); temp[t] = x + a; __syncthreads();
    }
    u32 pb = temp[t] - pv;
    u32 st0 = bs + pb, st1 = bs + pb + lh[2 * t];
    cur[2 * t] = st0; cur[2 * t + 1] = st1;
    uint2* d = (uint2*)(startsM + (b << 9));
    d[t] = make_uint2(st0, st1);
    __syncthreads();
    // phase 3: place into exact cell slots (strip mlow: key = depth<<32 | idx)
    for (u32 i = t; i < cnt; i += 256) {
        ull en = stageK[s + i];
        u32 mlow = (u32)(en >> 21) & 511u;
        u32 slot = atomicAdd(&cur[mlow], 1u);
        keysF[slot] = ((en >> 32) << 32) | (en & 0x1FFFFFull);
        payF[slot] = stageP[s + i];
    }
}

// ---------- segid scans (256 cells per block, 1 cell/thread) ----------
__device__ __forceinline__ void blk_map2(int b, int& si, int& bb) {
    if (b < 1024)      { si = 0; bb = b; }
    else if (b < 1280) { si = 1; bb = b - 1024; }
    else               { si = 2; bb = b - 1280; }
}
__device__ __forceinline__ u32 cell_cnt(const u32* startsM, int c, int wbits, int si) {
    u32 ci = (u32)c >> wbits, cj = (u32)c & ((1u << wbits) - 1u);
    u32 mb = morton2(ci, cj) << (2 * si);
    return startsM[mb + (1u << (2 * si))] - startsM[mb];
}

__global__ __launch_bounds__(256)
void scanB_partial(const u32* __restrict__ startsM, u32* __restrict__ bsumB) {
    int si, bb; blk_map2(blockIdx.x, si, bb);
    int wbits = 9 - si, t = threadIdx.x;
    int c = bb * 256 + t;
    u32 flg = (cell_cnt(startsM, c, wbits, si) > 0) ? 1u : 0u;
    __shared__ u32 red[256];
    red[t] = flg; __syncthreads();
    for (int off = 128; off; off >>= 1) {
        if (t < off) red[t] += red[t + off];
        __syncthreads();
    }
    if (!t) bsumB[blockIdx.x] = red[0];
}

struct SegArgs {
    u32* segid[3]; float* lens[3]; float* canvas[3];
};
__global__ __launch_bounds__(256)
void scanB_final(const u32* __restrict__ startsM, const u32* __restrict__ bsumB,
                 SegArgs sa, u32* __restrict__ ncells) {
    int si, bb; blk_map2(blockIdx.x, si, bb);
    int wbits = 9 - si, t = threadIdx.x;
    int segStart = (si == 0) ? 0 : (si == 1) ? 1024 : 1280;
    __shared__ u32 s_bpre;
    if (t < 64) {
        u32 acc = 0;
        for (int j = segStart + t; j < (int)blockIdx.x; j += 64) acc += bsumB[j];
        for (int o = 32; o; o >>= 1) acc += __shfl_down(acc, o);
        if (t == 0) s_bpre = acc;
    }
    int c = bb * 256 + t;
    u32 cnt = cell_cnt(startsM, c, wbits, si);
    u32 flg = cnt ? 1u : 0u;
    __shared__ u32 part[256];
    part[t] = flg; __syncthreads();
    for (int off = 1; off < 256; off <<= 1) {
        u32 x = part[t];
        u32 ad = (t >= off) ? part[t - off] : 0u;
        __syncthreads(); part[t] = x + ad; __syncthreads();
    }
    u32 run = s_bpre + part[t] - flg;
    u32* segid = sa.segid[si];
    float* lens = sa.lens[si];
    float* canvas = sa.canvas[si];
    u32 wmask = (1u << wbits) - 1u;
    segid[c] = run;
    if (flg) {
        u32 len = cnt < MAX_RAY ? cnt : MAX_RAY;
        lens[run] = (float)len;
        canvas[2 * run]     = (float)((u32)c >> wbits);
        canvas[2 * run + 1] = (float)((u32)c & wmask);
    }
    if (t == 255 && (blockIdx.x == 1023 || blockIdx.x == 1279 || blockIdx.x == 1343))
        ncells[si] = run + flg;
}

// ---------- emit: grouped LDS-broadcast rank + fused tail-zero ----------
struct CellRegs { ull k0, k1, k2, k3; u32 p0, p1, p2, p3; };
struct __attribute__((packed, aligned(8))) U2 { ull x, y; };
struct __attribute__((packed, aligned(4))) U4 { u32 x, y, z, w; };

template<int CAP>
__device__ __forceinline__ void loadCellG(const ull* __restrict__ keys,
                                          const u32* __restrict__ payg,
                                          const float* __restrict__ pm,
                                          u32 s0, u32 cnt, u32 li, CellRegs& c) {
    c.k0 = c.k1 = c.k2 = c.k3 = ~0ull;
    c.p0 = c.p1 = c.p2 = c.p3 = 0u;
    u32 m = li * 4u;
    if (cnt == 0u || cnt > (u32)CAP || m >= cnt) return;
    const U2* kp = (const U2*)(keys + s0 + m);
    U2 a = kp[0], b = kp[1];
    c.k0 = a.x; c.k1 = a.y; c.k2 = b.x; c.k3 = b.y;
    if (payg) {
        U4 pv = *(const U4*)(payg + s0 + m);
        c.p0 = pv.x; c.p1 = pv.y; c.p2 = pv.z; c.p3 = pv.w;
    } else {
        c.p0 = __float_as_uint(pm[(u32)(c.k0 & 0x1FFFFFull)]);
        if (m + 1 < cnt) c.p1 = __float_as_uint(pm[(u32)(c.k1 & 0x1FFFFFull)]);
        if (m + 2 < cnt) c.p2 = __float_as_uint(pm[(u32)(c.k2 & 0x1FFFFFull)]);
        if (m + 3 < cnt) c.p3 = __float_as_uint(pm[(u32)(c.k3 & 0x1FFFFFull)]);
    }
    if (m + 1 >= cnt) c.k1 = ~0ull;
    if (m + 2 >= cnt) c.k2 = ~0ull;
    if (m + 3 >= cnt) c.k3 = ~0ull;
}

template<int SI>
__device__ __forceinline__ void emit_body(
    const float* __restrict__ pm, const u32* __restrict__ payload,
    const u32* __restrict__ startsM, const ull* __restrict__ keys,
    const u32* __restrict__ segid, float* __restrict__ batch, int bb,
    float (&tile)[64][101], ull (&lkAll)[4][LKELEMS],
    u32 (&s_s0)[64], u32 (&s_cnt)[64], u32 (&s_seg)[64],
    u32 (&ovfl)[64], u32& ovflN)
{
    constexpr int WB   = 9 - SI;
    constexpr int G    = (SI == 0) ? 4 : (SI == 1) ? 16 : 64;    // lanes per cell
    constexpr int CAP  = G * 4;
    constexpr int STRD = (SI == 0) ? 18 : (SI == 1) ? 66 : 256;
    constexpr int NG   = 64 / G;
    constexpr int ROUNDS = 64 / (4 * NG);
    const int HW = 1 << (2 * WB);

    int t = threadIdx.x, wave = t >> 6, lane = t & 63;
    int gi = lane / G, li = lane % G;
    ull* lk = &lkAll[wave][0];

    if (t == 0) ovflN = 0;
    if (t < 64) {
        int cell = bb * 64 + t;
        u32 ci = (u32)cell >> WB, cj = (u32)cell & ((1u << WB) - 1u);
        u32 mb = morton2(ci, cj) << (2 * SI);
        u32 s0 = startsM[mb];
        s_s0[t]  = s0;
        s_cnt[t] = startsM[mb + (1u << (2 * SI))] - s0;
        s_seg[t] = segid[cell];
    }
    __syncthreads();

    CellRegs cur, nxt;
    {
        int lc0 = wave * NG + gi;
        loadCellG<CAP>(keys, payload, pm, s_s0[lc0], s_cnt[lc0], (u32)li, cur);
    }
#pragma unroll
    for (int rnd = 0; rnd < ROUNDS; ++rnd) {
        int lc = (rnd * 4 + wave) * NG + gi;
        u32 cnt = s_cnt[lc], m = (u32)li * 4u;
        bool fits = (cnt <= (u32)CAP);
        if (fits && m < cnt) {
            ull* dst = lk + gi * STRD + m;
            dst[0] = cur.k0; dst[1] = cur.k1; dst[2] = cur.k2; dst[3] = cur.k3;
        }
        if (!fits && li == 0) {
            u32 ix = atomicAdd(&ovflN, 1u);
            ovfl[ix] = (u32)lc;
        }
        if (rnd + 1 < ROUNDS) {
            int lc2 = ((rnd + 1) * 4 + wave) * NG + gi;
            loadCellG<CAP>(keys, payload, pm, s_s0[lc2], s_cnt[lc2], (u32)li, nxt);
        }
        if (cnt && fits) {
            asm volatile("s_waitcnt lgkmcnt(0)" ::: "memory");
            u32 cntR = (cnt + 3u) & ~3u;
            u32 r0 = 0, r1 = 0, r2 = 0, r3 = 0;
            const ull* kb = lk + gi * STRD;
            for (u32 j = 0; j < cntR; j += 4) {
                U2 a  = *(const U2*)(kb + j);
                U2 b2 = *(const U2*)(kb + j + 2);
                r0 += (a.x < cur.k0) + (a.y < cur.k0) + (b2.x < cur.k0) + (b2.y < cur.k0);
                r1 += (a.x < cur.k1) + (a.y < cur.k1) + (b2.x < cur.k1) + (b2.y < cur.k1);
                r2 += (a.x < cur.k2) + (a.y < cur.k2) + (b2.x < cur.k2) + (b2.y < cur.k2);
                r3 += (a.x < cur.k3) + (a.y < cur.k3) + (b2.x < cur.k3) + (b2.y < cur.k3);
            }
            if (m < cnt) {
                if (r0 < MAX_RAY)                 tile[lc][r0] = __uint_as_float(cur.p0);
                if (m + 1 < cnt && r1 < MAX_RAY)  tile[lc][r1] = __uint_as_float(cur.p1);
                if (m + 2 < cnt && r2 < MAX_RAY)  tile[lc][r2] = __uint_as_float(cur.p2);
                if (m + 3 < cnt && r3 < MAX_RAY)  tile[lc][r3] = __uint_as_float(cur.p3);
            }
        }
        cur = nxt;
    }
    __syncthreads();

    u32 no = ovflN;
    if (no && wave == 0) {
        for (u32 o = 0; o < no; ++o) {
            int lc = (int)ovfl[o];
            u32 s0 = s_s0[lc], cnt = s_cnt[lc];
            for (u32 i = lane; i < cnt; i += 64) {
                ull mk = keys[s0 + i];
                u32 r = 0;
                for (u32 j = 0; j < cnt; ++j) r += (keys[s0 + j] < mk) ? 1u : 0u;
                if (r < MAX_RAY) {
                    u32 pv = payload ? payload[s0 + i]
                                     : __float_as_uint(pm[(u32)(mk & 0x1FFFFFull)]);
                    tile[lc][r] = __uint_as_float(pv);
                }
            }
        }
    }
    __syncthreads();

    u32 myCnt = s_cnt[lane], mySeg = s_seg[lane];
    u32 lim = myCnt < MAX_RAY ? myCnt : MAX_RAY;
    for (int r = wave; r < MAX_RAY; r += 4) {
        if (myCnt) batch[(size_t)r * (size_t)HW + mySeg] = (r < (int)lim) ? tile[lane][r] : 0.0f;
    }
}

struct EmitArgs {
    const u32* segid[3]; float* batch[3]; float* lens[3]; float* canvas[3];
};
__global__ __launch_bounds__(256)
void emit_kernel(const float* __restrict__ pm,
                 const u32* __restrict__ payload,
                 const u32* __restrict__ startsM,
                 const ull* __restrict__ keys,
                 EmitArgs ea,
                 const u32* __restrict__ ncells) {
    __shared__ float tile[64][101];
    __shared__ __align__(16) ull lkAll[4][LKELEMS];
    __shared__ u32 s_s0[64], s_cnt[64], s_seg[64], ovfl[64], ovflN;

    int b = blockIdx.x;
    if (b >= 5376) {                       // fused tail-zero blocks
        int tb = b - 5376, t = threadIdx.x;
        for (int si = 0; si < 3; ++si) {
            int HW = (si == 0) ? 262144 : (si == 1) ? 65536 : 16384;
            float* batch = ea.batch[si];
            float* lens = ea.lens[si];
            float* canv = ea.canvas[si];
            u32 nc = ncells[si];
            for (u32 col = nc + (u32)(tb * 256 + t); col < (u32)HW; col += NTAIL * 256) {
                lens[col] = 0.0f;
                canv[2 * col] = 0.0f; canv[2 * col + 1] = 0.0f;
                for (int r = 0; r < MAX_RAY; ++r)
                    batch[(size_t)r * (size_t)HW + col] = 0.0f;
            }
        }
        return;
    }
    if (b < 256)
        emit_body<2>(pm, payload, startsM, keys, ea.segid[2], ea.batch[2], b,
                     tile, lkAll, s_s0, s_cnt, s_seg, ovfl, ovflN);
    else if (b < 1280)
        emit_body<1>(pm, payload, startsM, keys, ea.segid[1], ea.batch[1], b - 256,
                     tile, lkAll, s_s0, s_cnt, s_seg, ovfl, ovflN);
    else
        emit_body<0>(pm, payload, startsM, keys, ea.segid[0], ea.batch[0], b - 1280,
                     tile, lkAll, s_s0, s_cnt, s_seg, ovfl, ovflN);
}

extern "C" void kernel_launch(void* const* d_in, const int* in_sizes, int n_in,
                              void* d_out, int out_size, void* d_ws, size_t ws_size,
                              hipStream_t stream) {
    const float2* coords = (const float2*)d_in[0];
    const float*  depth  = (const float*)d_in[1];
    const float*  pm     = (const float*)d_in[2];
    float* out = (float*)d_out;
    const int n = in_sizes[1];

    const int HWs[3] = {512 * 512, 256 * 256, 128 * 128};

    // ---- workspace layout ----
    char* ws = (char*)d_ws;
    size_t off = 0;
    ull* keysF   = (ull*)(ws + off); off += (size_t)n * 8;
    u32* countsM = (u32*)(ws + off); off += (size_t)N0 * 4;
    u32* startsM = (u32*)(ws + off); off += (size_t)(N0 + 64) * 4;
    u32* segid[3];
    for (int i = 0; i < 3; ++i) { segid[i] = (u32*)(ws + off); off += (size_t)HWs[i] * 4; }
    u32* bsumB = (u32*)(ws + off); off += 2048 * 4;
    u32* bucketCnt   = (u32*)(ws + off); off += NBUCK * 4;
    u32* bucketStart = (u32*)(ws + off); off += (NBUCK + 64) * 4;
    u32* bucketCur   = (u32*)(ws + off); off += NBUCK * 4;
    u32* ncells      = (u32*)(ws + off); off += 64 * 4;
    u32* payF        = (u32*)(ws + off);
    size_t needPay = off + (size_t)n * 4;
    size_t offStage = needPay;
    ull* stageK = (ull*)(ws + offStage);
    u32* stageP = (u32*)(ws + offStage + (size_t)NBUCK * CAPB * 8);
    size_t needStaged = offStage + (size_t)NBUCK * CAPB * 12;

    bool haveStage = (ws_size >= needStaged);
    u32* payg = (ws_size >= needPay) ? payF : nullptr;

    // ---- output offsets ----
    size_t offB[3], offL[3], offC[3];
    size_t o = 0;
    for (int i = 0; i < 3; ++i) { offB[i] = o; o += (size_t)MAX_RAY * HWs[i]; }
    for (int i = 0; i < 3; ++i) { offL[i] = o; o += (size_t)HWs[i]; }
    for (int i = 0; i < 3; ++i) { offC[i] = o; o += 2 * (size_t)HWs[i]; }

    hipMemsetAsync(bucketCnt, 0, NBUCK * 4, stream);

    const int nblkPts = (n + PTS_PER_BLK - 1) / PTS_PER_BLK;

    if (haveStage) {
        bucket_scatter_fixed<<<nblkPts, 256, 0, stream>>>(coords, depth, pm, bucketCnt,
                                                          stageK, stageP, n);
        place_fused2<<<NBUCK, 256, 0, stream>>>(stageK, stageP, bucketCnt,
                                                startsM, keysF, payF);
        payg = payF;
    } else {
        bucket_hist_kernel<<<nblkPts, 256, 0, stream>>>(coords, bucketCnt, n);
        bucket_scan_kernel<<<1, NBUCK, 0, stream>>>(bucketCnt, bucketStart, bucketCur, n);
        bucket_scatter_kernel<<<nblkPts, 256, 0, stream>>>(coords, depth, pm, bucketCur,
                                                           keysF, payg, n);
        cell_hist_kernel<<<NBUCK, 256, 0, stream>>>(keysF, bucketStart, countsM);
        scanA_final2<<<NBLK0, 256, 0, stream>>>(countsM, bucketStart, startsM);
        place_kernel<<<NBUCK, 256, 0, stream>>>(keysF, payg, bucketStart, startsM);
    }

    SegArgs sa;
    for (int i = 0; i < 3; ++i) {
        sa.segid[i]  = segid[i];
        sa.lens[i]   = out + offL[i];
        sa.canvas[i] = out + offC[i];
    }
    scanB_partial<<<NBLKB2, 256, 0, stream>>>(startsM, bsumB);
    scanB_final<<<NBLKB2, 256, 0, stream>>>(startsM, bsumB, sa, ncells);

    EmitArgs ea;
    for (int i = 0; i < 3; ++i) {
        ea.segid[i]  = segid[i];
        ea.batch[i]  = out + offB[i];
        ea.lens[i]   = out + offL[i];
        ea.canvas[i] = out + offC[i];
    }
    emit_kernel<<<5376 + NTAIL, 256, 0, stream>>>(pm, payg, startsM, keysF, ea, ncells);
}